// Round 6
// baseline (373.304 us; speedup 1.0000x reference)
//
#include <hip/hip_runtime.h>
#include <math.h>

#define NB 64
#define NP 196
#define ND 256
#define NBP (NB * NP)   // 12544

typedef __bf16 v8bf __attribute__((ext_vector_type(8)));
typedef __bf16 v4bf __attribute__((ext_vector_type(4)));
typedef float f32x16 __attribute__((ext_vector_type(16)));

// ws layout (fast path), bytes:
//   inv1   @ 0          : 12544 f32
//   inv2   @ 50176      : 12544 f32
//   sim12  @ 100352     : 4096  f32
//   t1sw   @ 116736     : 98 tiles x 4 kc x (128x64 bf16 swizzled LDS image, 16KB) = 6422528 B
//   t2sw   @ 6539264    : 64 panels x 4 kc x (256x64 bf16 swizzled LDS image, 32KB; rows 196..255 zero) = 8388608 B
//   parts  @ 14927872   : 64*4*196 u64 = 401408 B
#define WS_T1SW   116736
#define WS_T2SW   6539264
#define WS_PARTS  14927872
#define WS_NEED   15329280

// ---------------------------------------------------------------------------
// packed (value,index) for argmax with np first-occurrence tie-break
// ---------------------------------------------------------------------------
__device__ __forceinline__ unsigned int fmono(float v) {
    unsigned int u = __float_as_uint(v);
    return (u & 0x80000000u) ? ~u : (u | 0x80000000u);
}
__device__ __forceinline__ unsigned long long packVI(float v, int idx) {
    return ((unsigned long long)fmono(v) << 32) | (unsigned int)(~idx);
}

// async global -> LDS, 16 B/lane. lds MUST be wave-uniform (HW adds lane*16).
__device__ __forceinline__ void gl_lds16(void* lds, const void* gp) {
    __builtin_amdgcn_global_load_lds(
        (const __attribute__((address_space(1))) unsigned int*)gp,
        (__attribute__((address_space(3))) unsigned int*)lds, 16, 0, 0);
}

// ===========================================================================
// FAST PATH
// ===========================================================================

// Kernel 1: per-row norm -> inv arrays; write normalized bf16 rows in the
// per-(tile,kc) swizzled LDS-image layout (linear-DMA-friendly: the MFMA
// kernel copies images verbatim and applies the swizzle on the READ side).
// 256 threads = 4 row-groups of 64 lanes. Block 0 zeroes sim12.
__global__ __launch_bounds__(256)
void filip_prep4(const float* __restrict__ t1, const float* __restrict__ t2,
                 float* __restrict__ inv1, float* __restrict__ inv2,
                 float* __restrict__ sim12,
                 char* __restrict__ t1sw, char* __restrict__ t2sw) {
    const int tid = threadIdx.x;
    if (blockIdx.x == 0) {
        float4 z = make_float4(0.f, 0.f, 0.f, 0.f);
        float4* s4 = reinterpret_cast<float4*>(sim12);
        #pragma unroll
        for (int j = 0; j < 4; ++j) s4[tid * 4 + j] = z;
    }
    int id = blockIdx.x * 4 + (tid >> 6);   // 0 .. NBP + NB*256 - 1
    int lane = tid & 63;
    int kc = lane >> 4;              // K chunk of 64
    int k8 = (lane & 15) * 8;        // byte col within chunk row
    if (id < NBP) {
        const float* src = t1 + (size_t)id * ND;
        float4 v = reinterpret_cast<const float4*>(src)[lane];
        float ss = v.x * v.x + v.y * v.y + v.z * v.z + v.w * v.w;
        #pragma unroll
        for (int off = 32; off > 0; off >>= 1) ss += __shfl_xor(ss, off, 64);
        float inv = 1.0f / fmaxf(sqrtf(ss), 1e-12f);
        if (lane == 0) inv1[id] = inv;
        v4bf o;
        o[0] = (__bf16)(v.x * inv); o[1] = (__bf16)(v.y * inv);
        o[2] = (__bf16)(v.z * inv); o[3] = (__bf16)(v.w * inv);
        int bRow = id >> 7, r = id & 127;
        char* dst = t1sw + (size_t)(bRow * 4 + kc) * 16384
                         + r * 128 + (k8 ^ ((r & 7) << 4));
        *reinterpret_cast<v4bf*>(dst) = o;
    } else {
        int pid = id - NBP;          // 0..16383
        int b2 = pid >> 8, r = pid & 255;
        char* dst = t2sw + (size_t)(b2 * 4 + kc) * 32768
                         + r * 128 + (k8 ^ ((r & 7) << 4));
        if (r < NP) {
            const float* src = t2 + (size_t)(b2 * NP + r) * ND;
            float4 v = reinterpret_cast<const float4*>(src)[lane];
            float ss = v.x * v.x + v.y * v.y + v.z * v.z + v.w * v.w;
            #pragma unroll
            for (int off = 32; off > 0; off >>= 1) ss += __shfl_xor(ss, off, 64);
            float inv = 1.0f / fmaxf(sqrtf(ss), 1e-12f);
            if (lane == 0) inv2[b2 * NP + r] = inv;
            v4bf o;
            o[0] = (__bf16)(v.x * inv); o[1] = (__bf16)(v.y * inv);
            o[2] = (__bf16)(v.z * inv); o[3] = (__bf16)(v.w * inv);
            *reinterpret_cast<v4bf*>(dst) = o;
        } else {
            v4bf z; z[0] = z[1] = z[2] = z[3] = (__bf16)0.0f;
            *reinterpret_cast<v4bf*>(dst) = z;
        }
    }
}

// Kernel 2: bf16 MFMA mean-of-rowmax. global_load_lds staging with
// WAVE-UNIFORM LDS base (readfirstlane) — per-lane global source, HW
// scatters lane i -> base + i*16. 3 blocks/CU.
#define BM 128
#define BN 256
#define BK 64

__global__ __launch_bounds__(256, 3)
void filip_mfma5(const char* __restrict__ t1sw, const char* __restrict__ t2sw,
                 float* __restrict__ sim12)
{
    __shared__ __align__(16) char Asb[BM * BK * 2];   // 16 KB swizzled image
    __shared__ __align__(16) char Bsb[BN * BK * 2];   // 32 KB
    __shared__ float rmx[2][BM];

    // XCD-aware bijection with A-tile reuse: XCD x = n&7 owns b2 in [8x,8x+8);
    // b2 varies innermost -> A-tile reused 8x back-to-back, 8 B-panel images
    // (1 MB) stay L2-resident per XCD.
    int n = blockIdx.x + 98 * blockIdx.y;   // 0..6271
    int x = n & 7, local = n >> 3;
    const int bRow = local >> 3;            // 0..97
    const int b2   = x * 8 + (local & 7);   // 0..63

    const int tid  = threadIdx.x;
    const int lane = tid & 63, wave = tid >> 6;
    const int wr = wave >> 1, wc = wave & 1;
    const int ln = lane & 31, hi = lane >> 5;

    // wave-uniform LDS chunk offset (1 KB per wave per DMA instruction)
    const int wvoff = __builtin_amdgcn_readfirstlane(wave << 10);
    const int l16 = lane * 16;

    const char* Ab = t1sw + (size_t)bRow * 4 * 16384;
    const char* Bb = t2sw + (size_t)b2 * 4 * 32768;

    f32x16 acc[2][4];
    #pragma unroll
    for (int mt = 0; mt < 2; ++mt)
        #pragma unroll
        for (int nt = 0; nt < 4; ++nt)
            #pragma unroll
            for (int r = 0; r < 16; ++r) acc[mt][nt][r] = 0.0f;

    for (int kc = 0; kc < 4; ++kc) {
        __syncthreads();   // prev tile's reads complete before DMA overwrite
        // stage A: 16 KB (4 x 1KB chunks per wave)
        #pragma unroll
        for (int i = 0; i < 4; ++i) {
            int off = i * 4096 + wvoff;
            gl_lds16(Asb + off, Ab + kc * 16384 + off + l16);
        }
        // stage B: 32 KB (8 x 1KB chunks per wave)
        #pragma unroll
        for (int i = 0; i < 8; ++i) {
            int off = i * 4096 + wvoff;
            gl_lds16(Bsb + off, Bb + kc * 32768 + off + l16);
        }
        __syncthreads();   // drains vmcnt -> LDS images complete
        // compute: 4 k-steps of K=16, 8 MFMA each (read path identical to r3)
        #pragma unroll
        for (int ks = 0; ks < 4; ++ks) {
            const int kb = ks * 32 + hi * 16;   // byte col in LDS row
            v8bf af[2], bfr[4];
            #pragma unroll
            for (int mt = 0; mt < 2; ++mt) {
                int r = wr * 64 + mt * 32 + ln;
                af[mt] = *reinterpret_cast<const v8bf*>(
                    Asb + r * 128 + (kb ^ ((r & 7) << 4)));
            }
            #pragma unroll
            for (int nt = 0; nt < 4; ++nt) {
                int c = wc * 128 + nt * 32 + ln;
                bfr[nt] = *reinterpret_cast<const v8bf*>(
                    Bsb + c * 128 + (kb ^ ((c & 7) << 4)));
            }
            #pragma unroll
            for (int mt = 0; mt < 2; ++mt)
                #pragma unroll
                for (int nt = 0; nt < 4; ++nt)
                    acc[mt][nt] = __builtin_amdgcn_mfma_f32_32x32x16_bf16(
                        af[mt], bfr[nt], acc[mt][nt], 0, 0, 0);
        }
    }

    // fused rowmax; C/D layout: col = lane&31, row = (r&3) + 8*(r>>2) + 4*hi
    #pragma unroll
    for (int mt = 0; mt < 2; ++mt) {
        float t[16];
        #pragma unroll
        for (int r = 0; r < 16; ++r) {
            float m = fmaxf(fmaxf(acc[mt][0][r], acc[mt][1][r]),
                            fmaxf(acc[mt][2][r], acc[mt][3][r]));
            #pragma unroll
            for (int off = 1; off <= 16; off <<= 1)
                m = fmaxf(m, __shfl_xor(m, off, 64));
            t[r] = m;
        }
        if (ln == 0) {
            #pragma unroll
            for (int r = 0; r < 16; ++r) {
                int row = wr * 64 + mt * 32 + (r & 3) + 8 * (r >> 2) + 4 * hi;
                rmx[wc][row] = t[r];
            }
        }
    }
    __syncthreads();
    if (tid < BM) {
        float m = fmaxf(rmx[0][tid], rmx[1][tid]);
        int grow = bRow * BM + tid;
        int b1 = grow / NP;
        int fb = (bRow * BM) / NP;
        float v0 = (b1 == fb) ? m : 0.0f;
        float v1 = (b1 != fb) ? m : 0.0f;
        #pragma unroll
        for (int off = 1; off < 64; off <<= 1) {
            v0 += __shfl_xor(v0, off, 64);
            v1 += __shfl_xor(v1, off, 64);
        }
        if (lane == 0) {
            atomicAdd(&sim12[fb * NB + b2], v0);
            int lb = (bRow * BM + BM - 1) / NP;
            if (lb != fb) atomicAdd(&sim12[lb * NB + b2], v1);
        }
    }
}

// Kernel 3: fp32-exact diagonal blocks, 4 blocks per batch (49 rows each).
__global__ __launch_bounds__(256)
void filip_diag4(const float* __restrict__ t1, const float* __restrict__ t2,
                 const float* __restrict__ inv1, const float* __restrict__ inv2,
                 unsigned long long* __restrict__ parts,
                 float* __restrict__ out)
{
    const int q = blockIdx.x;          // 0..3 (row quarter)
    const int b = blockIdx.y;          // 0..63
    const int r0 = q * 49;
    const int tid = threadIdx.x;
    const int tx = tid & 15, ty = tid >> 4;

    __shared__ float smemF[2176 + 8320];       // As[32][68] + Bs[32][260]
    float* As = smemF;
    float* Bs = smemF + 2176;
    unsigned long long* colP = reinterpret_cast<unsigned long long*>(smemF); // reuse

    const float* Ap = t1 + (size_t)b * NP * ND;
    const float* Bp = t2 + (size_t)b * NP * ND;
    const float* ia = inv1 + b * NP;
    const float* ib = inv2 + b * NP;

    float acc[4][4][4];
    #pragma unroll
    for (int i = 0; i < 4; ++i)
        #pragma unroll
        for (int j = 0; j < 4; ++j)
            #pragma unroll
            for (int l = 0; l < 4; ++l) acc[i][j][l] = 0.0f;

    for (int kc = 0; kc < 8; ++kc) {
        __syncthreads();
        #pragma unroll
        for (int i = 0; i < 2; ++i) {
            int f4 = tid + 256 * i;            // 0..511
            int row = f4 >> 3, k4 = f4 & 7;
            float4 v = make_float4(0.f, 0.f, 0.f, 0.f);
            if (row < 49) {
                v = *reinterpret_cast<const float4*>(Ap + (size_t)(r0 + row) * ND + kc * 32 + 4 * k4);
                float s = ia[r0 + row];
                v.x *= s; v.y *= s; v.z *= s; v.w *= s;
            }
            As[(4 * k4 + 0) * 68 + row] = v.x;
            As[(4 * k4 + 1) * 68 + row] = v.y;
            As[(4 * k4 + 2) * 68 + row] = v.z;
            As[(4 * k4 + 3) * 68 + row] = v.w;
        }
        #pragma unroll
        for (int i = 0; i < 8; ++i) {
            int f4 = tid + 256 * i;            // 0..2047
            int col = f4 >> 3, k4 = f4 & 7;
            float4 v = make_float4(0.f, 0.f, 0.f, 0.f);
            if (col < NP) {
                v = *reinterpret_cast<const float4*>(Bp + (size_t)col * ND + kc * 32 + 4 * k4);
                float s = ib[col];
                v.x *= s; v.y *= s; v.z *= s; v.w *= s;
            }
            Bs[(4 * k4 + 0) * 260 + col] = v.x;
            Bs[(4 * k4 + 1) * 260 + col] = v.y;
            Bs[(4 * k4 + 2) * 260 + col] = v.z;
            Bs[(4 * k4 + 3) * 260 + col] = v.w;
        }
        __syncthreads();
        #pragma unroll 4
        for (int k = 0; k < 32; ++k) {
            float a0 = As[k * 68 + 4 * ty + 0];
            float a1 = As[k * 68 + 4 * ty + 1];
            float a2 = As[k * 68 + 4 * ty + 2];
            float a3 = As[k * 68 + 4 * ty + 3];
            float4 bq[4];
            #pragma unroll
            for (int j = 0; j < 4; ++j)
                bq[j] = *reinterpret_cast<const float4*>(&Bs[k * 260 + 4 * tx + 64 * j]);
            #pragma unroll
            for (int j = 0; j < 4; ++j) {
                acc[0][j][0] = fmaf(a0, bq[j].x, acc[0][j][0]);
                acc[0][j][1] = fmaf(a0, bq[j].y, acc[0][j][1]);
                acc[0][j][2] = fmaf(a0, bq[j].z, acc[0][j][2]);
                acc[0][j][3] = fmaf(a0, bq[j].w, acc[0][j][3]);
                acc[1][j][0] = fmaf(a1, bq[j].x, acc[1][j][0]);
                acc[1][j][1] = fmaf(a1, bq[j].y, acc[1][j][1]);
                acc[1][j][2] = fmaf(a1, bq[j].z, acc[1][j][2]);
                acc[1][j][3] = fmaf(a1, bq[j].w, acc[1][j][3]);
                acc[2][j][0] = fmaf(a2, bq[j].x, acc[2][j][0]);
                acc[2][j][1] = fmaf(a2, bq[j].y, acc[2][j][1]);
                acc[2][j][2] = fmaf(a2, bq[j].z, acc[2][j][2]);
                acc[2][j][3] = fmaf(a2, bq[j].w, acc[2][j][3]);
                acc[3][j][0] = fmaf(a3, bq[j].x, acc[3][j][0]);
                acc[3][j][1] = fmaf(a3, bq[j].y, acc[3][j][1]);
                acc[3][j][2] = fmaf(a3, bq[j].z, acc[3][j][2]);
                acc[3][j][3] = fmaf(a3, bq[j].w, acc[3][j][3]);
            }
        }
    }

    // row argmax (idx_to_keep1_2)
    #pragma unroll
    for (int i = 0; i < 4; ++i) {
        unsigned long long best = 0ull;
        #pragma unroll
        for (int j = 0; j < 4; ++j)
            #pragma unroll
            for (int l = 0; l < 4; ++l) {
                int c = 64 * j + 4 * tx + l;
                if (c < NP) {
                    unsigned long long p = packVI(acc[i][j][l], c);
                    if (p > best) best = p;
                }
            }
        #pragma unroll
        for (int off = 1; off < 16; off <<= 1) {
            unsigned long long o = __shfl_xor(best, off, 16);
            if (o > best) best = o;
        }
        int rl = 4 * ty + i;
        if (tx == 0 && rl < 49)
            out[1 + b * NP + r0 + rl] = (float)(unsigned int)(~best);
    }

    // col argmax partials (idx_to_keep2_1)
    __syncthreads();
    #pragma unroll
    for (int j = 0; j < 4; ++j)
        #pragma unroll
        for (int l = 0; l < 4; ++l) {
            unsigned long long best = 0ull;
            #pragma unroll
            for (int i = 0; i < 4; ++i) {
                int rl = 4 * ty + i;
                if (rl < 49) {
                    unsigned long long p = packVI(acc[i][j][l], r0 + rl);
                    if (p > best) best = p;
                }
            }
            colP[ty * 256 + 64 * j + 4 * tx + l] = best;
        }
    __syncthreads();
    {
        unsigned long long best = 0ull;
        #pragma unroll
        for (int y = 0; y < 16; ++y) {
            unsigned long long o = colP[y * 256 + tid];
            if (o > best) best = o;
        }
        if (tid < NP) parts[(b * 4 + q) * NP + tid] = best;
    }
}

// Kernel 4: merge the 4 quarter partials -> idx_to_keep2_1
__global__ void filip_fin(const unsigned long long* __restrict__ parts,
                          float* __restrict__ out) {
    int id = blockIdx.x * 256 + threadIdx.x;   // 49*256 = 12544
    int b = id / NP, c = id - b * NP;
    unsigned long long best = 0ull;
    #pragma unroll
    for (int qq = 0; qq < 4; ++qq) {
        unsigned long long o = parts[(b * 4 + qq) * NP + c];
        if (o > best) best = o;
    }
    out[1 + NBP + id] = (float)(unsigned int)(~best);
}

// Kernel 5: InfoNCE loss. sim12 holds SUMS of rowmax -> scale by 10/196.
__global__ void filip_loss(const float* __restrict__ sim12,
                           float* __restrict__ out) {
    int i = threadIdx.x;  // 0..63
    const float SC = 10.0f / 196.0f;
    const float* row = sim12 + i * NB;
    float mx = -3.0e38f;
    for (int j = 0; j < NB; ++j) mx = fmaxf(mx, row[j] * SC);
    float s = 0.0f;
    for (int j = 0; j < NB; ++j) s += expf(row[j] * SC - mx);
    float lse = mx + logf(s);
    float li = lse - row[i] * SC;
    #pragma unroll
    for (int off = 32; off > 0; off >>= 1)
        li += __shfl_xor(li, off, 64);
    if (i == 0) out[0] = li / 64.0f;
}

// ===========================================================================
// FALLBACK PATH (verbatim round-2, known-passing) — used if ws too small
// ===========================================================================
__global__ void filip_norms(const float* __restrict__ t1,
                            const float* __restrict__ t2,
                            float* __restrict__ inv1,
                            float* __restrict__ inv2,
                            float* __restrict__ sim12) {
    int row = blockIdx.x;
    int lane = threadIdx.x;
    if (row < NB) sim12[row * NB + lane] = 0.0f;
    const float* src; float* dst; int r;
    if (row < NBP) { src = t1; dst = inv1; r = row; }
    else           { src = t2; dst = inv2; r = row - NBP; }
    float4 v = reinterpret_cast<const float4*>(src + (size_t)r * ND)[lane];
    float ss = v.x * v.x + v.y * v.y + v.z * v.z + v.w * v.w;
    #pragma unroll
    for (int off = 32; off > 0; off >>= 1)
        ss += __shfl_xor(ss, off, 64);
    if (lane == 0)
        dst[r] = 1.0f / fmaxf(sqrtf(ss), 1e-12f);
}

__device__ __forceinline__ v8bf cvt8(float4 a, float4 b, float s) {
    v8bf v;
    v[0] = (__bf16)(a.x * s); v[1] = (__bf16)(a.y * s);
    v[2] = (__bf16)(a.z * s); v[3] = (__bf16)(a.w * s);
    v[4] = (__bf16)(b.x * s); v[5] = (__bf16)(b.y * s);
    v[6] = (__bf16)(b.z * s); v[7] = (__bf16)(b.w * s);
    return v;
}

__global__ __launch_bounds__(256, 2)
void filip_mfma(const float* __restrict__ t1, const float* __restrict__ t2,
                const float* __restrict__ inv1, const float* __restrict__ inv2,
                float* __restrict__ sim12)
{
    __shared__ unsigned short Asb[BM * BK];
    __shared__ unsigned short Bsb[BN * BK];
    __shared__ float rmx[2][BM];

    const int bRow = blockIdx.x;
    const int b2   = blockIdx.y;
    const int tid  = threadIdx.x;
    const int lane = tid & 63, wave = tid >> 6;
    const int wr = wave >> 1, wc = wave & 1;
    const int ln = lane & 31, hi = lane >> 5;

    const float* Abase = t1 + (size_t)bRow * BM * ND;
    const float* Bbase = t2 + (size_t)b2 * NP * ND;

    f32x16 acc[2][4];
    #pragma unroll
    for (int mt = 0; mt < 2; ++mt)
        #pragma unroll
        for (int nt = 0; nt < 4; ++nt)
            #pragma unroll
            for (int r = 0; r < 16; ++r) acc[mt][nt][r] = 0.0f;

    for (int kc = 0; kc < 4; ++kc) {
        __syncthreads();
        #pragma unroll
        for (int i = 0; i < 4; ++i) {
            int flat = (i * 256 + tid) * 8;
            int r = flat >> 6, k0 = flat & 63;
            const float* gp = Abase + (size_t)r * ND + kc * BK + k0;
            float4 f0 = *reinterpret_cast<const float4*>(gp);
            float4 f1 = *reinterpret_cast<const float4*>(gp + 4);
            float s = inv1[bRow * BM + r];
            v8bf v = cvt8(f0, f1, s);
            int off = r * 128 + ((k0 * 2) ^ ((r & 7) << 4));
            *reinterpret_cast<v8bf*>(reinterpret_cast<char*>(Asb) + off) = v;
        }
        #pragma unroll
        for (int i = 0; i < 8; ++i) {
            int flat = (i * 256 + tid) * 8;
            int r = flat >> 6, k0 = flat & 63;
            v8bf v;
            if (r < NP) {
                const float* gp = Bbase + (size_t)r * ND + kc * BK + k0;
                float4 f0 = *reinterpret_cast<const float4*>(gp);
                float4 f1 = *reinterpret_cast<const float4*>(gp + 4);
                float s = inv2[b2 * NP + r];
                v = cvt8(f0, f1, s);
            } else {
                #pragma unroll
                for (int j = 0; j < 8; ++j) v[j] = (__bf16)0.0f;
            }
            int off = r * 128 + ((k0 * 2) ^ ((r & 7) << 4));
            *reinterpret_cast<v8bf*>(reinterpret_cast<char*>(Bsb) + off) = v;
        }
        __syncthreads();
        #pragma unroll
        for (int ks = 0; ks < 4; ++ks) {
            const int kb = ks * 32 + hi * 16;
            v8bf af[2], bfr[4];
            #pragma unroll
            for (int mt = 0; mt < 2; ++mt) {
                int r = wr * 64 + mt * 32 + ln;
                af[mt] = *reinterpret_cast<const v8bf*>(
                    reinterpret_cast<const char*>(Asb) + r * 128 + (kb ^ ((r & 7) << 4)));
            }
            #pragma unroll
            for (int nt = 0; nt < 4; ++nt) {
                int c = wc * 128 + nt * 32 + ln;
                bfr[nt] = *reinterpret_cast<const v8bf*>(
                    reinterpret_cast<const char*>(Bsb) + c * 128 + (kb ^ ((c & 7) << 4)));
            }
            #pragma unroll
            for (int mt = 0; mt < 2; ++mt)
                #pragma unroll
                for (int nt = 0; nt < 4; ++nt)
                    acc[mt][nt] = __builtin_amdgcn_mfma_f32_32x32x16_bf16(
                        af[mt], bfr[nt], acc[mt][nt], 0, 0, 0);
        }
    }

    #pragma unroll
    for (int mt = 0; mt < 2; ++mt) {
        float t[16];
        #pragma unroll
        for (int r = 0; r < 16; ++r) {
            float m = fmaxf(fmaxf(acc[mt][0][r], acc[mt][1][r]),
                            fmaxf(acc[mt][2][r], acc[mt][3][r]));
            #pragma unroll
            for (int off = 1; off <= 16; off <<= 1)
                m = fmaxf(m, __shfl_xor(m, off, 64));
            t[r] = m;
        }
        if (ln == 0) {
            #pragma unroll
            for (int r = 0; r < 16; ++r) {
                int row = wr * 64 + mt * 32 + (r & 3) + 8 * (r >> 2) + 4 * hi;
                rmx[wc][row] = t[r];
            }
        }
    }
    __syncthreads();
    if (tid < BM) {
        float m = fmaxf(rmx[0][tid], rmx[1][tid]);
        int grow = bRow * BM + tid;
        int b1 = grow / NP;
        int fb = (bRow * BM) / NP;
        float v0 = (b1 == fb) ? m : 0.0f;
        float v1 = (b1 != fb) ? m : 0.0f;
        #pragma unroll
        for (int off = 1; off < 64; off <<= 1) {
            v0 += __shfl_xor(v0, off, 64);
            v1 += __shfl_xor(v1, off, 64);
        }
        if (lane == 0) {
            atomicAdd(&sim12[fb * NB + b2], v0);
            int lb = (bRow * BM + BM - 1) / NP;
            if (lb != fb) atomicAdd(&sim12[lb * NB + b2], v1);
        }
    }
}

__global__ __launch_bounds__(256)
void filip_diag(const float* __restrict__ t1, const float* __restrict__ t2,
                const float* __restrict__ inv1, const float* __restrict__ inv2,
                float* __restrict__ out)
{
    const int b = blockIdx.x;
    const int tid = threadIdx.x;
    const int tx = tid & 15, ty = tid >> 4;

    __shared__ float As2[16][209];
    __shared__ float Bs2[16][65];
    __shared__ float colV[16][65];
    __shared__ int   colI[16][65];

    const float* Ap = t1 + (size_t)b * NP * ND;
    const float* Bp = t2 + (size_t)b * NP * ND;
    const float* ia = inv1 + b * NP;
    const float* ib = inv2 + b * NP;

    float rmax[13];
    int   ridx[13];
    #pragma unroll
    for (int m = 0; m < 13; ++m) { rmax[m] = -3.0e38f; ridx[m] = 1 << 30; }

    for (int tile = 0; tile < 4; ++tile) {
        float acc[13][4];
        #pragma unroll
        for (int m = 0; m < 13; ++m)
            #pragma unroll
            for (int n = 0; n < 4; ++n) acc[m][n] = 0.0f;

        for (int kk = 0; kk < 16; ++kk) {
            __syncthreads();
            #pragma unroll
            for (int i = 0; i < 13; ++i) {
                int e = tid + 256 * i;
                int p1 = e >> 4, k = e & 15;
                float v = 0.0f;
                if (p1 < NP) v = Ap[p1 * ND + kk * 16 + k] * ia[p1];
                As2[k][p1] = v;
            }
            #pragma unroll
            for (int i = 0; i < 4; ++i) {
                int e = tid + 256 * i;
                int pl = e >> 4, k = e & 15;
                int p2 = tile * 64 + pl;
                float v = 0.0f;
                if (p2 < NP) v = Bp[p2 * ND + kk * 16 + k] * ib[p2];
                Bs2[k][pl] = v;
            }
            __syncthreads();
            #pragma unroll 4
            for (int k = 0; k < 16; ++k) {
                float a[13], bq[4];
                #pragma unroll
                for (int m = 0; m < 13; ++m) a[m] = As2[k][ty + 16 * m];
                #pragma unroll
                for (int n = 0; n < 4; ++n) bq[n] = Bs2[k][tx + 16 * n];
                #pragma unroll
                for (int m = 0; m < 13; ++m)
                    #pragma unroll
                    for (int n = 0; n < 4; ++n)
                        acc[m][n] = fmaf(a[m], bq[n], acc[m][n]);
            }
        }

        #pragma unroll
        for (int n = 0; n < 4; ++n) {
            int c = tile * 64 + tx + 16 * n;
            if (c < NP) {
                #pragma unroll
                for (int m = 0; m < 13; ++m) {
                    float v = acc[m][n];
                    if (v > rmax[m] || (v == rmax[m] && c < ridx[m])) {
                        rmax[m] = v; ridx[m] = c;
                    }
                }
            }
        }

        #pragma unroll
        for (int n = 0; n < 4; ++n) {
            float bv = -3.0e38f; int bi = 1 << 30;
            #pragma unroll
            for (int m = 0; m < 13; ++m) {
                int row = ty + 16 * m;
                if (row < NP) {
                    float v = acc[m][n];
                    if (v > bv || (v == bv && row < bi)) { bv = v; bi = row; }
                }
            }
            colV[ty][tx + 16 * n] = bv;
            colI[ty][tx + 16 * n] = bi;
        }
        __syncthreads();
        if (tid < 64) {
            int c = tile * 64 + tid;
            if (c < NP) {
                float bv = -3.0e38f; int bi = 1 << 30;
                #pragma unroll
                for (int y = 0; y < 16; ++y) {
                    float v = colV[y][tid]; int i2 = colI[y][tid];
                    if (v > bv || (v == bv && i2 < bi)) { bv = v; bi = i2; }
                }
                out[1 + NBP + b * NP + c] = (float)bi;
            }
        }
        __syncthreads();
    }

    #pragma unroll
    for (int m = 0; m < 13; ++m) {
        float v = rmax[m]; int ix = ridx[m];
        #pragma unroll
        for (int off = 1; off < 16; off <<= 1) {
            float ov = __shfl_xor(v, off, 16);
            int   oi = __shfl_xor(ix, off, 16);
            if (ov > v || (ov == v && oi < ix)) { v = ov; ix = oi; }
        }
        rmax[m] = v; ridx[m] = ix;
    }
    if (tx == 0) {
        #pragma unroll
        for (int m = 0; m < 13; ++m) {
            int row = ty + 16 * m;
            if (row < NP) out[1 + b * NP + row] = (float)ridx[m];
        }
    }
}

// ---------------------------------------------------------------------------
extern "C" void kernel_launch(void* const* d_in, const int* in_sizes, int n_in,
                              void* d_out, int out_size, void* d_ws, size_t ws_size,
                              hipStream_t stream) {
    const float* t1 = (const float*)d_in[0];
    const float* t2 = (const float*)d_in[1];
    float* out = (float*)d_out;
    float* ws  = (float*)d_ws;

    float* inv1  = ws;
    float* inv2  = ws + NBP;
    float* sim12 = ws + 2 * NBP;

    if (ws_size >= (size_t)WS_NEED) {
        char* t1sw = (char*)d_ws + WS_T1SW;
        char* t2sw = (char*)d_ws + WS_T2SW;
        unsigned long long* parts = (unsigned long long*)((char*)d_ws + WS_PARTS);

        filip_prep4<<<(NBP + NB * 256) / 4, 256, 0, stream>>>(t1, t2, inv1, inv2, sim12, t1sw, t2sw);
        filip_mfma5<<<dim3(98, NB), 256, 0, stream>>>(t1sw, t2sw, sim12);
        filip_diag4<<<dim3(4, NB), 256, 0, stream>>>(t1, t2, inv1, inv2, parts, out);
        filip_fin<<<49, 256, 0, stream>>>(parts, out);
        filip_loss<<<1, 64, 0, stream>>>(sim12, out);
    } else {
        filip_norms<<<2 * NBP, 64, 0, stream>>>(t1, t2, inv1, inv2, sim12);
        filip_mfma<<<dim3(98, NB), 256, 0, stream>>>(t1, t2, inv1, inv2, sim12);
        filip_diag<<<NB, 256, 0, stream>>>(t1, t2, inv1, inv2, out);
        filip_loss<<<1, 64, 0, stream>>>(sim12, out);
    }
}

// Round 7
// 203.014 us; speedup vs baseline: 1.8388x; 1.8388x over previous
//
#include <hip/hip_runtime.h>
#include <math.h>

#define NB 64
#define NP 196
#define ND 256
#define NBP (NB * NP)   // 12544

typedef __bf16 v8bf __attribute__((ext_vector_type(8)));
typedef __bf16 v4bf __attribute__((ext_vector_type(4)));
typedef float f32x16 __attribute__((ext_vector_type(16)));

// ws layout (fast path), bytes:
//   inv1   @ 0          : 12544 f32
//   inv2   @ 50176      : 12544 f32
//   sim12  @ 100352     : 4096  f32
//   t1fl   @ 116736     : 98 tiles x fragment-linear (32 kgroups x 128 rows x 16B) = 6422528 B
//   t2fl   @ 6539264    : 64 panels x fragment-linear (32 kgroups x 256 cols x 16B; cols 196..255 zero) = 8388608 B
//   parts  @ 14927872   : 64*4*196 u64 = 401408 B
#define WS_T1FL   116736
#define WS_T2FL   6539264
#define WS_PARTS  14927872
#define WS_NEED   15329280

// ---------------------------------------------------------------------------
// packed (value,index) for argmax with np first-occurrence tie-break
// ---------------------------------------------------------------------------
__device__ __forceinline__ unsigned int fmono(float v) {
    unsigned int u = __float_as_uint(v);
    return (u & 0x80000000u) ? ~u : (u | 0x80000000u);
}
__device__ __forceinline__ unsigned long long packVI(float v, int idx) {
    return ((unsigned long long)fmono(v) << 32) | (unsigned int)(~idx);
}

// ===========================================================================
// FAST PATH
// ===========================================================================

// Kernel 1: per-row norm -> inv arrays; write normalized bf16 in
// FRAGMENT-LINEAR layout: for each 16B k-group g (8 bf16), all rows/cols
// contiguous. The MFMA kernel then loads each fragment as two contiguous
// 512B segments directly from global — no LDS anywhere in the GEMM.
//   A: t1fl + tile*65536 + g*2048 + row*16      (tile = 128 rows, g in [0,32))
//   B: t2fl + b2*131072  + g*4096 + col*16      (panel = 256 cols, g in [0,32))
// Lane L (0..63) holds k-elems [4L,4L+4) = 8 bytes: g = L>>1, half = (L&1)*8.
__global__ __launch_bounds__(256)
void filip_prep5(const float* __restrict__ t1, const float* __restrict__ t2,
                 float* __restrict__ inv1, float* __restrict__ inv2,
                 float* __restrict__ sim12,
                 char* __restrict__ t1fl, char* __restrict__ t2fl) {
    const int tid = threadIdx.x;
    if (blockIdx.x == 0) {
        float4 z = make_float4(0.f, 0.f, 0.f, 0.f);
        float4* s4 = reinterpret_cast<float4*>(sim12);
        #pragma unroll
        for (int j = 0; j < 4; ++j) s4[tid * 4 + j] = z;
    }
    int id = blockIdx.x * 4 + (tid >> 6);   // 0 .. NBP + NB*256 - 1
    int L = tid & 63;
    int g = L >> 1, h8 = (L & 1) * 8;
    if (id < NBP) {
        const float* src = t1 + (size_t)id * ND;
        float4 v = reinterpret_cast<const float4*>(src)[L];
        float ss = v.x * v.x + v.y * v.y + v.z * v.z + v.w * v.w;
        #pragma unroll
        for (int off = 32; off > 0; off >>= 1) ss += __shfl_xor(ss, off, 64);
        float inv = 1.0f / fmaxf(sqrtf(ss), 1e-12f);
        if (L == 0) inv1[id] = inv;
        v4bf o;
        o[0] = (__bf16)(v.x * inv); o[1] = (__bf16)(v.y * inv);
        o[2] = (__bf16)(v.z * inv); o[3] = (__bf16)(v.w * inv);
        int t = id >> 7, r = id & 127;
        char* dst = t1fl + (size_t)t * 65536 + g * 2048 + r * 16 + h8;
        *reinterpret_cast<v4bf*>(dst) = o;
    } else {
        int pid = id - NBP;          // 0..16383
        int b2 = pid >> 8, c = pid & 255;
        char* dst = t2fl + (size_t)b2 * 131072 + g * 4096 + c * 16 + h8;
        if (c < NP) {
            const float* src = t2 + (size_t)(b2 * NP + c) * ND;
            float4 v = reinterpret_cast<const float4*>(src)[L];
            float ss = v.x * v.x + v.y * v.y + v.z * v.z + v.w * v.w;
            #pragma unroll
            for (int off = 32; off > 0; off >>= 1) ss += __shfl_xor(ss, off, 64);
            float inv = 1.0f / fmaxf(sqrtf(ss), 1e-12f);
            if (L == 0) inv2[b2 * NP + c] = inv;
            v4bf o;
            o[0] = (__bf16)(v.x * inv); o[1] = (__bf16)(v.y * inv);
            o[2] = (__bf16)(v.z * inv); o[3] = (__bf16)(v.w * inv);
            *reinterpret_cast<v4bf*>(dst) = o;
        } else {
            v4bf z; z[0] = z[1] = z[2] = z[3] = (__bf16)0.0f;
            *reinterpret_cast<v4bf*>(dst) = z;
        }
    }
}

// Kernel 2: bf16 MFMA mean-of-rowmax, ZERO-LDS GEMM. Fragments loaded
// directly from fragment-linear global images (L1/L2-resident). No barriers
// in the K-loop; K-slice order identical to prior rounds -> bit-identical.
#define BM 128
#define BN 256

__global__ __launch_bounds__(256, 2)
void filip_mfma6(const char* __restrict__ t1fl, const char* __restrict__ t2fl,
                 float* __restrict__ sim12)
{
    __shared__ float rmx[2][BM];

    // XCD-aware bijection with A-tile reuse: XCD x = n&7 owns b2 in [8x,8x+8);
    // b2 varies innermost -> A-tile reused by 8 consecutive blocks; 8 B-panels
    // (1 MB) stay L2-resident per XCD.
    int n = blockIdx.x + 98 * blockIdx.y;   // 0..6271
    int x = n & 7, local = n >> 3;
    const int bRow = local >> 3;            // 0..97
    const int b2   = x * 8 + (local & 7);   // 0..63

    const int tid  = threadIdx.x;
    const int lane = tid & 63, wave = tid >> 6;
    const int wr = wave >> 1, wc = wave & 1;
    const int ln = lane & 31, hi = lane >> 5;

    // per-lane fragment base addresses (16B aligned)
    const char* Ap = t1fl + (size_t)bRow * 65536 + hi * 2048 + (wr * 64 + ln) * 16;
    const char* Bp = t2fl + (size_t)b2 * 131072 + hi * 4096 + (wc * 128 + ln) * 16;

    f32x16 acc[2][4];
    #pragma unroll
    for (int mt = 0; mt < 2; ++mt)
        #pragma unroll
        for (int nt = 0; nt < 4; ++nt)
            #pragma unroll
            for (int r = 0; r < 16; ++r) acc[mt][nt][r] = 0.0f;

    // 16 K-steps of K=16 (kk = kc*4+ks of prior rounds, same order).
    // Fully unrolled; no barriers -> compiler software-pipelines the loads.
    #pragma unroll
    for (int kk = 0; kk < 16; ++kk) {
        v8bf af[2], bfr[4];
        #pragma unroll
        for (int mt = 0; mt < 2; ++mt)
            af[mt] = *reinterpret_cast<const v8bf*>(Ap + kk * 4096 + mt * 512);
        #pragma unroll
        for (int nt = 0; nt < 4; ++nt)
            bfr[nt] = *reinterpret_cast<const v8bf*>(Bp + kk * 8192 + nt * 512);
        #pragma unroll
        for (int mt = 0; mt < 2; ++mt)
            #pragma unroll
            for (int nt = 0; nt < 4; ++nt)
                acc[mt][nt] = __builtin_amdgcn_mfma_f32_32x32x16_bf16(
                    af[mt], bfr[nt], acc[mt][nt], 0, 0, 0);
    }

    // fused rowmax; C/D layout: col = lane&31, row = (r&3) + 8*(r>>2) + 4*hi
    #pragma unroll
    for (int mt = 0; mt < 2; ++mt) {
        float t[16];
        #pragma unroll
        for (int r = 0; r < 16; ++r) {
            float m = fmaxf(fmaxf(acc[mt][0][r], acc[mt][1][r]),
                            fmaxf(acc[mt][2][r], acc[mt][3][r]));
            #pragma unroll
            for (int off = 1; off <= 16; off <<= 1)
                m = fmaxf(m, __shfl_xor(m, off, 64));
            t[r] = m;
        }
        if (ln == 0) {
            #pragma unroll
            for (int r = 0; r < 16; ++r) {
                int row = wr * 64 + mt * 32 + (r & 3) + 8 * (r >> 2) + 4 * hi;
                rmx[wc][row] = t[r];
            }
        }
    }
    __syncthreads();
    if (tid < BM) {
        float m = fmaxf(rmx[0][tid], rmx[1][tid]);
        int grow = bRow * BM + tid;
        int b1 = grow / NP;
        int fb = (bRow * BM) / NP;
        float v0 = (b1 == fb) ? m : 0.0f;
        float v1 = (b1 != fb) ? m : 0.0f;
        #pragma unroll
        for (int off = 1; off < 64; off <<= 1) {
            v0 += __shfl_xor(v0, off, 64);
            v1 += __shfl_xor(v1, off, 64);
        }
        if (lane == 0) {
            atomicAdd(&sim12[fb * NB + b2], v0);
            int lb = (bRow * BM + BM - 1) / NP;
            if (lb != fb) atomicAdd(&sim12[lb * NB + b2], v1);
        }
    }
}

// Kernel 3: fp32-exact diagonal blocks, 4 blocks per batch (49 rows each).
__global__ __launch_bounds__(256)
void filip_diag4(const float* __restrict__ t1, const float* __restrict__ t2,
                 const float* __restrict__ inv1, const float* __restrict__ inv2,
                 unsigned long long* __restrict__ parts,
                 float* __restrict__ out)
{
    const int q = blockIdx.x;          // 0..3 (row quarter)
    const int b = blockIdx.y;          // 0..63
    const int r0 = q * 49;
    const int tid = threadIdx.x;
    const int tx = tid & 15, ty = tid >> 4;

    __shared__ float smemF[2176 + 8320];       // As[32][68] + Bs[32][260]
    float* As = smemF;
    float* Bs = smemF + 2176;
    unsigned long long* colP = reinterpret_cast<unsigned long long*>(smemF); // reuse

    const float* Ap = t1 + (size_t)b * NP * ND;
    const float* Bp = t2 + (size_t)b * NP * ND;
    const float* ia = inv1 + b * NP;
    const float* ib = inv2 + b * NP;

    float acc[4][4][4];
    #pragma unroll
    for (int i = 0; i < 4; ++i)
        #pragma unroll
        for (int j = 0; j < 4; ++j)
            #pragma unroll
            for (int l = 0; l < 4; ++l) acc[i][j][l] = 0.0f;

    for (int kc = 0; kc < 8; ++kc) {
        __syncthreads();
        #pragma unroll
        for (int i = 0; i < 2; ++i) {
            int f4 = tid + 256 * i;            // 0..511
            int row = f4 >> 3, k4 = f4 & 7;
            float4 v = make_float4(0.f, 0.f, 0.f, 0.f);
            if (row < 49) {
                v = *reinterpret_cast<const float4*>(Ap + (size_t)(r0 + row) * ND + kc * 32 + 4 * k4);
                float s = ia[r0 + row];
                v.x *= s; v.y *= s; v.z *= s; v.w *= s;
            }
            As[(4 * k4 + 0) * 68 + row] = v.x;
            As[(4 * k4 + 1) * 68 + row] = v.y;
            As[(4 * k4 + 2) * 68 + row] = v.z;
            As[(4 * k4 + 3) * 68 + row] = v.w;
        }
        #pragma unroll
        for (int i = 0; i < 8; ++i) {
            int f4 = tid + 256 * i;            // 0..2047
            int col = f4 >> 3, k4 = f4 & 7;
            float4 v = make_float4(0.f, 0.f, 0.f, 0.f);
            if (col < NP) {
                v = *reinterpret_cast<const float4*>(Bp + (size_t)col * ND + kc * 32 + 4 * k4);
                float s = ib[col];
                v.x *= s; v.y *= s; v.z *= s; v.w *= s;
            }
            Bs[(4 * k4 + 0) * 260 + col] = v.x;
            Bs[(4 * k4 + 1) * 260 + col] = v.y;
            Bs[(4 * k4 + 2) * 260 + col] = v.z;
            Bs[(4 * k4 + 3) * 260 + col] = v.w;
        }
        __syncthreads();
        #pragma unroll 4
        for (int k = 0; k < 32; ++k) {
            float a0 = As[k * 68 + 4 * ty + 0];
            float a1 = As[k * 68 + 4 * ty + 1];
            float a2 = As[k * 68 + 4 * ty + 2];
            float a3 = As[k * 68 + 4 * ty + 3];
            float4 bq[4];
            #pragma unroll
            for (int j = 0; j < 4; ++j)
                bq[j] = *reinterpret_cast<const float4*>(&Bs[k * 260 + 4 * tx + 64 * j]);
            #pragma unroll
            for (int j = 0; j < 4; ++j) {
                acc[0][j][0] = fmaf(a0, bq[j].x, acc[0][j][0]);
                acc[0][j][1] = fmaf(a0, bq[j].y, acc[0][j][1]);
                acc[0][j][2] = fmaf(a0, bq[j].z, acc[0][j][2]);
                acc[0][j][3] = fmaf(a0, bq[j].w, acc[0][j][3]);
                acc[1][j][0] = fmaf(a1, bq[j].x, acc[1][j][0]);
                acc[1][j][1] = fmaf(a1, bq[j].y, acc[1][j][1]);
                acc[1][j][2] = fmaf(a1, bq[j].z, acc[1][j][2]);
                acc[1][j][3] = fmaf(a1, bq[j].w, acc[1][j][3]);
                acc[2][j][0] = fmaf(a2, bq[j].x, acc[2][j][0]);
                acc[2][j][1] = fmaf(a2, bq[j].y, acc[2][j][1]);
                acc[2][j][2] = fmaf(a2, bq[j].z, acc[2][j][2]);
                acc[2][j][3] = fmaf(a2, bq[j].w, acc[2][j][3]);
                acc[3][j][0] = fmaf(a3, bq[j].x, acc[3][j][0]);
                acc[3][j][1] = fmaf(a3, bq[j].y, acc[3][j][1]);
                acc[3][j][2] = fmaf(a3, bq[j].z, acc[3][j][2]);
                acc[3][j][3] = fmaf(a3, bq[j].w, acc[3][j][3]);
            }
        }
    }

    // row argmax (idx_to_keep1_2)
    #pragma unroll
    for (int i = 0; i < 4; ++i) {
        unsigned long long best = 0ull;
        #pragma unroll
        for (int j = 0; j < 4; ++j)
            #pragma unroll
            for (int l = 0; l < 4; ++l) {
                int c = 64 * j + 4 * tx + l;
                if (c < NP) {
                    unsigned long long p = packVI(acc[i][j][l], c);
                    if (p > best) best = p;
                }
            }
        #pragma unroll
        for (int off = 1; off < 16; off <<= 1) {
            unsigned long long o = __shfl_xor(best, off, 16);
            if (o > best) best = o;
        }
        int rl = 4 * ty + i;
        if (tx == 0 && rl < 49)
            out[1 + b * NP + r0 + rl] = (float)(unsigned int)(~best);
    }

    // col argmax partials (idx_to_keep2_1)
    __syncthreads();
    #pragma unroll
    for (int j = 0; j < 4; ++j)
        #pragma unroll
        for (int l = 0; l < 4; ++l) {
            unsigned long long best = 0ull;
            #pragma unroll
            for (int i = 0; i < 4; ++i) {
                int rl = 4 * ty + i;
                if (rl < 49) {
                    unsigned long long p = packVI(acc[i][j][l], r0 + rl);
                    if (p > best) best = p;
                }
            }
            colP[ty * 256 + 64 * j + 4 * tx + l] = best;
        }
    __syncthreads();
    {
        unsigned long long best = 0ull;
        #pragma unroll
        for (int y = 0; y < 16; ++y) {
            unsigned long long o = colP[y * 256 + tid];
            if (o > best) best = o;
        }
        if (tid < NP) parts[(b * 4 + q) * NP + tid] = best;
    }
}

// Kernel 4: merge the 4 quarter partials -> idx_to_keep2_1
__global__ void filip_fin(const unsigned long long* __restrict__ parts,
                          float* __restrict__ out) {
    int id = blockIdx.x * 256 + threadIdx.x;   // 49*256 = 12544
    int b = id / NP, c = id - b * NP;
    unsigned long long best = 0ull;
    #pragma unroll
    for (int qq = 0; qq < 4; ++qq) {
        unsigned long long o = parts[(b * 4 + qq) * NP + c];
        if (o > best) best = o;
    }
    out[1 + NBP + id] = (float)(unsigned int)(~best);
}

// Kernel 5: InfoNCE loss. sim12 holds SUMS of rowmax -> scale by 10/196.
__global__ void filip_loss(const float* __restrict__ sim12,
                           float* __restrict__ out) {
    int i = threadIdx.x;  // 0..63
    const float SC = 10.0f / 196.0f;
    const float* row = sim12 + i * NB;
    float mx = -3.0e38f;
    for (int j = 0; j < NB; ++j) mx = fmaxf(mx, row[j] * SC);
    float s = 0.0f;
    for (int j = 0; j < NB; ++j) s += expf(row[j] * SC - mx);
    float lse = mx + logf(s);
    float li = lse - row[i] * SC;
    #pragma unroll
    for (int off = 32; off > 0; off >>= 1)
        li += __shfl_xor(li, off, 64);
    if (i == 0) out[0] = li / 64.0f;
}

// ===========================================================================
// FALLBACK PATH (verbatim round-2, known-passing) — used if ws too small
// ===========================================================================
__global__ void filip_norms(const float* __restrict__ t1,
                            const float* __restrict__ t2,
                            float* __restrict__ inv1,
                            float* __restrict__ inv2,
                            float* __restrict__ sim12) {
    int row = blockIdx.x;
    int lane = threadIdx.x;
    if (row < NB) sim12[row * NB + lane] = 0.0f;
    const float* src; float* dst; int r;
    if (row < NBP) { src = t1; dst = inv1; r = row; }
    else           { src = t2; dst = inv2; r = row - NBP; }
    float4 v = reinterpret_cast<const float4*>(src + (size_t)r * ND)[lane];
    float ss = v.x * v.x + v.y * v.y + v.z * v.z + v.w * v.w;
    #pragma unroll
    for (int off = 32; off > 0; off >>= 1)
        ss += __shfl_xor(ss, off, 64);
    if (lane == 0)
        dst[r] = 1.0f / fmaxf(sqrtf(ss), 1e-12f);
}

__device__ __forceinline__ v8bf cvt8(float4 a, float4 b, float s) {
    v8bf v;
    v[0] = (__bf16)(a.x * s); v[1] = (__bf16)(a.y * s);
    v[2] = (__bf16)(a.z * s); v[3] = (__bf16)(a.w * s);
    v[4] = (__bf16)(b.x * s); v[5] = (__bf16)(b.y * s);
    v[6] = (__bf16)(b.z * s); v[7] = (__bf16)(b.w * s);
    return v;
}

#define BKF 64
__global__ __launch_bounds__(256, 2)
void filip_mfma(const float* __restrict__ t1, const float* __restrict__ t2,
                const float* __restrict__ inv1, const float* __restrict__ inv2,
                float* __restrict__ sim12)
{
    __shared__ unsigned short Asb[BM * BKF];
    __shared__ unsigned short Bsb[BN * BKF];
    __shared__ float rmx[2][BM];

    const int bRow = blockIdx.x;
    const int b2   = blockIdx.y;
    const int tid  = threadIdx.x;
    const int lane = tid & 63, wave = tid >> 6;
    const int wr = wave >> 1, wc = wave & 1;
    const int ln = lane & 31, hi = lane >> 5;

    const float* Abase = t1 + (size_t)bRow * BM * ND;
    const float* Bbase = t2 + (size_t)b2 * NP * ND;

    f32x16 acc[2][4];
    #pragma unroll
    for (int mt = 0; mt < 2; ++mt)
        #pragma unroll
        for (int nt = 0; nt < 4; ++nt)
            #pragma unroll
            for (int r = 0; r < 16; ++r) acc[mt][nt][r] = 0.0f;

    for (int kc = 0; kc < 4; ++kc) {
        __syncthreads();
        #pragma unroll
        for (int i = 0; i < 4; ++i) {
            int flat = (i * 256 + tid) * 8;
            int r = flat >> 6, k0 = flat & 63;
            const float* gp = Abase + (size_t)r * ND + kc * BKF + k0;
            float4 f0 = *reinterpret_cast<const float4*>(gp);
            float4 f1 = *reinterpret_cast<const float4*>(gp + 4);
            float s = inv1[bRow * BM + r];
            v8bf v = cvt8(f0, f1, s);
            int off = r * 128 + ((k0 * 2) ^ ((r & 7) << 4));
            *reinterpret_cast<v8bf*>(reinterpret_cast<char*>(Asb) + off) = v;
        }
        #pragma unroll
        for (int i = 0; i < 8; ++i) {
            int flat = (i * 256 + tid) * 8;
            int r = flat >> 6, k0 = flat & 63;
            v8bf v;
            if (r < NP) {
                const float* gp = Bbase + (size_t)r * ND + kc * BKF + k0;
                float4 f0 = *reinterpret_cast<const float4*>(gp);
                float4 f1 = *reinterpret_cast<const float4*>(gp + 4);
                float s = inv2[b2 * NP + r];
                v = cvt8(f0, f1, s);
            } else {
                #pragma unroll
                for (int j = 0; j < 8; ++j) v[j] = (__bf16)0.0f;
            }
            int off = r * 128 + ((k0 * 2) ^ ((r & 7) << 4));
            *reinterpret_cast<v8bf*>(reinterpret_cast<char*>(Bsb) + off) = v;
        }
        __syncthreads();
        #pragma unroll
        for (int ks = 0; ks < 4; ++ks) {
            const int kb = ks * 32 + hi * 16;
            v8bf af[2], bfr[4];
            #pragma unroll
            for (int mt = 0; mt < 2; ++mt) {
                int r = wr * 64 + mt * 32 + ln;
                af[mt] = *reinterpret_cast<const v8bf*>(
                    reinterpret_cast<const char*>(Asb) + r * 128 + (kb ^ ((r & 7) << 4)));
            }
            #pragma unroll
            for (int nt = 0; nt < 4; ++nt) {
                int c = wc * 128 + nt * 32 + ln;
                bfr[nt] = *reinterpret_cast<const v8bf*>(
                    reinterpret_cast<const char*>(Bsb) + c * 128 + (kb ^ ((c & 7) << 4)));
            }
            #pragma unroll
            for (int mt = 0; mt < 2; ++mt)
                #pragma unroll
                for (int nt = 0; nt < 4; ++nt)
                    acc[mt][nt] = __builtin_amdgcn_mfma_f32_32x32x16_bf16(
                        af[mt], bfr[nt], acc[mt][nt], 0, 0, 0);
        }
    }

    #pragma unroll
    for (int mt = 0; mt < 2; ++mt) {
        float t[16];
        #pragma unroll
        for (int r = 0; r < 16; ++r) {
            float m = fmaxf(fmaxf(acc[mt][0][r], acc[mt][1][r]),
                            fmaxf(acc[mt][2][r], acc[mt][3][r]));
            #pragma unroll
            for (int off = 1; off <= 16; off <<= 1)
                m = fmaxf(m, __shfl_xor(m, off, 64));
            t[r] = m;
        }
        if (ln == 0) {
            #pragma unroll
            for (int r = 0; r < 16; ++r) {
                int row = wr * 64 + mt * 32 + (r & 3) + 8 * (r >> 2) + 4 * hi;
                rmx[wc][row] = t[r];
            }
        }
    }
    __syncthreads();
    if (tid < BM) {
        float m = fmaxf(rmx[0][tid], rmx[1][tid]);
        int grow = bRow * BM + tid;
        int b1 = grow / NP;
        int fb = (bRow * BM) / NP;
        float v0 = (b1 == fb) ? m : 0.0f;
        float v1 = (b1 != fb) ? m : 0.0f;
        #pragma unroll
        for (int off = 1; off < 64; off <<= 1) {
            v0 += __shfl_xor(v0, off, 64);
            v1 += __shfl_xor(v1, off, 64);
        }
        if (lane == 0) {
            atomicAdd(&sim12[fb * NB + b2], v0);
            int lb = (bRow * BM + BM - 1) / NP;
            if (lb != fb) atomicAdd(&sim12[lb * NB + b2], v1);
        }
    }
}

__global__ __launch_bounds__(256)
void filip_diag(const float* __restrict__ t1, const float* __restrict__ t2,
                const float* __restrict__ inv1, const float* __restrict__ inv2,
                float* __restrict__ out)
{
    const int b = blockIdx.x;
    const int tid = threadIdx.x;
    const int tx = tid & 15, ty = tid >> 4;

    __shared__ float As2[16][209];
    __shared__ float Bs2[16][65];
    __shared__ float colV[16][65];
    __shared__ int   colI[16][65];

    const float* Ap = t1 + (size_t)b * NP * ND;
    const float* Bp = t2 + (size_t)b * NP * ND;
    const float* ia = inv1 + b * NP;
    const float* ib = inv2 + b * NP;

    float rmax[13];
    int   ridx[13];
    #pragma unroll
    for (int m = 0; m < 13; ++m) { rmax[m] = -3.0e38f; ridx[m] = 1 << 30; }

    for (int tile = 0; tile < 4; ++tile) {
        float acc[13][4];
        #pragma unroll
        for (int m = 0; m < 13; ++m)
            #pragma unroll
            for (int n = 0; n < 4; ++n) acc[m][n] = 0.0f;

        for (int kk = 0; kk < 16; ++kk) {
            __syncthreads();
            #pragma unroll
            for (int i = 0; i < 13; ++i) {
                int e = tid + 256 * i;
                int p1 = e >> 4, k = e & 15;
                float v = 0.0f;
                if (p1 < NP) v = Ap[p1 * ND + kk * 16 + k] * ia[p1];
                As2[k][p1] = v;
            }
            #pragma unroll
            for (int i = 0; i < 4; ++i) {
                int e = tid + 256 * i;
                int pl = e >> 4, k = e & 15;
                int p2 = tile * 64 + pl;
                float v = 0.0f;
                if (p2 < NP) v = Bp[p2 * ND + kk * 16 + k] * ib[p2];
                Bs2[k][pl] = v;
            }
            __syncthreads();
            #pragma unroll 4
            for (int k = 0; k < 16; ++k) {
                float a[13], bq[4];
                #pragma unroll
                for (int m = 0; m < 13; ++m) a[m] = As2[k][ty + 16 * m];
                #pragma unroll
                for (int n = 0; n < 4; ++n) bq[n] = Bs2[k][tx + 16 * n];
                #pragma unroll
                for (int m = 0; m < 13; ++m)
                    #pragma unroll
                    for (int n = 0; n < 4; ++n)
                        acc[m][n] = fmaf(a[m], bq[n], acc[m][n]);
            }
        }

        #pragma unroll
        for (int n = 0; n < 4; ++n) {
            int c = tile * 64 + tx + 16 * n;
            if (c < NP) {
                #pragma unroll
                for (int m = 0; m < 13; ++m) {
                    float v = acc[m][n];
                    if (v > rmax[m] || (v == rmax[m] && c < ridx[m])) {
                        rmax[m] = v; ridx[m] = c;
                    }
                }
            }
        }

        #pragma unroll
        for (int n = 0; n < 4; ++n) {
            float bv = -3.0e38f; int bi = 1 << 30;
            #pragma unroll
            for (int m = 0; m < 13; ++m) {
                int row = ty + 16 * m;
                if (row < NP) {
                    float v = acc[m][n];
                    if (v > bv || (v == bv && row < bi)) { bv = v; bi = row; }
                }
            }
            colV[ty][tx + 16 * n] = bv;
            colI[ty][tx + 16 * n] = bi;
        }
        __syncthreads();
        if (tid < 64) {
            int c = tile * 64 + tid;
            if (c < NP) {
                float bv = -3.0e38f; int bi = 1 << 30;
                #pragma unroll
                for (int y = 0; y < 16; ++y) {
                    float v = colV[y][tid]; int i2 = colI[y][tid];
                    if (v > bv || (v == bv && i2 < bi)) { bv = v; bi = i2; }
                }
                out[1 + NBP + b * NP + c] = (float)bi;
            }
        }
        __syncthreads();
    }

    #pragma unroll
    for (int m = 0; m < 13; ++m) {
        float v = rmax[m]; int ix = ridx[m];
        #pragma unroll
        for (int off = 1; off < 16; off <<= 1) {
            float ov = __shfl_xor(v, off, 16);
            int   oi = __shfl_xor(ix, off, 16);
            if (ov > v || (ov == v && oi < ix)) { v = ov; ix = oi; }
        }
        rmax[m] = v; ridx[m] = ix;
    }
    if (tx == 0) {
        #pragma unroll
        for (int m = 0; m < 13; ++m) {
            int row = ty + 16 * m;
            if (row < NP) out[1 + b * NP + row] = (float)ridx[m];
        }
    }
}

// ---------------------------------------------------------------------------
extern "C" void kernel_launch(void* const* d_in, const int* in_sizes, int n_in,
                              void* d_out, int out_size, void* d_ws, size_t ws_size,
                              hipStream_t stream) {
    const float* t1 = (const float*)d_in[0];
    const float* t2 = (const float*)d_in[1];
    float* out = (float*)d_out;
    float* ws  = (float*)d_ws;

    float* inv1  = ws;
    float* inv2  = ws + NBP;
    float* sim12 = ws + 2 * NBP;

    if (ws_size >= (size_t)WS_NEED) {
        char* t1fl = (char*)d_ws + WS_T1FL;
        char* t2fl = (char*)d_ws + WS_T2FL;
        unsigned long long* parts = (unsigned long long*)((char*)d_ws + WS_PARTS);

        filip_prep5<<<(NBP + NB * 256) / 4, 256, 0, stream>>>(t1, t2, inv1, inv2, sim12, t1fl, t2fl);
        filip_mfma6<<<dim3(98, NB), 256, 0, stream>>>(t1fl, t2fl, sim12);
        filip_diag4<<<dim3(4, NB), 256, 0, stream>>>(t1, t2, inv1, inv2, parts, out);
        filip_fin<<<49, 256, 0, stream>>>(parts, out);
        filip_loss<<<1, 64, 0, stream>>>(sim12, out);
    } else {
        filip_norms<<<2 * NBP, 64, 0, stream>>>(t1, t2, inv1, inv2, sim12);
        filip_mfma<<<dim3(98, NB), 256, 0, stream>>>(t1, t2, inv1, inv2, sim12);
        filip_diag<<<NB, 256, 0, stream>>>(t1, t2, inv1, inv2, out);
        filip_loss<<<1, 64, 0, stream>>>(sim12, out);
    }
}

// Round 8
// 188.251 us; speedup vs baseline: 1.9830x; 1.0784x over previous
//
#include <hip/hip_runtime.h>
#include <math.h>

#define NB 64
#define NP 196
#define ND 256
#define NBP (NB * NP)   // 12544

typedef __bf16 v8bf __attribute__((ext_vector_type(8)));
typedef __bf16 v4bf __attribute__((ext_vector_type(4)));
typedef float f32x16 __attribute__((ext_vector_type(16)));

// ws layout (fast path), bytes:
//   inv1   @ 0          : 12544 f32
//   inv2   @ 50176      : 12544 f32
//   sim12  @ 100352     : 4096  f32
//   t1fl   @ 116736     : 98 tiles x fragment-linear (32 kgroups x 128 rows x 16B) = 6422528 B
//   t2fl   @ 6539264    : 64 panels x fragment-linear (32 kgroups x 256 cols x 16B; cols 196..255 zero) = 8388608 B
//   parts  @ 14927872   : 64*4*196 u64 = 401408 B
#define WS_T1FL   116736
#define WS_T2FL   6539264
#define WS_PARTS  14927872
#define WS_NEED   15329280

// ---------------------------------------------------------------------------
// packed (value,index) for argmax with np first-occurrence tie-break
// ---------------------------------------------------------------------------
__device__ __forceinline__ unsigned int fmono(float v) {
    unsigned int u = __float_as_uint(v);
    return (u & 0x80000000u) ? ~u : (u | 0x80000000u);
}
__device__ __forceinline__ unsigned long long packVI(float v, int idx) {
    return ((unsigned long long)fmono(v) << 32) | (unsigned int)(~idx);
}

// ===========================================================================
// FAST PATH
// ===========================================================================

// Kernel 1: per-row norm -> inv arrays; write normalized bf16 in
// FRAGMENT-LINEAR layout (zero-LDS GEMM reads fragments as contiguous 512B
// runs). Lane L holds k-elems [4L,4L+4): g = L>>1, half = (L&1)*8.
__global__ __launch_bounds__(256)
void filip_prep5(const float* __restrict__ t1, const float* __restrict__ t2,
                 float* __restrict__ inv1, float* __restrict__ inv2,
                 float* __restrict__ sim12,
                 char* __restrict__ t1fl, char* __restrict__ t2fl) {
    const int tid = threadIdx.x;
    if (blockIdx.x == 0) {
        float4 z = make_float4(0.f, 0.f, 0.f, 0.f);
        float4* s4 = reinterpret_cast<float4*>(sim12);
        #pragma unroll
        for (int j = 0; j < 4; ++j) s4[tid * 4 + j] = z;
    }
    int id = blockIdx.x * 4 + (tid >> 6);   // 0 .. NBP + NB*256 - 1
    int L = tid & 63;
    int g = L >> 1, h8 = (L & 1) * 8;
    if (id < NBP) {
        const float* src = t1 + (size_t)id * ND;
        float4 v = reinterpret_cast<const float4*>(src)[L];
        float ss = v.x * v.x + v.y * v.y + v.z * v.z + v.w * v.w;
        #pragma unroll
        for (int off = 32; off > 0; off >>= 1) ss += __shfl_xor(ss, off, 64);
        float inv = 1.0f / fmaxf(sqrtf(ss), 1e-12f);
        if (L == 0) inv1[id] = inv;
        v4bf o;
        o[0] = (__bf16)(v.x * inv); o[1] = (__bf16)(v.y * inv);
        o[2] = (__bf16)(v.z * inv); o[3] = (__bf16)(v.w * inv);
        int t = id >> 7, r = id & 127;
        char* dst = t1fl + (size_t)t * 65536 + g * 2048 + r * 16 + h8;
        *reinterpret_cast<v4bf*>(dst) = o;
    } else {
        int pid = id - NBP;          // 0..16383
        int b2 = pid >> 8, c = pid & 255;
        char* dst = t2fl + (size_t)b2 * 131072 + g * 4096 + c * 16 + h8;
        if (c < NP) {
            const float* src = t2 + (size_t)(b2 * NP + c) * ND;
            float4 v = reinterpret_cast<const float4*>(src)[L];
            float ss = v.x * v.x + v.y * v.y + v.z * v.z + v.w * v.w;
            #pragma unroll
            for (int off = 32; off > 0; off >>= 1) ss += __shfl_xor(ss, off, 64);
            float inv = 1.0f / fmaxf(sqrtf(ss), 1e-12f);
            if (L == 0) inv2[b2 * NP + c] = inv;
            v4bf o;
            o[0] = (__bf16)(v.x * inv); o[1] = (__bf16)(v.y * inv);
            o[2] = (__bf16)(v.z * inv); o[3] = (__bf16)(v.w * inv);
            *reinterpret_cast<v4bf*>(dst) = o;
        } else {
            v4bf z; z[0] = z[1] = z[2] = z[3] = (__bf16)0.0f;
            *reinterpret_cast<v4bf*>(dst) = z;
        }
    }
}

// Kernel 2: zero-LDS MFMA mean-of-rowmax. launch_bounds(256,3) caps total
// regs at ~170/thread (128 AGPR acc + ~42 arch) -> 3 blocks/CU for TLP
// latency hiding. K-loop NOT unrolled: pointer-walk addressing (imm offsets
// 0/512/1024/1536), single fragment set. MFMA order identical to round 7.
#define BM 128
#define BN 256

__global__ __launch_bounds__(256, 3)
void filip_mfma7(const char* __restrict__ t1fl, const char* __restrict__ t2fl,
                 float* __restrict__ sim12)
{
    __shared__ float rmx[2][BM];

    // XCD-aware bijection with A-tile reuse: XCD x = n&7 owns b2 in [8x,8x+8);
    // b2 varies innermost -> A-tile reused by 8 consecutive blocks; 8 B-panels
    // (1 MB) stay L2-resident per XCD.
    int n = blockIdx.x + 98 * blockIdx.y;   // 0..6271
    int x = n & 7, local = n >> 3;
    const int bRow = local >> 3;            // 0..97
    const int b2   = x * 8 + (local & 7);   // 0..63

    const int tid  = threadIdx.x;
    const int lane = tid & 63, wave = tid >> 6;
    const int wr = wave >> 1, wc = wave & 1;
    const int ln = lane & 31, hi = lane >> 5;

    // per-lane fragment base addresses (16B aligned), walked by the K-loop
    const char* Ap = t1fl + (size_t)bRow * 65536 + hi * 2048 + (wr * 64 + ln) * 16;
    const char* Bp = t2fl + (size_t)b2 * 131072 + hi * 4096 + (wc * 128 + ln) * 16;

    f32x16 acc[2][4];
    #pragma unroll
    for (int mt = 0; mt < 2; ++mt)
        #pragma unroll
        for (int nt = 0; nt < 4; ++nt)
            #pragma unroll
            for (int r = 0; r < 16; ++r) acc[mt][nt][r] = 0.0f;

    // 16 K-steps of K=16; same kk order as all prior rounds -> bit-identical.
    #pragma unroll 1
    for (int kk = 0; kk < 16; ++kk) {
        v8bf af0 = *reinterpret_cast<const v8bf*>(Ap);
        v8bf af1 = *reinterpret_cast<const v8bf*>(Ap + 512);
        v8bf bf0 = *reinterpret_cast<const v8bf*>(Bp);
        v8bf bf1 = *reinterpret_cast<const v8bf*>(Bp + 512);
        v8bf bf2 = *reinterpret_cast<const v8bf*>(Bp + 1024);
        v8bf bf3 = *reinterpret_cast<const v8bf*>(Bp + 1536);
        acc[0][0] = __builtin_amdgcn_mfma_f32_32x32x16_bf16(af0, bf0, acc[0][0], 0, 0, 0);
        acc[0][1] = __builtin_amdgcn_mfma_f32_32x32x16_bf16(af0, bf1, acc[0][1], 0, 0, 0);
        acc[0][2] = __builtin_amdgcn_mfma_f32_32x32x16_bf16(af0, bf2, acc[0][2], 0, 0, 0);
        acc[0][3] = __builtin_amdgcn_mfma_f32_32x32x16_bf16(af0, bf3, acc[0][3], 0, 0, 0);
        acc[1][0] = __builtin_amdgcn_mfma_f32_32x32x16_bf16(af1, bf0, acc[1][0], 0, 0, 0);
        acc[1][1] = __builtin_amdgcn_mfma_f32_32x32x16_bf16(af1, bf1, acc[1][1], 0, 0, 0);
        acc[1][2] = __builtin_amdgcn_mfma_f32_32x32x16_bf16(af1, bf2, acc[1][2], 0, 0, 0);
        acc[1][3] = __builtin_amdgcn_mfma_f32_32x32x16_bf16(af1, bf3, acc[1][3], 0, 0, 0);
        Ap += 4096;
        Bp += 8192;
    }

    // fused rowmax; C/D layout: col = lane&31, row = (r&3) + 8*(r>>2) + 4*hi
    #pragma unroll
    for (int mt = 0; mt < 2; ++mt) {
        float t[16];
        #pragma unroll
        for (int r = 0; r < 16; ++r) {
            float m = fmaxf(fmaxf(acc[mt][0][r], acc[mt][1][r]),
                            fmaxf(acc[mt][2][r], acc[mt][3][r]));
            #pragma unroll
            for (int off = 1; off <= 16; off <<= 1)
                m = fmaxf(m, __shfl_xor(m, off, 64));
            t[r] = m;
        }
        if (ln == 0) {
            #pragma unroll
            for (int r = 0; r < 16; ++r) {
                int row = wr * 64 + mt * 32 + (r & 3) + 8 * (r >> 2) + 4 * hi;
                rmx[wc][row] = t[r];
            }
        }
    }
    __syncthreads();
    if (tid < BM) {
        float m = fmaxf(rmx[0][tid], rmx[1][tid]);
        int grow = bRow * BM + tid;
        int b1 = grow / NP;
        int fb = (bRow * BM) / NP;
        float v0 = (b1 == fb) ? m : 0.0f;
        float v1 = (b1 != fb) ? m : 0.0f;
        #pragma unroll
        for (int off = 1; off < 64; off <<= 1) {
            v0 += __shfl_xor(v0, off, 64);
            v1 += __shfl_xor(v1, off, 64);
        }
        if (lane == 0) {
            atomicAdd(&sim12[fb * NB + b2], v0);
            int lb = (bRow * BM + BM - 1) / NP;
            if (lb != fb) atomicAdd(&sim12[lb * NB + b2], v1);
        }
    }
}

// Kernel 3: fp32-exact diagonal blocks, 4 blocks per batch (49 rows each).
__global__ __launch_bounds__(256)
void filip_diag4(const float* __restrict__ t1, const float* __restrict__ t2,
                 const float* __restrict__ inv1, const float* __restrict__ inv2,
                 unsigned long long* __restrict__ parts,
                 float* __restrict__ out)
{
    const int q = blockIdx.x;          // 0..3 (row quarter)
    const int b = blockIdx.y;          // 0..63
    const int r0 = q * 49;
    const int tid = threadIdx.x;
    const int tx = tid & 15, ty = tid >> 4;

    __shared__ float smemF[2176 + 8320];       // As[32][68] + Bs[32][260]
    float* As = smemF;
    float* Bs = smemF + 2176;
    unsigned long long* colP = reinterpret_cast<unsigned long long*>(smemF); // reuse

    const float* Ap = t1 + (size_t)b * NP * ND;
    const float* Bp = t2 + (size_t)b * NP * ND;
    const float* ia = inv1 + b * NP;
    const float* ib = inv2 + b * NP;

    float acc[4][4][4];
    #pragma unroll
    for (int i = 0; i < 4; ++i)
        #pragma unroll
        for (int j = 0; j < 4; ++j)
            #pragma unroll
            for (int l = 0; l < 4; ++l) acc[i][j][l] = 0.0f;

    for (int kc = 0; kc < 8; ++kc) {
        __syncthreads();
        #pragma unroll
        for (int i = 0; i < 2; ++i) {
            int f4 = tid + 256 * i;            // 0..511
            int row = f4 >> 3, k4 = f4 & 7;
            float4 v = make_float4(0.f, 0.f, 0.f, 0.f);
            if (row < 49) {
                v = *reinterpret_cast<const float4*>(Ap + (size_t)(r0 + row) * ND + kc * 32 + 4 * k4);
                float s = ia[r0 + row];
                v.x *= s; v.y *= s; v.z *= s; v.w *= s;
            }
            As[(4 * k4 + 0) * 68 + row] = v.x;
            As[(4 * k4 + 1) * 68 + row] = v.y;
            As[(4 * k4 + 2) * 68 + row] = v.z;
            As[(4 * k4 + 3) * 68 + row] = v.w;
        }
        #pragma unroll
        for (int i = 0; i < 8; ++i) {
            int f4 = tid + 256 * i;            // 0..2047
            int col = f4 >> 3, k4 = f4 & 7;
            float4 v = make_float4(0.f, 0.f, 0.f, 0.f);
            if (col < NP) {
                v = *reinterpret_cast<const float4*>(Bp + (size_t)col * ND + kc * 32 + 4 * k4);
                float s = ib[col];
                v.x *= s; v.y *= s; v.z *= s; v.w *= s;
            }
            Bs[(4 * k4 + 0) * 260 + col] = v.x;
            Bs[(4 * k4 + 1) * 260 + col] = v.y;
            Bs[(4 * k4 + 2) * 260 + col] = v.z;
            Bs[(4 * k4 + 3) * 260 + col] = v.w;
        }
        __syncthreads();
        #pragma unroll 4
        for (int k = 0; k < 32; ++k) {
            float a0 = As[k * 68 + 4 * ty + 0];
            float a1 = As[k * 68 + 4 * ty + 1];
            float a2 = As[k * 68 + 4 * ty + 2];
            float a3 = As[k * 68 + 4 * ty + 3];
            float4 bq[4];
            #pragma unroll
            for (int j = 0; j < 4; ++j)
                bq[j] = *reinterpret_cast<const float4*>(&Bs[k * 260 + 4 * tx + 64 * j]);
            #pragma unroll
            for (int j = 0; j < 4; ++j) {
                acc[0][j][0] = fmaf(a0, bq[j].x, acc[0][j][0]);
                acc[0][j][1] = fmaf(a0, bq[j].y, acc[0][j][1]);
                acc[0][j][2] = fmaf(a0, bq[j].z, acc[0][j][2]);
                acc[0][j][3] = fmaf(a0, bq[j].w, acc[0][j][3]);
                acc[1][j][0] = fmaf(a1, bq[j].x, acc[1][j][0]);
                acc[1][j][1] = fmaf(a1, bq[j].y, acc[1][j][1]);
                acc[1][j][2] = fmaf(a1, bq[j].z, acc[1][j][2]);
                acc[1][j][3] = fmaf(a1, bq[j].w, acc[1][j][3]);
                acc[2][j][0] = fmaf(a2, bq[j].x, acc[2][j][0]);
                acc[2][j][1] = fmaf(a2, bq[j].y, acc[2][j][1]);
                acc[2][j][2] = fmaf(a2, bq[j].z, acc[2][j][2]);
                acc[2][j][3] = fmaf(a2, bq[j].w, acc[2][j][3]);
                acc[3][j][0] = fmaf(a3, bq[j].x, acc[3][j][0]);
                acc[3][j][1] = fmaf(a3, bq[j].y, acc[3][j][1]);
                acc[3][j][2] = fmaf(a3, bq[j].z, acc[3][j][2]);
                acc[3][j][3] = fmaf(a3, bq[j].w, acc[3][j][3]);
            }
        }
    }

    // row argmax (idx_to_keep1_2)
    #pragma unroll
    for (int i = 0; i < 4; ++i) {
        unsigned long long best = 0ull;
        #pragma unroll
        for (int j = 0; j < 4; ++j)
            #pragma unroll
            for (int l = 0; l < 4; ++l) {
                int c = 64 * j + 4 * tx + l;
                if (c < NP) {
                    unsigned long long p = packVI(acc[i][j][l], c);
                    if (p > best) best = p;
                }
            }
        #pragma unroll
        for (int off = 1; off < 16; off <<= 1) {
            unsigned long long o = __shfl_xor(best, off, 16);
            if (o > best) best = o;
        }
        int rl = 4 * ty + i;
        if (tx == 0 && rl < 49)
            out[1 + b * NP + r0 + rl] = (float)(unsigned int)(~best);
    }

    // col argmax partials (idx_to_keep2_1)
    __syncthreads();
    #pragma unroll
    for (int j = 0; j < 4; ++j)
        #pragma unroll
        for (int l = 0; l < 4; ++l) {
            unsigned long long best = 0ull;
            #pragma unroll
            for (int i = 0; i < 4; ++i) {
                int rl = 4 * ty + i;
                if (rl < 49) {
                    unsigned long long p = packVI(acc[i][j][l], r0 + rl);
                    if (p > best) best = p;
                }
            }
            colP[ty * 256 + 64 * j + 4 * tx + l] = best;
        }
    __syncthreads();
    {
        unsigned long long best = 0ull;
        #pragma unroll
        for (int y = 0; y < 16; ++y) {
            unsigned long long o = colP[y * 256 + tid];
            if (o > best) best = o;
        }
        if (tid < NP) parts[(b * 4 + q) * NP + tid] = best;
    }
}

// Kernel 4: merged fin (blocks 0..48) + loss (block 49).
__global__ void filip_finloss(const unsigned long long* __restrict__ parts,
                              const float* __restrict__ sim12,
                              float* __restrict__ out) {
    if (blockIdx.x < 49) {
        int id = blockIdx.x * 256 + threadIdx.x;   // 49*256 = 12544
        int b = id / NP, c = id - b * NP;
        unsigned long long best = 0ull;
        #pragma unroll
        for (int qq = 0; qq < 4; ++qq) {
            unsigned long long o = parts[(b * 4 + qq) * NP + c];
            if (o > best) best = o;
        }
        out[1 + NBP + id] = (float)(unsigned int)(~best);
    } else if (threadIdx.x < 64) {
        int i = threadIdx.x;  // 0..63
        const float SC = 10.0f / 196.0f;
        const float* row = sim12 + i * NB;
        float mx = -3.0e38f;
        for (int j = 0; j < NB; ++j) mx = fmaxf(mx, row[j] * SC);
        float s = 0.0f;
        for (int j = 0; j < NB; ++j) s += expf(row[j] * SC - mx);
        float lse = mx + logf(s);
        float li = lse - row[i] * SC;
        #pragma unroll
        for (int off = 32; off > 0; off >>= 1)
            li += __shfl_xor(li, off, 64);
        if (i == 0) out[0] = li / 64.0f;
    }
}

// ===========================================================================
// FALLBACK PATH (verbatim round-2, known-passing) — used if ws too small
// ===========================================================================
__global__ void filip_norms(const float* __restrict__ t1,
                            const float* __restrict__ t2,
                            float* __restrict__ inv1,
                            float* __restrict__ inv2,
                            float* __restrict__ sim12) {
    int row = blockIdx.x;
    int lane = threadIdx.x;
    if (row < NB) sim12[row * NB + lane] = 0.0f;
    const float* src; float* dst; int r;
    if (row < NBP) { src = t1; dst = inv1; r = row; }
    else           { src = t2; dst = inv2; r = row - NBP; }
    float4 v = reinterpret_cast<const float4*>(src + (size_t)r * ND)[lane];
    float ss = v.x * v.x + v.y * v.y + v.z * v.z + v.w * v.w;
    #pragma unroll
    for (int off = 32; off > 0; off >>= 1)
        ss += __shfl_xor(ss, off, 64);
    if (lane == 0)
        dst[r] = 1.0f / fmaxf(sqrtf(ss), 1e-12f);
}

__device__ __forceinline__ v8bf cvt8(float4 a, float4 b, float s) {
    v8bf v;
    v[0] = (__bf16)(a.x * s); v[1] = (__bf16)(a.y * s);
    v[2] = (__bf16)(a.z * s); v[3] = (__bf16)(a.w * s);
    v[4] = (__bf16)(b.x * s); v[5] = (__bf16)(b.y * s);
    v[6] = (__bf16)(b.z * s); v[7] = (__bf16)(b.w * s);
    return v;
}

#define BKF 64
__global__ __launch_bounds__(256, 2)
void filip_mfma(const float* __restrict__ t1, const float* __restrict__ t2,
                const float* __restrict__ inv1, const float* __restrict__ inv2,
                float* __restrict__ sim12)
{
    __shared__ unsigned short Asb[BM * BKF];
    __shared__ unsigned short Bsb[BN * BKF];
    __shared__ float rmx[2][BM];

    const int bRow = blockIdx.x;
    const int b2   = blockIdx.y;
    const int tid  = threadIdx.x;
    const int lane = tid & 63, wave = tid >> 6;
    const int wr = wave >> 1, wc = wave & 1;
    const int ln = lane & 31, hi = lane >> 5;

    const float* Abase = t1 + (size_t)bRow * BM * ND;
    const float* Bbase = t2 + (size_t)b2 * NP * ND;

    f32x16 acc[2][4];
    #pragma unroll
    for (int mt = 0; mt < 2; ++mt)
        #pragma unroll
        for (int nt = 0; nt < 4; ++nt)
            #pragma unroll
            for (int r = 0; r < 16; ++r) acc[mt][nt][r] = 0.0f;

    for (int kc = 0; kc < 4; ++kc) {
        __syncthreads();
        #pragma unroll
        for (int i = 0; i < 4; ++i) {
            int flat = (i * 256 + tid) * 8;
            int r = flat >> 6, k0 = flat & 63;
            const float* gp = Abase + (size_t)r * ND + kc * BKF + k0;
            float4 f0 = *reinterpret_cast<const float4*>(gp);
            float4 f1 = *reinterpret_cast<const float4*>(gp + 4);
            float s = inv1[bRow * BM + r];
            v8bf v = cvt8(f0, f1, s);
            int off = r * 128 + ((k0 * 2) ^ ((r & 7) << 4));
            *reinterpret_cast<v8bf*>(reinterpret_cast<char*>(Asb) + off) = v;
        }
        #pragma unroll
        for (int i = 0; i < 8; ++i) {
            int flat = (i * 256 + tid) * 8;
            int r = flat >> 6, k0 = flat & 63;
            v8bf v;
            if (r < NP) {
                const float* gp = Bbase + (size_t)r * ND + kc * BKF + k0;
                float4 f0 = *reinterpret_cast<const float4*>(gp);
                float4 f1 = *reinterpret_cast<const float4*>(gp + 4);
                float s = inv2[b2 * NP + r];
                v = cvt8(f0, f1, s);
            } else {
                #pragma unroll
                for (int j = 0; j < 8; ++j) v[j] = (__bf16)0.0f;
            }
            int off = r * 128 + ((k0 * 2) ^ ((r & 7) << 4));
            *reinterpret_cast<v8bf*>(reinterpret_cast<char*>(Bsb) + off) = v;
        }
        __syncthreads();
        #pragma unroll
        for (int ks = 0; ks < 4; ++ks) {
            const int kb = ks * 32 + hi * 16;
            v8bf af[2], bfr[4];
            #pragma unroll
            for (int mt = 0; mt < 2; ++mt) {
                int r = wr * 64 + mt * 32 + ln;
                af[mt] = *reinterpret_cast<const v8bf*>(
                    reinterpret_cast<const char*>(Asb) + r * 128 + (kb ^ ((r & 7) << 4)));
            }
            #pragma unroll
            for (int nt = 0; nt < 4; ++nt) {
                int c = wc * 128 + nt * 32 + ln;
                bfr[nt] = *reinterpret_cast<const v8bf*>(
                    reinterpret_cast<const char*>(Bsb) + c * 128 + (kb ^ ((c & 7) << 4)));
            }
            #pragma unroll
            for (int mt = 0; mt < 2; ++mt)
                #pragma unroll
                for (int nt = 0; nt < 4; ++nt)
                    acc[mt][nt] = __builtin_amdgcn_mfma_f32_32x32x16_bf16(
                        af[mt], bfr[nt], acc[mt][nt], 0, 0, 0);
        }
    }

    #pragma unroll
    for (int mt = 0; mt < 2; ++mt) {
        float t[16];
        #pragma unroll
        for (int r = 0; r < 16; ++r) {
            float m = fmaxf(fmaxf(acc[mt][0][r], acc[mt][1][r]),
                            fmaxf(acc[mt][2][r], acc[mt][3][r]));
            #pragma unroll
            for (int off = 1; off <= 16; off <<= 1)
                m = fmaxf(m, __shfl_xor(m, off, 64));
            t[r] = m;
        }
        if (ln == 0) {
            #pragma unroll
            for (int r = 0; r < 16; ++r) {
                int row = wr * 64 + mt * 32 + (r & 3) + 8 * (r >> 2) + 4 * hi;
                rmx[wc][row] = t[r];
            }
        }
    }
    __syncthreads();
    if (tid < BM) {
        float m = fmaxf(rmx[0][tid], rmx[1][tid]);
        int grow = bRow * BM + tid;
        int b1 = grow / NP;
        int fb = (bRow * BM) / NP;
        float v0 = (b1 == fb) ? m : 0.0f;
        float v1 = (b1 != fb) ? m : 0.0f;
        #pragma unroll
        for (int off = 1; off < 64; off <<= 1) {
            v0 += __shfl_xor(v0, off, 64);
            v1 += __shfl_xor(v1, off, 64);
        }
        if (lane == 0) {
            atomicAdd(&sim12[fb * NB + b2], v0);
            int lb = (bRow * BM + BM - 1) / NP;
            if (lb != fb) atomicAdd(&sim12[lb * NB + b2], v1);
        }
    }
}

__global__ __launch_bounds__(256)
void filip_diag(const float* __restrict__ t1, const float* __restrict__ t2,
                const float* __restrict__ inv1, const float* __restrict__ inv2,
                float* __restrict__ out)
{
    const int b = blockIdx.x;
    const int tid = threadIdx.x;
    const int tx = tid & 15, ty = tid >> 4;

    __shared__ float As2[16][209];
    __shared__ float Bs2[16][65];
    __shared__ float colV[16][65];
    __shared__ int   colI[16][65];

    const float* Ap = t1 + (size_t)b * NP * ND;
    const float* Bp = t2 + (size_t)b * NP * ND;
    const float* ia = inv1 + b * NP;
    const float* ib = inv2 + b * NP;

    float rmax[13];
    int   ridx[13];
    #pragma unroll
    for (int m = 0; m < 13; ++m) { rmax[m] = -3.0e38f; ridx[m] = 1 << 30; }

    for (int tile = 0; tile < 4; ++tile) {
        float acc[13][4];
        #pragma unroll
        for (int m = 0; m < 13; ++m)
            #pragma unroll
            for (int n = 0; n < 4; ++n) acc[m][n] = 0.0f;

        for (int kk = 0; kk < 16; ++kk) {
            __syncthreads();
            #pragma unroll
            for (int i = 0; i < 13; ++i) {
                int e = tid + 256 * i;
                int p1 = e >> 4, k = e & 15;
                float v = 0.0f;
                if (p1 < NP) v = Ap[p1 * ND + kk * 16 + k] * ia[p1];
                As2[k][p1] = v;
            }
            #pragma unroll
            for (int i = 0; i < 4; ++i) {
                int e = tid + 256 * i;
                int pl = e >> 4, k = e & 15;
                int p2 = tile * 64 + pl;
                float v = 0.0f;
                if (p2 < NP) v = Bp[p2 * ND + kk * 16 + k] * ib[p2];
                Bs2[k][pl] = v;
            }
            __syncthreads();
            #pragma unroll 4
            for (int k = 0; k < 16; ++k) {
                float a[13], bq[4];
                #pragma unroll
                for (int m = 0; m < 13; ++m) a[m] = As2[k][ty + 16 * m];
                #pragma unroll
                for (int n = 0; n < 4; ++n) bq[n] = Bs2[k][tx + 16 * n];
                #pragma unroll
                for (int m = 0; m < 13; ++m)
                    #pragma unroll
                    for (int n = 0; n < 4; ++n)
                        acc[m][n] = fmaf(a[m], bq[n], acc[m][n]);
            }
        }

        #pragma unroll
        for (int n = 0; n < 4; ++n) {
            int c = tile * 64 + tx + 16 * n;
            if (c < NP) {
                #pragma unroll
                for (int m = 0; m < 13; ++m) {
                    float v = acc[m][n];
                    if (v > rmax[m] || (v == rmax[m] && c < ridx[m])) {
                        rmax[m] = v; ridx[m] = c;
                    }
                }
            }
        }

        #pragma unroll
        for (int n = 0; n < 4; ++n) {
            float bv = -3.0e38f; int bi = 1 << 30;
            #pragma unroll
            for (int m = 0; m < 13; ++m) {
                int row = ty + 16 * m;
                if (row < NP) {
                    float v = acc[m][n];
                    if (v > bv || (v == bv && row < bi)) { bv = v; bi = row; }
                }
            }
            colV[ty][tx + 16 * n] = bv;
            colI[ty][tx + 16 * n] = bi;
        }
        __syncthreads();
        if (tid < 64) {
            int c = tile * 64 + tid;
            if (c < NP) {
                float bv = -3.0e38f; int bi = 1 << 30;
                #pragma unroll
                for (int y = 0; y < 16; ++y) {
                    float v = colV[y][tid]; int i2 = colI[y][tid];
                    if (v > bv || (v == bv && i2 < bi)) { bv = v; bi = i2; }
                }
                out[1 + NBP + b * NP + c] = (float)bi;
            }
        }
        __syncthreads();
    }

    #pragma unroll
    for (int m = 0; m < 13; ++m) {
        float v = rmax[m]; int ix = ridx[m];
        #pragma unroll
        for (int off = 1; off < 16; off <<= 1) {
            float ov = __shfl_xor(v, off, 16);
            int   oi = __shfl_xor(ix, off, 16);
            if (ov > v || (ov == v && oi < ix)) { v = ov; ix = oi; }
        }
        rmax[m] = v; ridx[m] = ix;
    }
    if (tx == 0) {
        #pragma unroll
        for (int m = 0; m < 13; ++m) {
            int row = ty + 16 * m;
            if (row < NP) out[1 + b * NP + row] = (float)ridx[m];
        }
    }
}

__global__ void filip_loss(const float* __restrict__ sim12,
                           float* __restrict__ out) {
    int i = threadIdx.x;  // 0..63
    const float SC = 10.0f / 196.0f;
    const float* row = sim12 + i * NB;
    float mx = -3.0e38f;
    for (int j = 0; j < NB; ++j) mx = fmaxf(mx, row[j] * SC);
    float s = 0.0f;
    for (int j = 0; j < NB; ++j) s += expf(row[j] * SC - mx);
    float lse = mx + logf(s);
    float li = lse - row[i] * SC;
    #pragma unroll
    for (int off = 32; off > 0; off >>= 1)
        li += __shfl_xor(li, off, 64);
    if (i == 0) out[0] = li / 64.0f;
}

// ---------------------------------------------------------------------------
extern "C" void kernel_launch(void* const* d_in, const int* in_sizes, int n_in,
                              void* d_out, int out_size, void* d_ws, size_t ws_size,
                              hipStream_t stream) {
    const float* t1 = (const float*)d_in[0];
    const float* t2 = (const float*)d_in[1];
    float* out = (float*)d_out;
    float* ws  = (float*)d_ws;

    float* inv1  = ws;
    float* inv2  = ws + NBP;
    float* sim12 = ws + 2 * NBP;

    if (ws_size >= (size_t)WS_NEED) {
        char* t1fl = (char*)d_ws + WS_T1FL;
        char* t2fl = (char*)d_ws + WS_T2FL;
        unsigned long long* parts = (unsigned long long*)((char*)d_ws + WS_PARTS);

        filip_prep5<<<(NBP + NB * 256) / 4, 256, 0, stream>>>(t1, t2, inv1, inv2, sim12, t1fl, t2fl);
        filip_mfma7<<<dim3(98, NB), 256, 0, stream>>>(t1fl, t2fl, sim12);
        filip_diag4<<<dim3(4, NB), 256, 0, stream>>>(t1, t2, inv1, inv2, parts, out);
        filip_finloss<<<50, 256, 0, stream>>>(parts, sim12, out);
    } else {
        filip_norms<<<2 * NBP, 64, 0, stream>>>(t1, t2, inv1, inv2, sim12);
        filip_mfma<<<dim3(98, NB), 256, 0, stream>>>(t1, t2, inv1, inv2, sim12);
        filip_diag<<<NB, 256, 0, stream>>>(t1, t2, inv1, inv2, out);
        filip_loss<<<1, 64, 0, stream>>>(sim12, out);
    }
}

// Round 9
// 176.239 us; speedup vs baseline: 2.1182x; 1.0682x over previous
//
#include <hip/hip_runtime.h>
#include <math.h>

#define NB 64
#define NP 196
#define ND 256
#define NBP (NB * NP)   // 12544

typedef __bf16 v8bf __attribute__((ext_vector_type(8)));
typedef __bf16 v4bf __attribute__((ext_vector_type(4)));
typedef float f32x16 __attribute__((ext_vector_type(16)));

// ws layout (fast path), bytes:
//   inv1   @ 0          : 12544 f32
//   inv2   @ 50176      : 12544 f32
//   sim12  @ 100352     : 4096  f32
//   t1fl   @ 116736     : 98 tiles x fragment-linear (32 kgroups x 128 rows x 16B) = 6422528 B
//   t2fl   @ 6539264    : 64 panels x fragment-linear (32 kgroups x 256 cols x 16B; cols 196..255 zero) = 8388608 B
//   parts  @ 14927872   : 64*4*196 u64 = 401408 B
#define WS_T1FL   116736
#define WS_T2FL   6539264
#define WS_PARTS  14927872
#define WS_NEED   15329280

// ---------------------------------------------------------------------------
// packed (value,index) for argmax with np first-occurrence tie-break
// ---------------------------------------------------------------------------
__device__ __forceinline__ unsigned int fmono(float v) {
    unsigned int u = __float_as_uint(v);
    return (u & 0x80000000u) ? ~u : (u | 0x80000000u);
}
__device__ __forceinline__ unsigned long long packVI(float v, int idx) {
    return ((unsigned long long)fmono(v) << 32) | (unsigned int)(~idx);
}

// ===========================================================================
// FAST PATH
// ===========================================================================

// Kernel 1: per-row norm -> inv arrays; write normalized bf16 in
// FRAGMENT-LINEAR layout (zero-LDS GEMM reads fragments as contiguous 512B
// runs). Lane L holds k-elems [4L,4L+4): g = L>>1, half = (L&1)*8.
__global__ __launch_bounds__(256)
void filip_prep5(const float* __restrict__ t1, const float* __restrict__ t2,
                 float* __restrict__ inv1, float* __restrict__ inv2,
                 float* __restrict__ sim12,
                 char* __restrict__ t1fl, char* __restrict__ t2fl) {
    const int tid = threadIdx.x;
    if (blockIdx.x == 0) {
        float4 z = make_float4(0.f, 0.f, 0.f, 0.f);
        float4* s4 = reinterpret_cast<float4*>(sim12);
        #pragma unroll
        for (int j = 0; j < 4; ++j) s4[tid * 4 + j] = z;
    }
    int id = blockIdx.x * 4 + (tid >> 6);   // 0 .. NBP + NB*256 - 1
    int L = tid & 63;
    int g = L >> 1, h8 = (L & 1) * 8;
    if (id < NBP) {
        const float* src = t1 + (size_t)id * ND;
        float4 v = reinterpret_cast<const float4*>(src)[L];
        float ss = v.x * v.x + v.y * v.y + v.z * v.z + v.w * v.w;
        #pragma unroll
        for (int off = 32; off > 0; off >>= 1) ss += __shfl_xor(ss, off, 64);
        float inv = 1.0f / fmaxf(sqrtf(ss), 1e-12f);
        if (L == 0) inv1[id] = inv;
        v4bf o;
        o[0] = (__bf16)(v.x * inv); o[1] = (__bf16)(v.y * inv);
        o[2] = (__bf16)(v.z * inv); o[3] = (__bf16)(v.w * inv);
        int t = id >> 7, r = id & 127;
        char* dst = t1fl + (size_t)t * 65536 + g * 2048 + r * 16 + h8;
        *reinterpret_cast<v4bf*>(dst) = o;
    } else {
        int pid = id - NBP;          // 0..16383
        int b2 = pid >> 8, c = pid & 255;
        char* dst = t2fl + (size_t)b2 * 131072 + g * 4096 + c * 16 + h8;
        if (c < NP) {
            const float* src = t2 + (size_t)(b2 * NP + c) * ND;
            float4 v = reinterpret_cast<const float4*>(src)[L];
            float ss = v.x * v.x + v.y * v.y + v.z * v.z + v.w * v.w;
            #pragma unroll
            for (int off = 32; off > 0; off >>= 1) ss += __shfl_xor(ss, off, 64);
            float inv = 1.0f / fmaxf(sqrtf(ss), 1e-12f);
            if (L == 0) inv2[b2 * NP + c] = inv;
            v4bf o;
            o[0] = (__bf16)(v.x * inv); o[1] = (__bf16)(v.y * inv);
            o[2] = (__bf16)(v.z * inv); o[3] = (__bf16)(v.w * inv);
            *reinterpret_cast<v4bf*>(dst) = o;
        } else {
            v4bf z; z[0] = z[1] = z[2] = z[3] = (__bf16)0.0f;
            *reinterpret_cast<v4bf*>(dst) = z;
        }
    }
}

// Kernel 2: zero-LDS MFMA mean-of-rowmax, 2-deep software prefetch +
// LDS-transpose rowmax epilogue (max is associative -> bit-identical).
#define BM 128
#define BN 256

__global__ __launch_bounds__(256, 2)
void filip_mfma8(const char* __restrict__ t1fl, const char* __restrict__ t2fl,
                 float* __restrict__ sim12)
{
    __shared__ __align__(16) float pmx[128][68];   // 34816 B, stride 68 (conflict-light)

    // XCD-aware bijection with A-tile reuse (b2 innermost per XCD).
    int n = blockIdx.x + 98 * blockIdx.y;   // 0..6271
    int x = n & 7, local = n >> 3;
    const int bRow = local >> 3;            // 0..97
    const int b2   = x * 8 + (local & 7);   // 0..63

    const int tid  = threadIdx.x;
    const int lane = tid & 63, wave = tid >> 6;
    const int wr = wave >> 1, wc = wave & 1;
    const int ln = lane & 31, hi = lane >> 5;

    const char* Ap = t1fl + (size_t)bRow * 65536 + hi * 2048 + (wr * 64 + ln) * 16;
    const char* Bp = t2fl + (size_t)b2 * 131072 + hi * 4096 + (wc * 128 + ln) * 16;

    f32x16 acc[2][4];
    #pragma unroll
    for (int mt = 0; mt < 2; ++mt)
        #pragma unroll
        for (int nt = 0; nt < 4; ++nt)
            #pragma unroll
            for (int r = 0; r < 16; ++r) acc[mt][nt][r] = 0.0f;

    // prologue: even-kk fragment set
    v8bf a0 = *reinterpret_cast<const v8bf*>(Ap);
    v8bf a1 = *reinterpret_cast<const v8bf*>(Ap + 512);
    v8bf b0 = *reinterpret_cast<const v8bf*>(Bp);
    v8bf b1 = *reinterpret_cast<const v8bf*>(Bp + 512);
    v8bf b2f = *reinterpret_cast<const v8bf*>(Bp + 1024);
    v8bf b3 = *reinterpret_cast<const v8bf*>(Bp + 1536);

    // 8 iterations x 2 kk; kk order identical to prior rounds -> bit-identical
    #pragma unroll 1
    for (int it = 0; it < 8; ++it) {
        // prefetch odd set (kk = 2*it+1)
        v8bf c0 = *reinterpret_cast<const v8bf*>(Ap + 4096);
        v8bf c1 = *reinterpret_cast<const v8bf*>(Ap + 4608);
        v8bf d0 = *reinterpret_cast<const v8bf*>(Bp + 8192);
        v8bf d1 = *reinterpret_cast<const v8bf*>(Bp + 8704);
        v8bf d2 = *reinterpret_cast<const v8bf*>(Bp + 9216);
        v8bf d3 = *reinterpret_cast<const v8bf*>(Bp + 9728);
        // MFMA even
        acc[0][0] = __builtin_amdgcn_mfma_f32_32x32x16_bf16(a0, b0, acc[0][0], 0, 0, 0);
        acc[0][1] = __builtin_amdgcn_mfma_f32_32x32x16_bf16(a0, b1, acc[0][1], 0, 0, 0);
        acc[0][2] = __builtin_amdgcn_mfma_f32_32x32x16_bf16(a0, b2f, acc[0][2], 0, 0, 0);
        acc[0][3] = __builtin_amdgcn_mfma_f32_32x32x16_bf16(a0, b3, acc[0][3], 0, 0, 0);
        acc[1][0] = __builtin_amdgcn_mfma_f32_32x32x16_bf16(a1, b0, acc[1][0], 0, 0, 0);
        acc[1][1] = __builtin_amdgcn_mfma_f32_32x32x16_bf16(a1, b1, acc[1][1], 0, 0, 0);
        acc[1][2] = __builtin_amdgcn_mfma_f32_32x32x16_bf16(a1, b2f, acc[1][2], 0, 0, 0);
        acc[1][3] = __builtin_amdgcn_mfma_f32_32x32x16_bf16(a1, b3, acc[1][3], 0, 0, 0);
        // advance to next even base; prefetch next even set (kk = 2*it+2)
        Ap += 8192;
        Bp += 16384;
        if (it < 7) {
            a0 = *reinterpret_cast<const v8bf*>(Ap);
            a1 = *reinterpret_cast<const v8bf*>(Ap + 512);
            b0 = *reinterpret_cast<const v8bf*>(Bp);
            b1 = *reinterpret_cast<const v8bf*>(Bp + 512);
            b2f = *reinterpret_cast<const v8bf*>(Bp + 1024);
            b3 = *reinterpret_cast<const v8bf*>(Bp + 1536);
        }
        // MFMA odd
        acc[0][0] = __builtin_amdgcn_mfma_f32_32x32x16_bf16(c0, d0, acc[0][0], 0, 0, 0);
        acc[0][1] = __builtin_amdgcn_mfma_f32_32x32x16_bf16(c0, d1, acc[0][1], 0, 0, 0);
        acc[0][2] = __builtin_amdgcn_mfma_f32_32x32x16_bf16(c0, d2, acc[0][2], 0, 0, 0);
        acc[0][3] = __builtin_amdgcn_mfma_f32_32x32x16_bf16(c0, d3, acc[0][3], 0, 0, 0);
        acc[1][0] = __builtin_amdgcn_mfma_f32_32x32x16_bf16(c1, d0, acc[1][0], 0, 0, 0);
        acc[1][1] = __builtin_amdgcn_mfma_f32_32x32x16_bf16(c1, d1, acc[1][1], 0, 0, 0);
        acc[1][2] = __builtin_amdgcn_mfma_f32_32x32x16_bf16(c1, d2, acc[1][2], 0, 0, 0);
        acc[1][3] = __builtin_amdgcn_mfma_f32_32x32x16_bf16(c1, d3, acc[1][3], 0, 0, 0);
    }

    // --- rowmax epilogue via LDS transpose (max exact -> order-free) ---
    // C/D layout: col = lane&31, row = (r&3) + 8*(r>>2) + 4*hi
    #pragma unroll
    for (int mt = 0; mt < 2; ++mt) {
        #pragma unroll
        for (int r = 0; r < 16; ++r) {
            float m = fmaxf(fmaxf(acc[mt][0][r], acc[mt][1][r]),
                            fmaxf(acc[mt][2][r], acc[mt][3][r]));
            int row = wr * 64 + mt * 32 + (r & 3) + 8 * (r >> 2) + 4 * hi;
            pmx[row][wc * 32 + ln] = m;   // 64 partials per row
        }
    }
    __syncthreads();
    if (tid < BM) {
        const float4* prow = reinterpret_cast<const float4*>(pmx[tid]);
        float m = -3.0e38f;
        #pragma unroll
        for (int j = 0; j < 16; ++j) {
            float4 v = prow[j];
            m = fmaxf(m, fmaxf(fmaxf(v.x, v.y), fmaxf(v.z, v.w)));
        }
        int grow = bRow * BM + tid;
        int b1 = grow / NP;
        int fb = (bRow * BM) / NP;
        float v0 = (b1 == fb) ? m : 0.0f;
        float v1 = (b1 != fb) ? m : 0.0f;
        #pragma unroll
        for (int off = 1; off < 64; off <<= 1) {
            v0 += __shfl_xor(v0, off, 64);
            v1 += __shfl_xor(v1, off, 64);
        }
        if (lane == 0) {
            atomicAdd(&sim12[fb * NB + b2], v0);
            int lb = (bRow * BM + BM - 1) / NP;
            if (lb != fb) atomicAdd(&sim12[lb * NB + b2], v1);
        }
    }
}

// Kernel 3: fp32-exact diagonal blocks, 4 blocks per batch (49 rows each).
__global__ __launch_bounds__(256)
void filip_diag4(const float* __restrict__ t1, const float* __restrict__ t2,
                 const float* __restrict__ inv1, const float* __restrict__ inv2,
                 unsigned long long* __restrict__ parts,
                 float* __restrict__ out)
{
    const int q = blockIdx.x;          // 0..3 (row quarter)
    const int b = blockIdx.y;          // 0..63
    const int r0 = q * 49;
    const int tid = threadIdx.x;
    const int tx = tid & 15, ty = tid >> 4;

    __shared__ float smemF[2176 + 8320];       // As[32][68] + Bs[32][260]
    float* As = smemF;
    float* Bs = smemF + 2176;
    unsigned long long* colP = reinterpret_cast<unsigned long long*>(smemF); // reuse

    const float* Ap = t1 + (size_t)b * NP * ND;
    const float* Bp = t2 + (size_t)b * NP * ND;
    const float* ia = inv1 + b * NP;
    const float* ib = inv2 + b * NP;

    float acc[4][4][4];
    #pragma unroll
    for (int i = 0; i < 4; ++i)
        #pragma unroll
        for (int j = 0; j < 4; ++j)
            #pragma unroll
            for (int l = 0; l < 4; ++l) acc[i][j][l] = 0.0f;

    for (int kc = 0; kc < 8; ++kc) {
        __syncthreads();
        #pragma unroll
        for (int i = 0; i < 2; ++i) {
            int f4 = tid + 256 * i;            // 0..511
            int row = f4 >> 3, k4 = f4 & 7;
            float4 v = make_float4(0.f, 0.f, 0.f, 0.f);
            if (row < 49) {
                v = *reinterpret_cast<const float4*>(Ap + (size_t)(r0 + row) * ND + kc * 32 + 4 * k4);
                float s = ia[r0 + row];
                v.x *= s; v.y *= s; v.z *= s; v.w *= s;
            }
            As[(4 * k4 + 0) * 68 + row] = v.x;
            As[(4 * k4 + 1) * 68 + row] = v.y;
            As[(4 * k4 + 2) * 68 + row] = v.z;
            As[(4 * k4 + 3) * 68 + row] = v.w;
        }
        #pragma unroll
        for (int i = 0; i < 8; ++i) {
            int f4 = tid + 256 * i;            // 0..2047
            int col = f4 >> 3, k4 = f4 & 7;
            float4 v = make_float4(0.f, 0.f, 0.f, 0.f);
            if (col < NP) {
                v = *reinterpret_cast<const float4*>(Bp + (size_t)col * ND + kc * 32 + 4 * k4);
                float s = ib[col];
                v.x *= s; v.y *= s; v.z *= s; v.w *= s;
            }
            Bs[(4 * k4 + 0) * 260 + col] = v.x;
            Bs[(4 * k4 + 1) * 260 + col] = v.y;
            Bs[(4 * k4 + 2) * 260 + col] = v.z;
            Bs[(4 * k4 + 3) * 260 + col] = v.w;
        }
        __syncthreads();
        #pragma unroll 4
        for (int k = 0; k < 32; ++k) {
            float a0 = As[k * 68 + 4 * ty + 0];
            float a1 = As[k * 68 + 4 * ty + 1];
            float a2 = As[k * 68 + 4 * ty + 2];
            float a3 = As[k * 68 + 4 * ty + 3];
            float4 bq[4];
            #pragma unroll
            for (int j = 0; j < 4; ++j)
                bq[j] = *reinterpret_cast<const float4*>(&Bs[k * 260 + 4 * tx + 64 * j]);
            #pragma unroll
            for (int j = 0; j < 4; ++j) {
                acc[0][j][0] = fmaf(a0, bq[j].x, acc[0][j][0]);
                acc[0][j][1] = fmaf(a0, bq[j].y, acc[0][j][1]);
                acc[0][j][2] = fmaf(a0, bq[j].z, acc[0][j][2]);
                acc[0][j][3] = fmaf(a0, bq[j].w, acc[0][j][3]);
                acc[1][j][0] = fmaf(a1, bq[j].x, acc[1][j][0]);
                acc[1][j][1] = fmaf(a1, bq[j].y, acc[1][j][1]);
                acc[1][j][2] = fmaf(a1, bq[j].z, acc[1][j][2]);
                acc[1][j][3] = fmaf(a1, bq[j].w, acc[1][j][3]);
                acc[2][j][0] = fmaf(a2, bq[j].x, acc[2][j][0]);
                acc[2][j][1] = fmaf(a2, bq[j].y, acc[2][j][1]);
                acc[2][j][2] = fmaf(a2, bq[j].z, acc[2][j][2]);
                acc[2][j][3] = fmaf(a2, bq[j].w, acc[2][j][3]);
                acc[3][j][0] = fmaf(a3, bq[j].x, acc[3][j][0]);
                acc[3][j][1] = fmaf(a3, bq[j].y, acc[3][j][1]);
                acc[3][j][2] = fmaf(a3, bq[j].z, acc[3][j][2]);
                acc[3][j][3] = fmaf(a3, bq[j].w, acc[3][j][3]);
            }
        }
    }

    // row argmax (idx_to_keep1_2)
    #pragma unroll
    for (int i = 0; i < 4; ++i) {
        unsigned long long best = 0ull;
        #pragma unroll
        for (int j = 0; j < 4; ++j)
            #pragma unroll
            for (int l = 0; l < 4; ++l) {
                int c = 64 * j + 4 * tx + l;
                if (c < NP) {
                    unsigned long long p = packVI(acc[i][j][l], c);
                    if (p > best) best = p;
                }
            }
        #pragma unroll
        for (int off = 1; off < 16; off <<= 1) {
            unsigned long long o = __shfl_xor(best, off, 16);
            if (o > best) best = o;
        }
        int rl = 4 * ty + i;
        if (tx == 0 && rl < 49)
            out[1 + b * NP + r0 + rl] = (float)(unsigned int)(~best);
    }

    // col argmax partials (idx_to_keep2_1)
    __syncthreads();
    #pragma unroll
    for (int j = 0; j < 4; ++j)
        #pragma unroll
        for (int l = 0; l < 4; ++l) {
            unsigned long long best = 0ull;
            #pragma unroll
            for (int i = 0; i < 4; ++i) {
                int rl = 4 * ty + i;
                if (rl < 49) {
                    unsigned long long p = packVI(acc[i][j][l], r0 + rl);
                    if (p > best) best = p;
                }
            }
            colP[ty * 256 + 64 * j + 4 * tx + l] = best;
        }
    __syncthreads();
    {
        unsigned long long best = 0ull;
        #pragma unroll
        for (int y = 0; y < 16; ++y) {
            unsigned long long o = colP[y * 256 + tid];
            if (o > best) best = o;
        }
        if (tid < NP) parts[(b * 4 + q) * NP + tid] = best;
    }
}

// Kernel 4: merged fin (blocks 0..48) + loss (block 49).
__global__ void filip_finloss(const unsigned long long* __restrict__ parts,
                              const float* __restrict__ sim12,
                              float* __restrict__ out) {
    if (blockIdx.x < 49) {
        int id = blockIdx.x * 256 + threadIdx.x;   // 49*256 = 12544
        int b = id / NP, c = id - b * NP;
        unsigned long long best = 0ull;
        #pragma unroll
        for (int qq = 0; qq < 4; ++qq) {
            unsigned long long o = parts[(b * 4 + qq) * NP + c];
            if (o > best) best = o;
        }
        out[1 + NBP + id] = (float)(unsigned int)(~best);
    } else if (threadIdx.x < 64) {
        int i = threadIdx.x;  // 0..63
        const float SC = 10.0f / 196.0f;
        const float* row = sim12 + i * NB;
        float mx = -3.0e38f;
        for (int j = 0; j < NB; ++j) mx = fmaxf(mx, row[j] * SC);
        float s = 0.0f;
        for (int j = 0; j < NB; ++j) s += expf(row[j] * SC - mx);
        float lse = mx + logf(s);
        float li = lse - row[i] * SC;
        #pragma unroll
        for (int off = 32; off > 0; off >>= 1)
            li += __shfl_xor(li, off, 64);
        if (i == 0) out[0] = li / 64.0f;
    }
}

// ===========================================================================
// FALLBACK PATH (verbatim round-2, known-passing) — used if ws too small
// ===========================================================================
__global__ void filip_norms(const float* __restrict__ t1,
                            const float* __restrict__ t2,
                            float* __restrict__ inv1,
                            float* __restrict__ inv2,
                            float* __restrict__ sim12) {
    int row = blockIdx.x;
    int lane = threadIdx.x;
    if (row < NB) sim12[row * NB + lane] = 0.0f;
    const float* src; float* dst; int r;
    if (row < NBP) { src = t1; dst = inv1; r = row; }
    else           { src = t2; dst = inv2; r = row - NBP; }
    float4 v = reinterpret_cast<const float4*>(src + (size_t)r * ND)[lane];
    float ss = v.x * v.x + v.y * v.y + v.z * v.z + v.w * v.w;
    #pragma unroll
    for (int off = 32; off > 0; off >>= 1)
        ss += __shfl_xor(ss, off, 64);
    if (lane == 0)
        dst[r] = 1.0f / fmaxf(sqrtf(ss), 1e-12f);
}

__device__ __forceinline__ v8bf cvt8(float4 a, float4 b, float s) {
    v8bf v;
    v[0] = (__bf16)(a.x * s); v[1] = (__bf16)(a.y * s);
    v[2] = (__bf16)(a.z * s); v[3] = (__bf16)(a.w * s);
    v[4] = (__bf16)(b.x * s); v[5] = (__bf16)(b.y * s);
    v[6] = (__bf16)(b.z * s); v[7] = (__bf16)(b.w * s);
    return v;
}

#define BKF 64
__global__ __launch_bounds__(256, 2)
void filip_mfma(const float* __restrict__ t1, const float* __restrict__ t2,
                const float* __restrict__ inv1, const float* __restrict__ inv2,
                float* __restrict__ sim12)
{
    __shared__ unsigned short Asb[BM * BKF];
    __shared__ unsigned short Bsb[BN * BKF];
    __shared__ float rmx[2][BM];

    const int bRow = blockIdx.x;
    const int b2   = blockIdx.y;
    const int tid  = threadIdx.x;
    const int lane = tid & 63, wave = tid >> 6;
    const int wr = wave >> 1, wc = wave & 1;
    const int ln = lane & 31, hi = lane >> 5;

    const float* Abase = t1 + (size_t)bRow * BM * ND;
    const float* Bbase = t2 + (size_t)b2 * NP * ND;

    f32x16 acc[2][4];
    #pragma unroll
    for (int mt = 0; mt < 2; ++mt)
        #pragma unroll
        for (int nt = 0; nt < 4; ++nt)
            #pragma unroll
            for (int r = 0; r < 16; ++r) acc[mt][nt][r] = 0.0f;

    for (int kc = 0; kc < 4; ++kc) {
        __syncthreads();
        #pragma unroll
        for (int i = 0; i < 4; ++i) {
            int flat = (i * 256 + tid) * 8;
            int r = flat >> 6, k0 = flat & 63;
            const float* gp = Abase + (size_t)r * ND + kc * BKF + k0;
            float4 f0 = *reinterpret_cast<const float4*>(gp);
            float4 f1 = *reinterpret_cast<const float4*>(gp + 4);
            float s = inv1[bRow * BM + r];
            v8bf v = cvt8(f0, f1, s);
            int off = r * 128 + ((k0 * 2) ^ ((r & 7) << 4));
            *reinterpret_cast<v8bf*>(reinterpret_cast<char*>(Asb) + off) = v;
        }
        #pragma unroll
        for (int i = 0; i < 8; ++i) {
            int flat = (i * 256 + tid) * 8;
            int r = flat >> 6, k0 = flat & 63;
            v8bf v;
            if (r < NP) {
                const float* gp = Bbase + (size_t)r * ND + kc * BKF + k0;
                float4 f0 = *reinterpret_cast<const float4*>(gp);
                float4 f1 = *reinterpret_cast<const float4*>(gp + 4);
                float s = inv2[b2 * NP + r];
                v = cvt8(f0, f1, s);
            } else {
                #pragma unroll
                for (int j = 0; j < 8; ++j) v[j] = (__bf16)0.0f;
            }
            int off = r * 128 + ((k0 * 2) ^ ((r & 7) << 4));
            *reinterpret_cast<v8bf*>(reinterpret_cast<char*>(Bsb) + off) = v;
        }
        __syncthreads();
        #pragma unroll
        for (int ks = 0; ks < 4; ++ks) {
            const int kb = ks * 32 + hi * 16;
            v8bf af[2], bfr[4];
            #pragma unroll
            for (int mt = 0; mt < 2; ++mt) {
                int r = wr * 64 + mt * 32 + ln;
                af[mt] = *reinterpret_cast<const v8bf*>(
                    reinterpret_cast<const char*>(Asb) + r * 128 + (kb ^ ((r & 7) << 4)));
            }
            #pragma unroll
            for (int nt = 0; nt < 4; ++nt) {
                int c = wc * 128 + nt * 32 + ln;
                bfr[nt] = *reinterpret_cast<const v8bf*>(
                    reinterpret_cast<const char*>(Bsb) + c * 128 + (kb ^ ((c & 7) << 4)));
            }
            #pragma unroll
            for (int mt = 0; mt < 2; ++mt)
                #pragma unroll
                for (int nt = 0; nt < 4; ++nt)
                    acc[mt][nt] = __builtin_amdgcn_mfma_f32_32x32x16_bf16(
                        af[mt], bfr[nt], acc[mt][nt], 0, 0, 0);
        }
    }

    #pragma unroll
    for (int mt = 0; mt < 2; ++mt) {
        float t[16];
        #pragma unroll
        for (int r = 0; r < 16; ++r) {
            float m = fmaxf(fmaxf(acc[mt][0][r], acc[mt][1][r]),
                            fmaxf(acc[mt][2][r], acc[mt][3][r]));
            #pragma unroll
            for (int off = 1; off <= 16; off <<= 1)
                m = fmaxf(m, __shfl_xor(m, off, 64));
            t[r] = m;
        }
        if (ln == 0) {
            #pragma unroll
            for (int r = 0; r < 16; ++r) {
                int row = wr * 64 + mt * 32 + (r & 3) + 8 * (r >> 2) + 4 * hi;
                rmx[wc][row] = t[r];
            }
        }
    }
    __syncthreads();
    if (tid < BM) {
        float m = fmaxf(rmx[0][tid], rmx[1][tid]);
        int grow = bRow * BM + tid;
        int b1 = grow / NP;
        int fb = (bRow * BM) / NP;
        float v0 = (b1 == fb) ? m : 0.0f;
        float v1 = (b1 != fb) ? m : 0.0f;
        #pragma unroll
        for (int off = 1; off < 64; off <<= 1) {
            v0 += __shfl_xor(v0, off, 64);
            v1 += __shfl_xor(v1, off, 64);
        }
        if (lane == 0) {
            atomicAdd(&sim12[fb * NB + b2], v0);
            int lb = (bRow * BM + BM - 1) / NP;
            if (lb != fb) atomicAdd(&sim12[lb * NB + b2], v1);
        }
    }
}

__global__ __launch_bounds__(256)
void filip_diag(const float* __restrict__ t1, const float* __restrict__ t2,
                const float* __restrict__ inv1, const float* __restrict__ inv2,
                float* __restrict__ out)
{
    const int b = blockIdx.x;
    const int tid = threadIdx.x;
    const int tx = tid & 15, ty = tid >> 4;

    __shared__ float As2[16][209];
    __shared__ float Bs2[16][65];
    __shared__ float colV[16][65];
    __shared__ int   colI[16][65];

    const float* Ap = t1 + (size_t)b * NP * ND;
    const float* Bp = t2 + (size_t)b * NP * ND;
    const float* ia = inv1 + b * NP;
    const float* ib = inv2 + b * NP;

    float rmax[13];
    int   ridx[13];
    #pragma unroll
    for (int m = 0; m < 13; ++m) { rmax[m] = -3.0e38f; ridx[m] = 1 << 30; }

    for (int tile = 0; tile < 4; ++tile) {
        float acc[13][4];
        #pragma unroll
        for (int m = 0; m < 13; ++m)
            #pragma unroll
            for (int n = 0; n < 4; ++n) acc[m][n] = 0.0f;

        for (int kk = 0; kk < 16; ++kk) {
            __syncthreads();
            #pragma unroll
            for (int i = 0; i < 13; ++i) {
                int e = tid + 256 * i;
                int p1 = e >> 4, k = e & 15;
                float v = 0.0f;
                if (p1 < NP) v = Ap[p1 * ND + kk * 16 + k] * ia[p1];
                As2[k][p1] = v;
            }
            #pragma unroll
            for (int i = 0; i < 4; ++i) {
                int e = tid + 256 * i;
                int pl = e >> 4, k = e & 15;
                int p2 = tile * 64 + pl;
                float v = 0.0f;
                if (p2 < NP) v = Bp[p2 * ND + kk * 16 + k] * ib[p2];
                Bs2[k][pl] = v;
            }
            __syncthreads();
            #pragma unroll 4
            for (int k = 0; k < 16; ++k) {
                float a[13], bq[4];
                #pragma unroll
                for (int m = 0; m < 13; ++m) a[m] = As2[k][ty + 16 * m];
                #pragma unroll
                for (int n = 0; n < 4; ++n) bq[n] = Bs2[k][tx + 16 * n];
                #pragma unroll
                for (int m = 0; m < 13; ++m)
                    #pragma unroll
                    for (int n = 0; n < 4; ++n)
                        acc[m][n] = fmaf(a[m], bq[n], acc[m][n]);
            }
        }

        #pragma unroll
        for (int n = 0; n < 4; ++n) {
            int c = tile * 64 + tx + 16 * n;
            if (c < NP) {
                #pragma unroll
                for (int m = 0; m < 13; ++m) {
                    float v = acc[m][n];
                    if (v > rmax[m] || (v == rmax[m] && c < ridx[m])) {
                        rmax[m] = v; ridx[m] = c;
                    }
                }
            }
        }

        #pragma unroll
        for (int n = 0; n < 4; ++n) {
            float bv = -3.0e38f; int bi = 1 << 30;
            #pragma unroll
            for (int m = 0; m < 13; ++m) {
                int row = ty + 16 * m;
                if (row < NP) {
                    float v = acc[m][n];
                    if (v > bv || (v == bv && row < bi)) { bv = v; bi = row; }
                }
            }
            colV[ty][tx + 16 * n] = bv;
            colI[ty][tx + 16 * n] = bi;
        }
        __syncthreads();
        if (tid < 64) {
            int c = tile * 64 + tid;
            if (c < NP) {
                float bv = -3.0e38f; int bi = 1 << 30;
                #pragma unroll
                for (int y = 0; y < 16; ++y) {
                    float v = colV[y][tid]; int i2 = colI[y][tid];
                    if (v > bv || (v == bv && i2 < bi)) { bv = v; bi = i2; }
                }
                out[1 + NBP + b * NP + c] = (float)bi;
            }
        }
        __syncthreads();
    }

    #pragma unroll
    for (int m = 0; m < 13; ++m) {
        float v = rmax[m]; int ix = ridx[m];
        #pragma unroll
        for (int off = 1; off < 16; off <<= 1) {
            float ov = __shfl_xor(v, off, 16);
            int   oi = __shfl_xor(ix, off, 16);
            if (ov > v || (ov == v && oi < ix)) { v = ov; ix = oi; }
        }
        rmax[m] = v; ridx[m] = ix;
    }
    if (tx == 0) {
        #pragma unroll
        for (int m = 0; m < 13; ++m) {
            int row = ty + 16 * m;
            if (row < NP) out[1 + b * NP + row] = (float)ridx[m];
        }
    }
}

__global__ void filip_loss(const float* __restrict__ sim12,
                           float* __restrict__ out) {
    int i = threadIdx.x;  // 0..63
    const float SC = 10.0f / 196.0f;
    const float* row = sim12 + i * NB;
    float mx = -3.0e38f;
    for (int j = 0; j < NB; ++j) mx = fmaxf(mx, row[j] * SC);
    float s = 0.0f;
    for (int j = 0; j < NB; ++j) s += expf(row[j] * SC - mx);
    float lse = mx + logf(s);
    float li = lse - row[i] * SC;
    #pragma unroll
    for (int off = 32; off > 0; off >>= 1)
        li += __shfl_xor(li, off, 64);
    if (i == 0) out[0] = li / 64.0f;
}

// ---------------------------------------------------------------------------
extern "C" void kernel_launch(void* const* d_in, const int* in_sizes, int n_in,
                              void* d_out, int out_size, void* d_ws, size_t ws_size,
                              hipStream_t stream) {
    const float* t1 = (const float*)d_in[0];
    const float* t2 = (const float*)d_in[1];
    float* out = (float*)d_out;
    float* ws  = (float*)d_ws;

    float* inv1  = ws;
    float* inv2  = ws + NBP;
    float* sim12 = ws + 2 * NBP;

    if (ws_size >= (size_t)WS_NEED) {
        char* t1fl = (char*)d_ws + WS_T1FL;
        char* t2fl = (char*)d_ws + WS_T2FL;
        unsigned long long* parts = (unsigned long long*)((char*)d_ws + WS_PARTS);

        filip_prep5<<<(NBP + NB * 256) / 4, 256, 0, stream>>>(t1, t2, inv1, inv2, sim12, t1fl, t2fl);
        filip_mfma8<<<dim3(98, NB), 256, 0, stream>>>(t1fl, t2fl, sim12);
        filip_diag4<<<dim3(4, NB), 256, 0, stream>>>(t1, t2, inv1, inv2, parts, out);
        filip_finloss<<<50, 256, 0, stream>>>(parts, sim12, out);
    } else {
        filip_norms<<<2 * NBP, 64, 0, stream>>>(t1, t2, inv1, inv2, sim12);
        filip_mfma<<<dim3(98, NB), 256, 0, stream>>>(t1, t2, inv1, inv2, sim12);
        filip_diag<<<NB, 256, 0, stream>>>(t1, t2, inv1, inv2, out);
        filip_loss<<<1, 64, 0, stream>>>(sim12, out);
    }
}

// Round 10
// 155.837 us; speedup vs baseline: 2.3955x; 1.1309x over previous
//
#include <hip/hip_runtime.h>
#include <math.h>

#define NB 64
#define NP 196
#define ND 256
#define NBP (NB * NP)   // 12544

typedef __bf16 v8bf __attribute__((ext_vector_type(8)));
typedef __bf16 v4bf __attribute__((ext_vector_type(4)));
typedef float f32x16 __attribute__((ext_vector_type(16)));

// ws layout (fast path), bytes:
//   inv1   @ 0          : 12544 f32
//   inv2   @ 50176      : 12544 f32
//   sim12  @ 100352     : 4096  f32
//   t1fl   @ 116736     : 98 tiles x fragment-linear (32 kgroups x 128 rows x 16B) = 6422528 B
//   t2fl   @ 6539264    : 64 panels x fragment-linear (32 kgroups x 256 cols x 16B; cols 196..255 zero) = 8388608 B
//   parts  @ 14927872   : 64*4*196 u64 = 401408 B
#define WS_T1FL   116736
#define WS_T2FL   6539264
#define WS_PARTS  14927872
#define WS_NEED   15329280

// ---------------------------------------------------------------------------
// packed (value,index) for argmax with np first-occurrence tie-break
// ---------------------------------------------------------------------------
__device__ __forceinline__ unsigned int fmono(float v) {
    unsigned int u = __float_as_uint(v);
    return (u & 0x80000000u) ? ~u : (u | 0x80000000u);
}
__device__ __forceinline__ unsigned long long packVI(float v, int idx) {
    return ((unsigned long long)fmono(v) << 32) | (unsigned int)(~idx);
}

// ===========================================================================
// FAST PATH
// ===========================================================================

// Kernel 1: per-row norm -> inv arrays; write normalized bf16 in
// FRAGMENT-LINEAR layout (zero-LDS GEMM reads fragments as contiguous 512B
// runs). Lane L holds k-elems [4L,4L+4): g = L>>1, half = (L&1)*8.
__global__ __launch_bounds__(256)
void filip_prep5(const float* __restrict__ t1, const float* __restrict__ t2,
                 float* __restrict__ inv1, float* __restrict__ inv2,
                 float* __restrict__ sim12,
                 char* __restrict__ t1fl, char* __restrict__ t2fl) {
    const int tid = threadIdx.x;
    if (blockIdx.x == 0) {
        float4 z = make_float4(0.f, 0.f, 0.f, 0.f);
        float4* s4 = reinterpret_cast<float4*>(sim12);
        #pragma unroll
        for (int j = 0; j < 4; ++j) s4[tid * 4 + j] = z;
    }
    int id = blockIdx.x * 4 + (tid >> 6);   // 0 .. NBP + NB*256 - 1
    int L = tid & 63;
    int g = L >> 1, h8 = (L & 1) * 8;
    if (id < NBP) {
        const float* src = t1 + (size_t)id * ND;
        float4 v = reinterpret_cast<const float4*>(src)[L];
        float ss = v.x * v.x + v.y * v.y + v.z * v.z + v.w * v.w;
        #pragma unroll
        for (int off = 32; off > 0; off >>= 1) ss += __shfl_xor(ss, off, 64);
        float inv = 1.0f / fmaxf(sqrtf(ss), 1e-12f);
        if (L == 0) inv1[id] = inv;
        v4bf o;
        o[0] = (__bf16)(v.x * inv); o[1] = (__bf16)(v.y * inv);
        o[2] = (__bf16)(v.z * inv); o[3] = (__bf16)(v.w * inv);
        int t = id >> 7, r = id & 127;
        char* dst = t1fl + (size_t)t * 65536 + g * 2048 + r * 16 + h8;
        *reinterpret_cast<v4bf*>(dst) = o;
    } else {
        int pid = id - NBP;          // 0..16383
        int b2 = pid >> 8, c = pid & 255;
        char* dst = t2fl + (size_t)b2 * 131072 + g * 4096 + c * 16 + h8;
        if (c < NP) {
            const float* src = t2 + (size_t)(b2 * NP + c) * ND;
            float4 v = reinterpret_cast<const float4*>(src)[L];
            float ss = v.x * v.x + v.y * v.y + v.z * v.z + v.w * v.w;
            #pragma unroll
            for (int off = 32; off > 0; off >>= 1) ss += __shfl_xor(ss, off, 64);
            float inv = 1.0f / fmaxf(sqrtf(ss), 1e-12f);
            if (L == 0) inv2[b2 * NP + c] = inv;
            v4bf o;
            o[0] = (__bf16)(v.x * inv); o[1] = (__bf16)(v.y * inv);
            o[2] = (__bf16)(v.z * inv); o[3] = (__bf16)(v.w * inv);
            *reinterpret_cast<v4bf*>(dst) = o;
        } else {
            v4bf z; z[0] = z[1] = z[2] = z[3] = (__bf16)0.0f;
            *reinterpret_cast<v4bf*>(dst) = z;
        }
    }
}

#define BM 128
#define BN 256

#define MFMA8(A0, A1, B0, B1, B2, B3)                                              \
    acc[0][0] = __builtin_amdgcn_mfma_f32_32x32x16_bf16(A0, B0, acc[0][0], 0, 0, 0); \
    acc[0][1] = __builtin_amdgcn_mfma_f32_32x32x16_bf16(A0, B1, acc[0][1], 0, 0, 0); \
    acc[0][2] = __builtin_amdgcn_mfma_f32_32x32x16_bf16(A0, B2, acc[0][2], 0, 0, 0); \
    acc[0][3] = __builtin_amdgcn_mfma_f32_32x32x16_bf16(A0, B3, acc[0][3], 0, 0, 0); \
    acc[1][0] = __builtin_amdgcn_mfma_f32_32x32x16_bf16(A1, B0, acc[1][0], 0, 0, 0); \
    acc[1][1] = __builtin_amdgcn_mfma_f32_32x32x16_bf16(A1, B1, acc[1][1], 0, 0, 0); \
    acc[1][2] = __builtin_amdgcn_mfma_f32_32x32x16_bf16(A1, B2, acc[1][2], 0, 0, 0); \
    acc[1][3] = __builtin_amdgcn_mfma_f32_32x32x16_bf16(A1, B3, acc[1][3], 0, 0, 0);

#define LDSETA(P, OFF, X0, X1)                                   \
    X0 = *reinterpret_cast<const v8bf*>(P + (OFF));              \
    X1 = *reinterpret_cast<const v8bf*>(P + (OFF) + 512);
#define LDSETB(P, OFF, X0, X1, X2, X3)                           \
    X0 = *reinterpret_cast<const v8bf*>(P + (OFF));              \
    X1 = *reinterpret_cast<const v8bf*>(P + (OFF) + 512);        \
    X2 = *reinterpret_cast<const v8bf*>(P + (OFF) + 1024);       \
    X3 = *reinterpret_cast<const v8bf*>(P + (OFF) + 1536);

// Kernel 2 (MEGA): blocks [0,256) = fp32-exact diagonal argmax (dispatched
// first, overlaps the GEMM); blocks [256, 6528) = zero-LDS MFMA GEMM with
// period-2 software pipeline (4 named fragment sets) + setprio around MFMA.
__global__ __launch_bounds__(256, 2)
void filip_mega(const char* __restrict__ t1fl, const char* __restrict__ t2fl,
                float* __restrict__ sim12,
                const float* __restrict__ t1, const float* __restrict__ t2,
                const float* __restrict__ inv1, const float* __restrict__ inv2,
                unsigned long long* __restrict__ parts,
                float* __restrict__ out)
{
    __shared__ __align__(16) char smem[41984];
    const int bid = blockIdx.x;
    const int tid = threadIdx.x;

    if (bid >= 256) {
        // =================== MFMA GEMM path ===================
        float (*pmx)[68] = reinterpret_cast<float (*)[68]>(smem);

        int n = bid - 256;                      // 0..6271
        int x = n & 7, local = n >> 3;
        const int bRow = local >> 3;            // 0..97
        const int b2   = x * 8 + (local & 7);   // 0..63

        const int lane = tid & 63, wave = tid >> 6;
        const int wr = wave >> 1, wc = wave & 1;
        const int ln = lane & 31, hi = lane >> 5;

        const char* Ap = t1fl + (size_t)bRow * 65536 + hi * 2048 + (wr * 64 + ln) * 16;
        const char* Bp = t2fl + (size_t)b2 * 131072 + hi * 4096 + (wc * 128 + ln) * 16;

        f32x16 acc[2][4];
        #pragma unroll
        for (int mt = 0; mt < 2; ++mt)
            #pragma unroll
            for (int nt = 0; nt < 4; ++nt)
                #pragma unroll
                for (int r = 0; r < 16; ++r) acc[mt][nt][r] = 0.0f;

        v8bf a0_0, a0_1, a1_0, a1_1, a2_0, a2_1, a3_0, a3_1;
        v8bf b0_0, b0_1, b0_2, b0_3, b1_0, b1_1, b1_2, b1_3;
        v8bf b2_0, b2_1, b2_2, b2_3, b3_0, b3_1, b3_2, b3_3;

        // prologue: kk=0,1
        LDSETA(Ap, 0,    a0_0, a0_1); LDSETB(Bp, 0,    b0_0, b0_1, b0_2, b0_3);
        LDSETA(Ap, 4096, a1_0, a1_1); LDSETB(Bp, 8192, b1_0, b1_1, b1_2, b1_3);

        // 4 iterations x 4 kk, ascending kk order -> bit-identical to prior
        #pragma unroll 1
        for (int it = 0; it < 4; ++it) {
            // prefetch kk = 4it+2, 4it+3
            LDSETA(Ap, 8192,  a2_0, a2_1); LDSETB(Bp, 16384, b2_0, b2_1, b2_2, b2_3);
            LDSETA(Ap, 12288, a3_0, a3_1); LDSETB(Bp, 24576, b3_0, b3_1, b3_2, b3_3);
            __builtin_amdgcn_s_setprio(1);
            MFMA8(a0_0, a0_1, b0_0, b0_1, b0_2, b0_3);   // kk = 4it
            MFMA8(a1_0, a1_1, b1_0, b1_1, b1_2, b1_3);   // kk = 4it+1
            __builtin_amdgcn_s_setprio(0);
            Ap += 16384;
            Bp += 32768;
            if (it < 3) {
                // prefetch kk = 4it+4, 4it+5
                LDSETA(Ap, 0,    a0_0, a0_1); LDSETB(Bp, 0,    b0_0, b0_1, b0_2, b0_3);
                LDSETA(Ap, 4096, a1_0, a1_1); LDSETB(Bp, 8192, b1_0, b1_1, b1_2, b1_3);
            }
            __builtin_amdgcn_s_setprio(1);
            MFMA8(a2_0, a2_1, b2_0, b2_1, b2_2, b2_3);   // kk = 4it+2
            MFMA8(a3_0, a3_1, b3_0, b3_1, b3_2, b3_3);   // kk = 4it+3
            __builtin_amdgcn_s_setprio(0);
        }

        // rowmax epilogue via LDS transpose (max associative -> exact)
        // C/D layout: col = lane&31, row = (r&3) + 8*(r>>2) + 4*hi
        #pragma unroll
        for (int mt = 0; mt < 2; ++mt) {
            #pragma unroll
            for (int r = 0; r < 16; ++r) {
                float m = fmaxf(fmaxf(acc[mt][0][r], acc[mt][1][r]),
                                fmaxf(acc[mt][2][r], acc[mt][3][r]));
                int row = wr * 64 + mt * 32 + (r & 3) + 8 * (r >> 2) + 4 * hi;
                pmx[row][wc * 32 + ln] = m;
            }
        }
        __syncthreads();
        if (tid < BM) {
            const float4* prow = reinterpret_cast<const float4*>(pmx[tid]);
            float m = -3.0e38f;
            #pragma unroll
            for (int j = 0; j < 16; ++j) {
                float4 v = prow[j];
                m = fmaxf(m, fmaxf(fmaxf(v.x, v.y), fmaxf(v.z, v.w)));
            }
            int grow = bRow * BM + tid;
            int b1 = grow / NP;
            int fb = (bRow * BM) / NP;
            float v0 = (b1 == fb) ? m : 0.0f;
            float v1 = (b1 != fb) ? m : 0.0f;
            #pragma unroll
            for (int off = 1; off < 64; off <<= 1) {
                v0 += __shfl_xor(v0, off, 64);
                v1 += __shfl_xor(v1, off, 64);
            }
            if (lane == 0) {
                atomicAdd(&sim12[fb * NB + b2], v0);
                int lb = (bRow * BM + BM - 1) / NP;
                if (lb != fb) atomicAdd(&sim12[lb * NB + b2], v1);
            }
        }
        return;
    }

    // =================== fp32-exact diagonal path ===================
    {
        const int q = bid & 3;             // 0..3 (row quarter)
        const int b = bid >> 2;            // 0..63
        const int r0 = q * 49;
        const int tx = tid & 15, ty = tid >> 4;

        float* As = reinterpret_cast<float*>(smem);
        float* Bs = As + 2176;
        unsigned long long* colP = reinterpret_cast<unsigned long long*>(smem);

        const float* Ap = t1 + (size_t)b * NP * ND;
        const float* Bp = t2 + (size_t)b * NP * ND;
        const float* ia = inv1 + b * NP;
        const float* ib = inv2 + b * NP;

        float acc[4][4][4];
        #pragma unroll
        for (int i = 0; i < 4; ++i)
            #pragma unroll
            for (int j = 0; j < 4; ++j)
                #pragma unroll
                for (int l = 0; l < 4; ++l) acc[i][j][l] = 0.0f;

        for (int kc = 0; kc < 8; ++kc) {
            __syncthreads();
            #pragma unroll
            for (int i = 0; i < 2; ++i) {
                int f4 = tid + 256 * i;            // 0..511
                int row = f4 >> 3, k4 = f4 & 7;
                float4 v = make_float4(0.f, 0.f, 0.f, 0.f);
                if (row < 49) {
                    v = *reinterpret_cast<const float4*>(Ap + (size_t)(r0 + row) * ND + kc * 32 + 4 * k4);
                    float s = ia[r0 + row];
                    v.x *= s; v.y *= s; v.z *= s; v.w *= s;
                }
                As[(4 * k4 + 0) * 68 + row] = v.x;
                As[(4 * k4 + 1) * 68 + row] = v.y;
                As[(4 * k4 + 2) * 68 + row] = v.z;
                As[(4 * k4 + 3) * 68 + row] = v.w;
            }
            #pragma unroll
            for (int i = 0; i < 8; ++i) {
                int f4 = tid + 256 * i;            // 0..2047
                int col = f4 >> 3, k4 = f4 & 7;
                float4 v = make_float4(0.f, 0.f, 0.f, 0.f);
                if (col < NP) {
                    v = *reinterpret_cast<const float4*>(Bp + (size_t)col * ND + kc * 32 + 4 * k4);
                    float s = ib[col];
                    v.x *= s; v.y *= s; v.z *= s; v.w *= s;
                }
                Bs[(4 * k4 + 0) * 260 + col] = v.x;
                Bs[(4 * k4 + 1) * 260 + col] = v.y;
                Bs[(4 * k4 + 2) * 260 + col] = v.z;
                Bs[(4 * k4 + 3) * 260 + col] = v.w;
            }
            __syncthreads();
            #pragma unroll 4
            for (int k = 0; k < 32; ++k) {
                float a0 = As[k * 68 + 4 * ty + 0];
                float a1 = As[k * 68 + 4 * ty + 1];
                float a2 = As[k * 68 + 4 * ty + 2];
                float a3 = As[k * 68 + 4 * ty + 3];
                float4 bq[4];
                #pragma unroll
                for (int j = 0; j < 4; ++j)
                    bq[j] = *reinterpret_cast<const float4*>(&Bs[k * 260 + 4 * tx + 64 * j]);
                #pragma unroll
                for (int j = 0; j < 4; ++j) {
                    acc[0][j][0] = fmaf(a0, bq[j].x, acc[0][j][0]);
                    acc[0][j][1] = fmaf(a0, bq[j].y, acc[0][j][1]);
                    acc[0][j][2] = fmaf(a0, bq[j].z, acc[0][j][2]);
                    acc[0][j][3] = fmaf(a0, bq[j].w, acc[0][j][3]);
                    acc[1][j][0] = fmaf(a1, bq[j].x, acc[1][j][0]);
                    acc[1][j][1] = fmaf(a1, bq[j].y, acc[1][j][1]);
                    acc[1][j][2] = fmaf(a1, bq[j].z, acc[1][j][2]);
                    acc[1][j][3] = fmaf(a1, bq[j].w, acc[1][j][3]);
                    acc[2][j][0] = fmaf(a2, bq[j].x, acc[2][j][0]);
                    acc[2][j][1] = fmaf(a2, bq[j].y, acc[2][j][1]);
                    acc[2][j][2] = fmaf(a2, bq[j].z, acc[2][j][2]);
                    acc[2][j][3] = fmaf(a2, bq[j].w, acc[2][j][3]);
                    acc[3][j][0] = fmaf(a3, bq[j].x, acc[3][j][0]);
                    acc[3][j][1] = fmaf(a3, bq[j].y, acc[3][j][1]);
                    acc[3][j][2] = fmaf(a3, bq[j].z, acc[3][j][2]);
                    acc[3][j][3] = fmaf(a3, bq[j].w, acc[3][j][3]);
                }
            }
        }

        // row argmax (idx_to_keep1_2)
        #pragma unroll
        for (int i = 0; i < 4; ++i) {
            unsigned long long best = 0ull;
            #pragma unroll
            for (int j = 0; j < 4; ++j)
                #pragma unroll
                for (int l = 0; l < 4; ++l) {
                    int c = 64 * j + 4 * tx + l;
                    if (c < NP) {
                        unsigned long long p = packVI(acc[i][j][l], c);
                        if (p > best) best = p;
                    }
                }
            #pragma unroll
            for (int off = 1; off < 16; off <<= 1) {
                unsigned long long o = __shfl_xor(best, off, 16);
                if (o > best) best = o;
            }
            int rl = 4 * ty + i;
            if (tx == 0 && rl < 49)
                out[1 + b * NP + r0 + rl] = (float)(unsigned int)(~best);
        }

        // col argmax partials (idx_to_keep2_1)
        __syncthreads();
        #pragma unroll
        for (int j = 0; j < 4; ++j)
            #pragma unroll
            for (int l = 0; l < 4; ++l) {
                unsigned long long best = 0ull;
                #pragma unroll
                for (int i = 0; i < 4; ++i) {
                    int rl = 4 * ty + i;
                    if (rl < 49) {
                        unsigned long long p = packVI(acc[i][j][l], r0 + rl);
                        if (p > best) best = p;
                    }
                }
                colP[ty * 256 + 64 * j + 4 * tx + l] = best;
            }
        __syncthreads();
        {
            unsigned long long best = 0ull;
            #pragma unroll
            for (int y = 0; y < 16; ++y) {
                unsigned long long o = colP[y * 256 + tid];
                if (o > best) best = o;
            }
            if (tid < NP) parts[(b * 4 + q) * NP + tid] = best;
        }
    }
}

// Kernel 3: merged fin (blocks 0..48) + loss (block 49).
__global__ void filip_finloss(const unsigned long long* __restrict__ parts,
                              const float* __restrict__ sim12,
                              float* __restrict__ out) {
    if (blockIdx.x < 49) {
        int id = blockIdx.x * 256 + threadIdx.x;   // 49*256 = 12544
        int b = id / NP, c = id - b * NP;
        unsigned long long best = 0ull;
        #pragma unroll
        for (int qq = 0; qq < 4; ++qq) {
            unsigned long long o = parts[(b * 4 + qq) * NP + c];
            if (o > best) best = o;
        }
        out[1 + NBP + id] = (float)(unsigned int)(~best);
    } else if (threadIdx.x < 64) {
        int i = threadIdx.x;  // 0..63
        const float SC = 10.0f / 196.0f;
        const float* row = sim12 + i * NB;
        float mx = -3.0e38f;
        for (int j = 0; j < NB; ++j) mx = fmaxf(mx, row[j] * SC);
        float s = 0.0f;
        for (int j = 0; j < NB; ++j) s += expf(row[j] * SC - mx);
        float lse = mx + logf(s);
        float li = lse - row[i] * SC;
        #pragma unroll
        for (int off = 32; off > 0; off >>= 1)
            li += __shfl_xor(li, off, 64);
        if (i == 0) out[0] = li / 64.0f;
    }
}

// ===========================================================================
// FALLBACK PATH (verbatim round-2, known-passing) — used if ws too small
// ===========================================================================
__global__ void filip_norms(const float* __restrict__ t1,
                            const float* __restrict__ t2,
                            float* __restrict__ inv1,
                            float* __restrict__ inv2,
                            float* __restrict__ sim12) {
    int row = blockIdx.x;
    int lane = threadIdx.x;
    if (row < NB) sim12[row * NB + lane] = 0.0f;
    const float* src; float* dst; int r;
    if (row < NBP) { src = t1; dst = inv1; r = row; }
    else           { src = t2; dst = inv2; r = row - NBP; }
    float4 v = reinterpret_cast<const float4*>(src + (size_t)r * ND)[lane];
    float ss = v.x * v.x + v.y * v.y + v.z * v.z + v.w * v.w;
    #pragma unroll
    for (int off = 32; off > 0; off >>= 1)
        ss += __shfl_xor(ss, off, 64);
    if (lane == 0)
        dst[r] = 1.0f / fmaxf(sqrtf(ss), 1e-12f);
}

__device__ __forceinline__ v8bf cvt8(float4 a, float4 b, float s) {
    v8bf v;
    v[0] = (__bf16)(a.x * s); v[1] = (__bf16)(a.y * s);
    v[2] = (__bf16)(a.z * s); v[3] = (__bf16)(a.w * s);
    v[4] = (__bf16)(b.x * s); v[5] = (__bf16)(b.y * s);
    v[6] = (__bf16)(b.z * s); v[7] = (__bf16)(b.w * s);
    return v;
}

#define BKF 64
__global__ __launch_bounds__(256, 2)
void filip_mfma(const float* __restrict__ t1, const float* __restrict__ t2,
                const float* __restrict__ inv1, const float* __restrict__ inv2,
                float* __restrict__ sim12)
{
    __shared__ unsigned short Asb[BM * BKF];
    __shared__ unsigned short Bsb[BN * BKF];
    __shared__ float rmx[2][BM];

    const int bRow = blockIdx.x;
    const int b2   = blockIdx.y;
    const int tid  = threadIdx.x;
    const int lane = tid & 63, wave = tid >> 6;
    const int wr = wave >> 1, wc = wave & 1;
    const int ln = lane & 31, hi = lane >> 5;

    const float* Abase = t1 + (size_t)bRow * BM * ND;
    const float* Bbase = t2 + (size_t)b2 * NP * ND;

    f32x16 acc[2][4];
    #pragma unroll
    for (int mt = 0; mt < 2; ++mt)
        #pragma unroll
        for (int nt = 0; nt < 4; ++nt)
            #pragma unroll
            for (int r = 0; r < 16; ++r) acc[mt][nt][r] = 0.0f;

    for (int kc = 0; kc < 4; ++kc) {
        __syncthreads();
        #pragma unroll
        for (int i = 0; i < 4; ++i) {
            int flat = (i * 256 + tid) * 8;
            int r = flat >> 6, k0 = flat & 63;
            const float* gp = Abase + (size_t)r * ND + kc * BKF + k0;
            float4 f0 = *reinterpret_cast<const float4*>(gp);
            float4 f1 = *reinterpret_cast<const float4*>(gp + 4);
            float s = inv1[bRow * BM + r];
            v8bf v = cvt8(f0, f1, s);
            int off = r * 128 + ((k0 * 2) ^ ((r & 7) << 4));
            *reinterpret_cast<v8bf*>(reinterpret_cast<char*>(Asb) + off) = v;
        }
        #pragma unroll
        for (int i = 0; i < 8; ++i) {
            int flat = (i * 256 + tid) * 8;
            int r = flat >> 6, k0 = flat & 63;
            v8bf v;
            if (r < NP) {
                const float* gp = Bbase + (size_t)r * ND + kc * BKF + k0;
                float4 f0 = *reinterpret_cast<const float4*>(gp);
                float4 f1 = *reinterpret_cast<const float4*>(gp + 4);
                float s = inv2[b2 * NP + r];
                v = cvt8(f0, f1, s);
            } else {
                #pragma unroll
                for (int j = 0; j < 8; ++j) v[j] = (__bf16)0.0f;
            }
            int off = r * 128 + ((k0 * 2) ^ ((r & 7) << 4));
            *reinterpret_cast<v8bf*>(reinterpret_cast<char*>(Bsb) + off) = v;
        }
        __syncthreads();
        #pragma unroll
        for (int ks = 0; ks < 4; ++ks) {
            const int kb = ks * 32 + hi * 16;
            v8bf af[2], bfr[4];
            #pragma unroll
            for (int mt = 0; mt < 2; ++mt) {
                int r = wr * 64 + mt * 32 + ln;
                af[mt] = *reinterpret_cast<const v8bf*>(
                    reinterpret_cast<const char*>(Asb) + r * 128 + (kb ^ ((r & 7) << 4)));
            }
            #pragma unroll
            for (int nt = 0; nt < 4; ++nt) {
                int c = wc * 128 + nt * 32 + ln;
                bfr[nt] = *reinterpret_cast<const v8bf*>(
                    reinterpret_cast<const char*>(Bsb) + c * 128 + (kb ^ ((c & 7) << 4)));
            }
            #pragma unroll
            for (int mt = 0; mt < 2; ++mt)
                #pragma unroll
                for (int nt = 0; nt < 4; ++nt)
                    acc[mt][nt] = __builtin_amdgcn_mfma_f32_32x32x16_bf16(
                        af[mt], bfr[nt], acc[mt][nt], 0, 0, 0);
        }
    }

    #pragma unroll
    for (int mt = 0; mt < 2; ++mt) {
        float t[16];
        #pragma unroll
        for (int r = 0; r < 16; ++r) {
            float m = fmaxf(fmaxf(acc[mt][0][r], acc[mt][1][r]),
                            fmaxf(acc[mt][2][r], acc[mt][3][r]));
            #pragma unroll
            for (int off = 1; off <= 16; off <<= 1)
                m = fmaxf(m, __shfl_xor(m, off, 64));
            t[r] = m;
        }
        if (ln == 0) {
            #pragma unroll
            for (int r = 0; r < 16; ++r) {
                int row = wr * 64 + mt * 32 + (r & 3) + 8 * (r >> 2) + 4 * hi;
                rmx[wc][row] = t[r];
            }
        }
    }
    __syncthreads();
    if (tid < BM) {
        float m = fmaxf(rmx[0][tid], rmx[1][tid]);
        int grow = bRow * BM + tid;
        int b1 = grow / NP;
        int fb = (bRow * BM) / NP;
        float v0 = (b1 == fb) ? m : 0.0f;
        float v1 = (b1 != fb) ? m : 0.0f;
        #pragma unroll
        for (int off = 1; off < 64; off <<= 1) {
            v0 += __shfl_xor(v0, off, 64);
            v1 += __shfl_xor(v1, off, 64);
        }
        if (lane == 0) {
            atomicAdd(&sim12[fb * NB + b2], v0);
            int lb = (bRow * BM + BM - 1) / NP;
            if (lb != fb) atomicAdd(&sim12[lb * NB + b2], v1);
        }
    }
}

__global__ __launch_bounds__(256)
void filip_diag(const float* __restrict__ t1, const float* __restrict__ t2,
                const float* __restrict__ inv1, const float* __restrict__ inv2,
                float* __restrict__ out)
{
    const int b = blockIdx.x;
    const int tid = threadIdx.x;
    const int tx = tid & 15, ty = tid >> 4;

    __shared__ float As2[16][209];
    __shared__ float Bs2[16][65];
    __shared__ float colV[16][65];
    __shared__ int   colI[16][65];

    const float* Ap = t1 + (size_t)b * NP * ND;
    const float* Bp = t2 + (size_t)b * NP * ND;
    const float* ia = inv1 + b * NP;
    const float* ib = inv2 + b * NP;

    float rmax[13];
    int   ridx[13];
    #pragma unroll
    for (int m = 0; m < 13; ++m) { rmax[m] = -3.0e38f; ridx[m] = 1 << 30; }

    for (int tile = 0; tile < 4; ++tile) {
        float acc[13][4];
        #pragma unroll
        for (int m = 0; m < 13; ++m)
            #pragma unroll
            for (int n = 0; n < 4; ++n) acc[m][n] = 0.0f;

        for (int kk = 0; kk < 16; ++kk) {
            __syncthreads();
            #pragma unroll
            for (int i = 0; i < 13; ++i) {
                int e = tid + 256 * i;
                int p1 = e >> 4, k = e & 15;
                float v = 0.0f;
                if (p1 < NP) v = Ap[p1 * ND + kk * 16 + k] * ia[p1];
                As2[k][p1] = v;
            }
            #pragma unroll
            for (int i = 0; i < 4; ++i) {
                int e = tid + 256 * i;
                int pl = e >> 4, k = e & 15;
                int p2 = tile * 64 + pl;
                float v = 0.0f;
                if (p2 < NP) v = Bp[p2 * ND + kk * 16 + k] * ib[p2];
                Bs2[k][pl] = v;
            }
            __syncthreads();
            #pragma unroll 4
            for (int k = 0; k < 16; ++k) {
                float a[13], bq[4];
                #pragma unroll
                for (int m = 0; m < 13; ++m) a[m] = As2[k][ty + 16 * m];
                #pragma unroll
                for (int n = 0; n < 4; ++n) bq[n] = Bs2[k][tx + 16 * n];
                #pragma unroll
                for (int m = 0; m < 13; ++m)
                    #pragma unroll
                    for (int n = 0; n < 4; ++n)
                        acc[m][n] = fmaf(a[m], bq[n], acc[m][n]);
            }
        }

        #pragma unroll
        for (int n = 0; n < 4; ++n) {
            int c = tile * 64 + tx + 16 * n;
            if (c < NP) {
                #pragma unroll
                for (int m = 0; m < 13; ++m) {
                    float v = acc[m][n];
                    if (v > rmax[m] || (v == rmax[m] && c < ridx[m])) {
                        rmax[m] = v; ridx[m] = c;
                    }
                }
            }
        }

        #pragma unroll
        for (int n = 0; n < 4; ++n) {
            float bv = -3.0e38f; int bi = 1 << 30;
            #pragma unroll
            for (int m = 0; m < 13; ++m) {
                int row = ty + 16 * m;
                if (row < NP) {
                    float v = acc[m][n];
                    if (v > bv || (v == bv && row < bi)) { bv = v; bi = row; }
                }
            }
            colV[ty][tx + 16 * n] = bv;
            colI[ty][tx + 16 * n] = bi;
        }
        __syncthreads();
        if (tid < 64) {
            int c = tile * 64 + tid;
            if (c < NP) {
                float bv = -3.0e38f; int bi = 1 << 30;
                #pragma unroll
                for (int y = 0; y < 16; ++y) {
                    float v = colV[y][tid]; int i2 = colI[y][tid];
                    if (v > bv || (v == bv && i2 < bi)) { bv = v; bi = i2; }
                }
                out[1 + NBP + b * NP + c] = (float)bi;
            }
        }
        __syncthreads();
    }

    #pragma unroll
    for (int m = 0; m < 13; ++m) {
        float v = rmax[m]; int ix = ridx[m];
        #pragma unroll
        for (int off = 1; off < 16; off <<= 1) {
            float ov = __shfl_xor(v, off, 16);
            int   oi = __shfl_xor(ix, off, 16);
            if (ov > v || (ov == v && oi < ix)) { v = ov; ix = oi; }
        }
        rmax[m] = v; ridx[m] = ix;
    }
    if (tx == 0) {
        #pragma unroll
        for (int m = 0; m < 13; ++m) {
            int row = ty + 16 * m;
            if (row < NP) out[1 + b * NP + row] = (float)ridx[m];
        }
    }
}

__global__ void filip_loss(const float* __restrict__ sim12,
                           float* __restrict__ out) {
    int i = threadIdx.x;  // 0..63
    const float SC = 10.0f / 196.0f;
    const float* row = sim12 + i * NB;
    float mx = -3.0e38f;
    for (int j = 0; j < NB; ++j) mx = fmaxf(mx, row[j] * SC);
    float s = 0.0f;
    for (int j = 0; j < NB; ++j) s += expf(row[j] * SC - mx);
    float lse = mx + logf(s);
    float li = lse - row[i] * SC;
    #pragma unroll
    for (int off = 32; off > 0; off >>= 1)
        li += __shfl_xor(li, off, 64);
    if (i == 0) out[0] = li / 64.0f;
}

// ---------------------------------------------------------------------------
extern "C" void kernel_launch(void* const* d_in, const int* in_sizes, int n_in,
                              void* d_out, int out_size, void* d_ws, size_t ws_size,
                              hipStream_t stream) {
    const float* t1 = (const float*)d_in[0];
    const float* t2 = (const float*)d_in[1];
    float* out = (float*)d_out;
    float* ws  = (float*)d_ws;

    float* inv1  = ws;
    float* inv2  = ws + NBP;
    float* sim12 = ws + 2 * NBP;

    if (ws_size >= (size_t)WS_NEED) {
        char* t1fl = (char*)d_ws + WS_T1FL;
        char* t2fl = (char*)d_ws + WS_T2FL;
        unsigned long long* parts = (unsigned long long*)((char*)d_ws + WS_PARTS);

        filip_prep5<<<(NBP + NB * 256) / 4, 256, 0, stream>>>(t1, t2, inv1, inv2, sim12, t1fl, t2fl);
        filip_mega<<<6528, 256, 0, stream>>>(t1fl, t2fl, sim12, t1, t2, inv1, inv2, parts, out);
        filip_finloss<<<50, 256, 0, stream>>>(parts, sim12, out);
    } else {
        filip_norms<<<2 * NBP, 64, 0, stream>>>(t1, t2, inv1, inv2, sim12);
        filip_mfma<<<dim3(98, NB), 256, 0, stream>>>(t1, t2, inv1, inv2, sim12);
        filip_diag<<<NB, 256, 0, stream>>>(t1, t2, inv1, inv2, out);
        filip_loss<<<1, 64, 0, stream>>>(sim12, out);
    }
}

// Round 12
// 135.363 us; speedup vs baseline: 2.7578x; 1.1513x over previous
//
#include <hip/hip_runtime.h>
#include <math.h>

#define NB 64
#define NP 196
#define ND 256
#define NBP (NB * NP)   // 12544

typedef __bf16 v8bf __attribute__((ext_vector_type(8)));
typedef float f32x16 __attribute__((ext_vector_type(16)));

// ws layout (fast path), bytes:
//   inv1   @ 0        : 12544 f32
//   inv2   @ 50176    : 12544 f32
//   sim12  @ 100352   : 4096  f32
//   t1q    @ 116736   : 98 tiles  x fp8 fragment-linear [kkp8][hi2][row128][16B] = 3211264 B
//   t2q    @ 3328000  : 64 panels x fp8 fragment-linear [kkp8][hi2][col256][16B] = 4194304 B
//   parts  @ 7522304  : 64*4*196 u64 = 401408 B
#define WS_T1Q    116736
#define WS_T2Q    3328000
#define WS_PARTS  7522304
#define WS_NEED   7923712

// ---------------------------------------------------------------------------
// packed (value,index) for argmax with np first-occurrence tie-break
// ---------------------------------------------------------------------------
__device__ __forceinline__ unsigned int fmono(float v) {
    unsigned int u = __float_as_uint(v);
    return (u & 0x80000000u) ? ~u : (u | 0x80000000u);
}
__device__ __forceinline__ unsigned long long packVI(float v, int idx) {
    return ((unsigned long long)fmono(v) << 32) | (unsigned int)(~idx);
}

// ===========================================================================
// FAST PATH
// ===========================================================================

// Kernel 1: per-row norm -> inv arrays; write normalized FP8 (e4m3, via
// v_cvt_pk_fp8_f32) in fragment-linear layout. Per 16B granule: two K-steps
// (even kk in bytes 0..7, odd kk in bytes 8..15) so the GEMM loads one 16B
// ulonglong2 per fragment-PAIR. Lane L holds k = 4L..4L+3:
//   kkp=(L>>3), odd=(L>>2)&1, hi=(L>>1)&1, j0=(L&1)*4.
__global__ __launch_bounds__(256)
void filip_prep6(const float* __restrict__ t1, const float* __restrict__ t2,
                 float* __restrict__ inv1, float* __restrict__ inv2,
                 float* __restrict__ sim12,
                 char* __restrict__ t1q, char* __restrict__ t2q) {
    const int tid = threadIdx.x;
    if (blockIdx.x == 0) {
        float4 z = make_float4(0.f, 0.f, 0.f, 0.f);
        float4* s4 = reinterpret_cast<float4*>(sim12);
        #pragma unroll
        for (int j = 0; j < 4; ++j) s4[tid * 4 + j] = z;
    }
    int id = blockIdx.x * 4 + (tid >> 6);   // 0 .. NBP + NB*256 - 1
    int L = tid & 63;
    int kkp = L >> 3, odd = (L >> 2) & 1, hi = (L >> 1) & 1, j0 = (L & 1) * 4;
    if (id < NBP) {
        const float* src = t1 + (size_t)id * ND;
        float4 v = reinterpret_cast<const float4*>(src)[L];
        float ss = v.x * v.x + v.y * v.y + v.z * v.z + v.w * v.w;
        #pragma unroll
        for (int off = 32; off > 0; off >>= 1) ss += __shfl_xor(ss, off, 64);
        float inv = 1.0f / fmaxf(sqrtf(ss), 1e-12f);
        if (L == 0) inv1[id] = inv;
        int w0 = __builtin_amdgcn_cvt_pk_fp8_f32(v.x * inv, v.y * inv, 0, false);
        int w  = __builtin_amdgcn_cvt_pk_fp8_f32(v.z * inv, v.w * inv, w0, true);
        int t = id >> 7, r = id & 127;
        *reinterpret_cast<int*>(t1q + (size_t)t * 32768 + kkp * 4096 + hi * 2048
                                + r * 16 + odd * 8 + j0) = w;
    } else {
        int pid = id - NBP;          // 0..16383
        int b2 = pid >> 8, c = pid & 255;
        char* dst = t2q + (size_t)b2 * 65536 + kkp * 8192 + hi * 4096
                    + c * 16 + odd * 8 + j0;
        if (c < NP) {
            const float* src = t2 + (size_t)(b2 * NP + c) * ND;
            float4 v = reinterpret_cast<const float4*>(src)[L];
            float ss = v.x * v.x + v.y * v.y + v.z * v.z + v.w * v.w;
            #pragma unroll
            for (int off = 32; off > 0; off >>= 1) ss += __shfl_xor(ss, off, 64);
            float inv = 1.0f / fmaxf(sqrtf(ss), 1e-12f);
            if (L == 0) inv2[b2 * NP + c] = inv;
            int w0 = __builtin_amdgcn_cvt_pk_fp8_f32(v.x * inv, v.y * inv, 0, false);
            int w  = __builtin_amdgcn_cvt_pk_fp8_f32(v.z * inv, v.w * inv, w0, true);
            *reinterpret_cast<int*>(dst) = w;
        } else {
            *reinterpret_cast<int*>(dst) = 0;   // fp8 zeros
        }
    }
}

#define BM 128
#define BN 256

// 8 MFMAs (2 mt x 4 nt) for one K-step; args are i64 fp8 operands
#define QMFMA8(A0, A1, B0, B1, B2, B3)                                                 \
    acc[0][0] = __builtin_amdgcn_mfma_f32_32x32x16_fp8_fp8((long)(A0), (long)(B0), acc[0][0], 0, 0, 0); \
    acc[0][1] = __builtin_amdgcn_mfma_f32_32x32x16_fp8_fp8((long)(A0), (long)(B1), acc[0][1], 0, 0, 0); \
    acc[0][2] = __builtin_amdgcn_mfma_f32_32x32x16_fp8_fp8((long)(A0), (long)(B2), acc[0][2], 0, 0, 0); \
    acc[0][3] = __builtin_amdgcn_mfma_f32_32x32x16_fp8_fp8((long)(A0), (long)(B3), acc[0][3], 0, 0, 0); \
    acc[1][0] = __builtin_amdgcn_mfma_f32_32x32x16_fp8_fp8((long)(A1), (long)(B0), acc[1][0], 0, 0, 0); \
    acc[1][1] = __builtin_amdgcn_mfma_f32_32x32x16_fp8_fp8((long)(A1), (long)(B1), acc[1][1], 0, 0, 0); \
    acc[1][2] = __builtin_amdgcn_mfma_f32_32x32x16_fp8_fp8((long)(A1), (long)(B2), acc[1][2], 0, 0, 0); \
    acc[1][3] = __builtin_amdgcn_mfma_f32_32x32x16_fp8_fp8((long)(A1), (long)(B3), acc[1][3], 0, 0, 0);

// one superstep set = 2 K-steps: even kk in .x, odd kk in .y
#define QMFMA_SET(SA0, SA1, SB0, SB1, SB2, SB3)                      \
    QMFMA8(SA0.x, SA1.x, SB0.x, SB1.x, SB2.x, SB3.x);                \
    QMFMA8(SA0.y, SA1.y, SB0.y, SB1.y, SB2.y, SB3.y);

#define LDQA(P, OFF, X0, X1)                                           \
    X0 = *reinterpret_cast<const ulonglong2*>(P + (OFF));              \
    X1 = *reinterpret_cast<const ulonglong2*>(P + (OFF) + 512);
#define LDQB(P, OFF, X0, X1, X2, X3)                                   \
    X0 = *reinterpret_cast<const ulonglong2*>(P + (OFF));              \
    X1 = *reinterpret_cast<const ulonglong2*>(P + (OFF) + 512);        \
    X2 = *reinterpret_cast<const ulonglong2*>(P + (OFF) + 1024);       \
    X3 = *reinterpret_cast<const ulonglong2*>(P + (OFF) + 1536);

// Kernel 2 (MEGA): blocks [0,256) = fp32-exact diagonal argmax (overlaps the
// GEMM); blocks [256, 6528) = zero-LDS FP8 MFMA GEMM, 4 superstep sets
// (2 kk each), 2-superstep prefetch distance, setprio around MFMA clusters.
__global__ __launch_bounds__(256, 2)
void filip_mega(const char* __restrict__ t1q, const char* __restrict__ t2q,
                float* __restrict__ sim12,
                const float* __restrict__ t1, const float* __restrict__ t2,
                const float* __restrict__ inv1, const float* __restrict__ inv2,
                unsigned long long* __restrict__ parts,
                float* __restrict__ out)
{
    __shared__ __align__(16) char smem[41984];
    const int bid = blockIdx.x;
    const int tid = threadIdx.x;

    if (bid >= 256) {
        // =================== FP8 MFMA GEMM path ===================
        float (*pmx)[68] = reinterpret_cast<float (*)[68]>(smem);

        int n = bid - 256;                      // 0..6271
        int x = n & 7, local = n >> 3;
        const int bRow = local >> 3;            // 0..97
        const int b2   = x * 8 + (local & 7);   // 0..63

        const int lane = tid & 63, wave = tid >> 6;
        const int wr = wave >> 1, wc = wave & 1;
        const int ln = lane & 31, hi = lane >> 5;

        const char* Ap = t1q + (size_t)bRow * 32768 + hi * 2048 + (wr * 64 + ln) * 16;
        const char* Bp = t2q + (size_t)b2 * 65536 + hi * 4096 + (wc * 128 + ln) * 16;

        f32x16 acc[2][4];
        #pragma unroll
        for (int mt = 0; mt < 2; ++mt)
            #pragma unroll
            for (int nt = 0; nt < 4; ++nt)
                #pragma unroll
                for (int r = 0; r < 16; ++r) acc[mt][nt][r] = 0.0f;

        ulonglong2 s0a0, s0a1, s0b0, s0b1, s0b2, s0b3;
        ulonglong2 s1a0, s1a1, s1b0, s1b1, s1b2, s1b3;
        ulonglong2 s2a0, s2a1, s2b0, s2b1, s2b2, s2b3;
        ulonglong2 s3a0, s3a1, s3b0, s3b1, s3b2, s3b3;

        // prologue: supersteps 0,1 (kk 0..3)
        LDQA(Ap, 0,    s0a0, s0a1); LDQB(Bp, 0,    s0b0, s0b1, s0b2, s0b3);
        LDQA(Ap, 4096, s1a0, s1a1); LDQB(Bp, 8192, s1b0, s1b1, s1b2, s1b3);

        #pragma unroll 1
        for (int it = 0; it < 2; ++it) {
            // prefetch supersteps 4it+2, 4it+3
            LDQA(Ap, 8192,  s2a0, s2a1); LDQB(Bp, 16384, s2b0, s2b1, s2b2, s2b3);
            LDQA(Ap, 12288, s3a0, s3a1); LDQB(Bp, 24576, s3b0, s3b1, s3b2, s3b3);
            __builtin_amdgcn_s_setprio(1);
            QMFMA_SET(s0a0, s0a1, s0b0, s0b1, s0b2, s0b3);   // kk 8it .. 8it+1
            QMFMA_SET(s1a0, s1a1, s1b0, s1b1, s1b2, s1b3);   // kk 8it+2 .. +3
            __builtin_amdgcn_s_setprio(0);
            Ap += 16384;
            Bp += 32768;
            if (it < 1) {
                LDQA(Ap, 0,    s0a0, s0a1); LDQB(Bp, 0,    s0b0, s0b1, s0b2, s0b3);
                LDQA(Ap, 4096, s1a0, s1a1); LDQB(Bp, 8192, s1b0, s1b1, s1b2, s1b3);
            }
            __builtin_amdgcn_s_setprio(1);
            QMFMA_SET(s2a0, s2a1, s2b0, s2b1, s2b2, s2b3);   // kk 8it+4 .. +5
            QMFMA_SET(s3a0, s3a1, s3b0, s3b1, s3b2, s3b3);   // kk 8it+6 .. +7
            __builtin_amdgcn_s_setprio(0);
        }

        // rowmax epilogue via LDS transpose (max associative -> exact)
        // C/D layout (dtype-independent): col = lane&31, row = (r&3)+8*(r>>2)+4*hi
        #pragma unroll
        for (int mt = 0; mt < 2; ++mt) {
            #pragma unroll
            for (int r = 0; r < 16; ++r) {
                float m = fmaxf(fmaxf(acc[mt][0][r], acc[mt][1][r]),
                                fmaxf(acc[mt][2][r], acc[mt][3][r]));
                int row = wr * 64 + mt * 32 + (r & 3) + 8 * (r >> 2) + 4 * hi;
                pmx[row][wc * 32 + ln] = m;
            }
        }
        __syncthreads();
        if (tid < BM) {
            const float4* prow = reinterpret_cast<const float4*>(pmx[tid]);
            float m = -3.0e38f;
            #pragma unroll
            for (int j = 0; j < 16; ++j) {
                float4 v = prow[j];
                m = fmaxf(m, fmaxf(fmaxf(v.x, v.y), fmaxf(v.z, v.w)));
            }
            int grow = bRow * BM + tid;
            int b1 = grow / NP;
            int fb = (bRow * BM) / NP;
            float v0 = (b1 == fb) ? m : 0.0f;
            float v1 = (b1 != fb) ? m : 0.0f;
            #pragma unroll
            for (int off = 1; off < 64; off <<= 1) {
                v0 += __shfl_xor(v0, off, 64);
                v1 += __shfl_xor(v1, off, 64);
            }
            if (lane == 0) {
                atomicAdd(&sim12[fb * NB + b2], v0);
                int lb = (bRow * BM + BM - 1) / NP;
                if (lb != fb) atomicAdd(&sim12[lb * NB + b2], v1);
            }
        }
        return;
    }

    // =================== fp32-exact diagonal path ===================
    {
        const int q = bid & 3;             // 0..3 (row quarter)
        const int b = bid >> 2;            // 0..63
        const int r0 = q * 49;
        const int tx = tid & 15, ty = tid >> 4;

        float* As = reinterpret_cast<float*>(smem);
        float* Bs = As + 2176;
        unsigned long long* colP = reinterpret_cast<unsigned long long*>(smem);

        const float* Ap = t1 + (size_t)b * NP * ND;
        const float* Bp = t2 + (size_t)b * NP * ND;
        const float* ia = inv1 + b * NP;
        const float* ib = inv2 + b * NP;

        float acc[4][4][4];
        #pragma unroll
        for (int i = 0; i < 4; ++i)
            #pragma unroll
            for (int j = 0; j < 4; ++j)
                #pragma unroll
                for (int l = 0; l < 4; ++l) acc[i][j][l] = 0.0f;

        for (int kc = 0; kc < 8; ++kc) {
            __syncthreads();
            #pragma unroll
            for (int i = 0; i < 2; ++i) {
                int f4 = tid + 256 * i;            // 0..511
                int row = f4 >> 3, k4 = f4 & 7;
                float4 v = make_float4(0.f, 0.f, 0.f, 0.f);
                if (row < 49) {
                    v = *reinterpret_cast<const float4*>(Ap + (size_t)(r0 + row) * ND + kc * 32 + 4 * k4);
                    float s = ia[r0 + row];
                    v.x *= s; v.y *= s; v.z *= s; v.w *= s;
                }
                As[(4 * k4 + 0) * 68 + row] = v.x;
                As[(4 * k4 + 1) * 68 + row] = v.y;
                As[(4 * k4 + 2) * 68 + row] = v.z;
                As[(4 * k4 + 3) * 68 + row] = v.w;
            }
            #pragma unroll
            for (int i = 0; i < 8; ++i) {
                int f4 = tid + 256 * i;            // 0..2047
                int col = f4 >> 3, k4 = f4 & 7;
                float4 v = make_float4(0.f, 0.f, 0.f, 0.f);
                if (col < NP) {
                    v = *reinterpret_cast<const float4*>(Bp + (size_t)col * ND + kc * 32 + 4 * k4);
                    float s = ib[col];
                    v.x *= s; v.y *= s; v.z *= s; v.w *= s;
                }
                Bs[(4 * k4 + 0) * 260 + col] = v.x;
                Bs[(4 * k4 + 1) * 260 + col] = v.y;
                Bs[(4 * k4 + 2) * 260 + col] = v.z;
                Bs[(4 * k4 + 3) * 260 + col] = v.w;
            }
            __syncthreads();
            #pragma unroll 4
            for (int k = 0; k < 32; ++k) {
                float a0 = As[k * 68 + 4 * ty + 0];
                float a1 = As[k * 68 + 4 * ty + 1];
                float a2 = As[k * 68 + 4 * ty + 2];
                float a3 = As[k * 68 + 4 * ty + 3];
                float4 bq[4];
                #pragma unroll
                for (int j = 0; j < 4; ++j)
                    bq[j] = *reinterpret_cast<const float4*>(&Bs[k * 260 + 4 * tx + 64 * j]);
                #pragma unroll
                for (int j = 0; j < 4; ++j) {
                    acc[0][j][0] = fmaf(a0, bq[j].x, acc[0][j][0]);
                    acc[0][j][1] = fmaf(a0, bq[j].y, acc[0][j][1]);
                    acc[0][j][2] = fmaf(a0, bq[j].z, acc[0][j][2]);
                    acc[0][j][3] = fmaf(a0, bq[j].w, acc[0][j][3]);
                    acc[1][j][0] = fmaf(a1, bq[j].x, acc[1][j][0]);
                    acc[1][j][1] = fmaf(a1, bq[j].y, acc[1][j][1]);
                    acc[1][j][2] = fmaf(a1, bq[j].z, acc[1][j][2]);
                    acc[1][j][3] = fmaf(a1, bq[j].w, acc[1][j][3]);
                    acc[2][j][0] = fmaf(a2, bq[j].x, acc[2][j][0]);
                    acc[2][j][1] = fmaf(a2, bq[j].y, acc[2][j][1]);
                    acc[2][j][2] = fmaf(a2, bq[j].z, acc[2][j][2]);
                    acc[2][j][3] = fmaf(a2, bq[j].w, acc[2][j][3]);
                    acc[3][j][0] = fmaf(a3, bq[j].x, acc[3][j][0]);
                    acc[3][j][1] = fmaf(a3, bq[j].y, acc[3][j][1]);
                    acc[3][j][2] = fmaf(a3, bq[j].z, acc[3][j][2]);
                    acc[3][j][3] = fmaf(a3, bq[j].w, acc[3][j][3]);
                }
            }
        }

        // row argmax (idx_to_keep1_2)
        #pragma unroll
        for (int i = 0; i < 4; ++i) {
            unsigned long long best = 0ull;
            #pragma unroll
            for (int j = 0; j < 4; ++j)
                #pragma unroll
                for (int l = 0; l < 4; ++l) {
                    int c = 64 * j + 4 * tx + l;
                    if (c < NP) {
                        unsigned long long p = packVI(acc[i][j][l], c);
                        if (p > best) best = p;
                    }
                }
            #pragma unroll
            for (int off = 1; off < 16; off <<= 1) {
                unsigned long long o = __shfl_xor(best, off, 16);
                if (o > best) best = o;
            }
            int rl = 4 * ty + i;
            if (tx == 0 && rl < 49)
                out[1 + b * NP + r0 + rl] = (float)(unsigned int)(~best);
        }

        // col argmax partials (idx_to_keep2_1)
        __syncthreads();
        #pragma unroll
        for (int j = 0; j < 4; ++j)
            #pragma unroll
            for (int l = 0; l < 4; ++l) {
                unsigned long long best = 0ull;
                #pragma unroll
                for (int i = 0; i < 4; ++i) {
                    int rl = 4 * ty + i;
                    if (rl < 49) {
                        unsigned long long p = packVI(acc[i][j][l], r0 + rl);
                        if (p > best) best = p;
                    }
                }
                colP[ty * 256 + 64 * j + 4 * tx + l] = best;
            }
        __syncthreads();
        {
            unsigned long long best = 0ull;
            #pragma unroll
            for (int y = 0; y < 16; ++y) {
                unsigned long long o = colP[y * 256 + tid];
                if (o > best) best = o;
            }
            if (tid < NP) parts[(b * 4 + q) * NP + tid] = best;
        }
    }
}

// Kernel 3: merged fin (blocks 0..48) + loss (block 49).
__global__ void filip_finloss(const unsigned long long* __restrict__ parts,
                              const float* __restrict__ sim12,
                              float* __restrict__ out) {
    if (blockIdx.x < 49) {
        int id = blockIdx.x * 256 + threadIdx.x;   // 49*256 = 12544
        int b = id / NP, c = id - b * NP;
        unsigned long long best = 0ull;
        #pragma unroll
        for (int qq = 0; qq < 4; ++qq) {
            unsigned long long o = parts[(b * 4 + qq) * NP + c];
            if (o > best) best = o;
        }
        out[1 + NBP + id] = (float)(unsigned int)(~best);
    } else if (threadIdx.x < 64) {
        int i = threadIdx.x;  // 0..63
        const float SC = 10.0f / 196.0f;
        const float* row = sim12 + i * NB;
        float mx = -3.0e38f;
        for (int j = 0; j < NB; ++j) mx = fmaxf(mx, row[j] * SC);
        float s = 0.0f;
        for (int j = 0; j < NB; ++j) s += expf(row[j] * SC - mx);
        float lse = mx + logf(s);
        float li = lse - row[i] * SC;
        #pragma unroll
        for (int off = 32; off > 0; off >>= 1)
            li += __shfl_xor(li, off, 64);
        if (i == 0) out[0] = li / 64.0f;
    }
}

// ===========================================================================
// FALLBACK PATH (verbatim round-2, known-passing) — used if ws too small
// ===========================================================================
__global__ void filip_norms(const float* __restrict__ t1,
                            const float* __restrict__ t2,
                            float* __restrict__ inv1,
                            float* __restrict__ inv2,
                            float* __restrict__ sim12) {
    int row = blockIdx.x;
    int lane = threadIdx.x;
    if (row < NB) sim12[row * NB + lane] = 0.0f;
    const float* src; float* dst; int r;
    if (row < NBP) { src = t1; dst = inv1; r = row; }
    else           { src = t2; dst = inv2; r = row - NBP; }
    float4 v = reinterpret_cast<const float4*>(src + (size_t)r * ND)[lane];
    float ss = v.x * v.x + v.y * v.y + v.z * v.z + v.w * v.w;
    #pragma unroll
    for (int off = 32; off > 0; off >>= 1)
        ss += __shfl_xor(ss, off, 64);
    if (lane == 0)
        dst[r] = 1.0f / fmaxf(sqrtf(ss), 1e-12f);
}

__device__ __forceinline__ v8bf cvt8(float4 a, float4 b, float s) {
    v8bf v;
    v[0] = (__bf16)(a.x * s); v[1] = (__bf16)(a.y * s);
    v[2] = (__bf16)(a.z * s); v[3] = (__bf16)(a.w * s);
    v[4] = (__bf16)(b.x * s); v[5] = (__bf16)(b.y * s);
    v[6] = (__bf16)(b.z * s); v[7] = (__bf16)(b.w * s);
    return v;
}

#define BKF 64
__global__ __launch_bounds__(256, 2)
void filip_mfma(const float* __restrict__ t1, const float* __restrict__ t2,
                const float* __restrict__ inv1, const float* __restrict__ inv2,
                float* __restrict__ sim12)
{
    __shared__ unsigned short Asb[BM * BKF];
    __shared__ unsigned short Bsb[BN * BKF];
    __shared__ float rmx[2][BM];

    const int bRow = blockIdx.x;
    const int b2   = blockIdx.y;
    const int tid  = threadIdx.x;
    const int lane = tid & 63, wave = tid >> 6;
    const int wr = wave >> 1, wc = wave & 1;
    const int ln = lane & 31, hi = lane >> 5;

    const float* Abase = t1 + (size_t)bRow * BM * ND;
    const float* Bbase = t2 + (size_t)b2 * NP * ND;

    f32x16 acc[2][4];
    #pragma unroll
    for (int mt = 0; mt < 2; ++mt)
        #pragma unroll
        for (int nt = 0; nt < 4; ++nt)
            #pragma unroll
            for (int r = 0; r < 16; ++r) acc[mt][nt][r] = 0.0f;

    for (int kc = 0; kc < 4; ++kc) {
        __syncthreads();
        #pragma unroll
        for (int i = 0; i < 4; ++i) {
            int flat = (i * 256 + tid) * 8;
            int r = flat >> 6, k0 = flat & 63;
            const float* gp = Abase + (size_t)r * ND + kc * BKF + k0;
            float4 f0 = *reinterpret_cast<const float4*>(gp);
            float4 f1 = *reinterpret_cast<const float4*>(gp + 4);
            float s = inv1[bRow * BM + r];
            v8bf v = cvt8(f0, f1, s);
            int off = r * 128 + ((k0 * 2) ^ ((r & 7) << 4));
            *reinterpret_cast<v8bf*>(reinterpret_cast<char*>(Asb) + off) = v;
        }
        #pragma unroll
        for (int i = 0; i < 8; ++i) {
            int flat = (i * 256 + tid) * 8;
            int r = flat >> 6, k0 = flat & 63;
            v8bf v;
            if (r < NP) {
                const float* gp = Bbase + (size_t)r * ND + kc * BKF + k0;
                float4 f0 = *reinterpret_cast<const float4*>(gp);
                float4 f1 = *reinterpret_cast<const float4*>(gp + 4);
                float s = inv2[b2 * NP + r];
                v = cvt8(f0, f1, s);
            } else {
                #pragma unroll
                for (int j = 0; j < 8; ++j) v[j] = (__bf16)0.0f;
            }
            int off = r * 128 + ((k0 * 2) ^ ((r & 7) << 4));
            *reinterpret_cast<v8bf*>(reinterpret_cast<char*>(Bsb) + off) = v;
        }
        __syncthreads();
        #pragma unroll
        for (int ks = 0; ks < 4; ++ks) {
            const int kb = ks * 32 + hi * 16;
            v8bf af[2], bfr[4];
            #pragma unroll
            for (int mt = 0; mt < 2; ++mt) {
                int r = wr * 64 + mt * 32 + ln;
                af[mt] = *reinterpret_cast<const v8bf*>(
                    reinterpret_cast<const char*>(Asb) + r * 128 + (kb ^ ((r & 7) << 4)));
            }
            #pragma unroll
            for (int nt = 0; nt < 4; ++nt) {
                int c = wc * 128 + nt * 32 + ln;
                bfr[nt] = *reinterpret_cast<const v8bf*>(
                    reinterpret_cast<const char*>(Bsb) + c * 128 + (kb ^ ((c & 7) << 4)));
            }
            #pragma unroll
            for (int mt = 0; mt < 2; ++mt)
                #pragma unroll
                for (int nt = 0; nt < 4; ++nt)
                    acc[mt][nt] = __builtin_amdgcn_mfma_f32_32x32x16_bf16(
                        af[mt], bfr[nt], acc[mt][nt], 0, 0, 0);
        }
    }

    #pragma unroll
    for (int mt = 0; mt < 2; ++mt) {
        float t[16];
        #pragma unroll
        for (int r = 0; r < 16; ++r) {
            float m = fmaxf(fmaxf(acc[mt][0][r], acc[mt][1][r]),
                            fmaxf(acc[mt][2][r], acc[mt][3][r]));
            #pragma unroll
            for (int off = 1; off <= 16; off <<= 1)
                m = fmaxf(m, __shfl_xor(m, off, 64));
            t[r] = m;
        }
        if (ln == 0) {
            #pragma unroll
            for (int r = 0; r < 16; ++r) {
                int row = wr * 64 + mt * 32 + (r & 3) + 8 * (r >> 2) + 4 * hi;
                rmx[wc][row] = t[r];
            }
        }
    }
    __syncthreads();
    if (tid < BM) {
        float m = fmaxf(rmx[0][tid], rmx[1][tid]);
        int grow = bRow * BM + tid;
        int b1 = grow / NP;
        int fb = (bRow * BM) / NP;
        float v0 = (b1 == fb) ? m : 0.0f;
        float v1 = (b1 != fb) ? m : 0.0f;
        #pragma unroll
        for (int off = 1; off < 64; off <<= 1) {
            v0 += __shfl_xor(v0, off, 64);
            v1 += __shfl_xor(v1, off, 64);
        }
        if (lane == 0) {
            atomicAdd(&sim12[fb * NB + b2], v0);
            int lb = (bRow * BM + BM - 1) / NP;
            if (lb != fb) atomicAdd(&sim12[lb * NB + b2], v1);
        }
    }
}

__global__ __launch_bounds__(256)
void filip_diag(const float* __restrict__ t1, const float* __restrict__ t2,
                const float* __restrict__ inv1, const float* __restrict__ inv2,
                float* __restrict__ out)
{
    const int b = blockIdx.x;
    const int tid = threadIdx.x;
    const int tx = tid & 15, ty = tid >> 4;

    __shared__ float As2[16][209];
    __shared__ float Bs2[16][65];
    __shared__ float colV[16][65];
    __shared__ int   colI[16][65];

    const float* Ap = t1 + (size_t)b * NP * ND;
    const float* Bp = t2 + (size_t)b * NP * ND;
    const float* ia = inv1 + b * NP;
    const float* ib = inv2 + b * NP;

    float rmax[13];
    int   ridx[13];
    #pragma unroll
    for (int m = 0; m < 13; ++m) { rmax[m] = -3.0e38f; ridx[m] = 1 << 30; }

    for (int tile = 0; tile < 4; ++tile) {
        float acc[13][4];
        #pragma unroll
        for (int m = 0; m < 13; ++m)
            #pragma unroll
            for (int n = 0; n < 4; ++n) acc[m][n] = 0.0f;

        for (int kk = 0; kk < 16; ++kk) {
            __syncthreads();
            #pragma unroll
            for (int i = 0; i < 13; ++i) {
                int e = tid + 256 * i;
                int p1 = e >> 4, k = e & 15;
                float v = 0.0f;
                if (p1 < NP) v = Ap[p1 * ND + kk * 16 + k] * ia[p1];
                As2[k][p1] = v;
            }
            #pragma unroll
            for (int i = 0; i < 4; ++i) {
                int e = tid + 256 * i;
                int pl = e >> 4, k = e & 15;
                int p2 = tile * 64 + pl;
                float v = 0.0f;
                if (p2 < NP) v = Bp[p2 * ND + kk * 16 + k] * ib[p2];
                Bs2[k][pl] = v;
            }
            __syncthreads();
            #pragma unroll 4
            for (int k = 0; k < 16; ++k) {
                float a[13], bq[4];
                #pragma unroll
                for (int m = 0; m < 13; ++m) a[m] = As2[k][ty + 16 * m];
                #pragma unroll
                for (int n = 0; n < 4; ++n) bq[n] = Bs2[k][tx + 16 * n];
                #pragma unroll
                for (int m = 0; m < 13; ++m)
                    #pragma unroll
                    for (int n = 0; n < 4; ++n)
                        acc[m][n] = fmaf(a[m], bq[n], acc[m][n]);
            }
        }

        #pragma unroll
        for (int n = 0; n < 4; ++n) {
            int c = tile * 64 + tx + 16 * n;
            if (c < NP) {
                #pragma unroll
                for (int m = 0; m < 13; ++m) {
                    float v = acc[m][n];
                    if (v > rmax[m] || (v == rmax[m] && c < ridx[m])) {
                        rmax[m] = v; ridx[m] = c;
                    }
                }
            }
        }

        #pragma unroll
        for (int n = 0; n < 4; ++n) {
            float bv = -3.0e38f; int bi = 1 << 30;
            #pragma unroll
            for (int m = 0; m < 13; ++m) {
                int row = ty + 16 * m;
                if (row < NP) {
                    float v = acc[m][n];
                    if (v > bv || (v == bv && row < bi)) { bv = v; bi = row; }
                }
            }
            colV[ty][tx + 16 * n] = bv;
            colI[ty][tx + 16 * n] = bi;
        }
        __syncthreads();
        if (tid < 64) {
            int c = tile * 64 + tid;
            if (c < NP) {
                float bv = -3.0e38f; int bi = 1 << 30;
                #pragma unroll
                for (int y = 0; y < 16; ++y) {
                    float v = colV[y][tid]; int i2 = colI[y][tid];
                    if (v > bv || (v == bv && i2 < bi)) { bv = v; bi = i2; }
                }
                out[1 + NBP + b * NP + c] = (float)bi;
            }
        }
        __syncthreads();
    }

    #pragma unroll
    for (int m = 0; m < 13; ++m) {
        float v = rmax[m]; int ix = ridx[m];
        #pragma unroll
        for (int off = 1; off < 16; off <<= 1) {
            float ov = __shfl_xor(v, off, 16);
            int   oi = __shfl_xor(ix, off, 16);
            if (ov > v || (ov == v && oi < ix)) { v = ov; ix = oi; }
        }
        rmax[m] = v; ridx[m] = ix;
    }
    if (tx == 0) {
        #pragma unroll
        for (int m = 0; m < 13; ++m) {
            int row = ty + 16 * m;
            if (row < NP) out[1 + b * NP + row] = (float)ridx[m];
        }
    }
}

__global__ void filip_loss(const float* __restrict__ sim12,
                           float* __restrict__ out) {
    int i = threadIdx.x;  // 0..63
    const float SC = 10.0f / 196.0f;
    const float* row = sim12 + i * NB;
    float mx = -3.0e38f;
    for (int j = 0; j < NB; ++j) mx = fmaxf(mx, row[j] * SC);
    float s = 0.0f;
    for (int j = 0; j < NB; ++j) s += expf(row[j] * SC - mx);
    float lse = mx + logf(s);
    float li = lse - row[i] * SC;
    #pragma unroll
    for (int off = 32; off > 0; off >>= 1)
        li += __shfl_xor(li, off, 64);
    if (i == 0) out[0] = li / 64.0f;
}

// ---------------------------------------------------------------------------
extern "C" void kernel_launch(void* const* d_in, const int* in_sizes, int n_in,
                              void* d_out, int out_size, void* d_ws, size_t ws_size,
                              hipStream_t stream) {
    const float* t1 = (const float*)d_in[0];
    const float* t2 = (const float*)d_in[1];
    float* out = (float*)d_out;
    float* ws  = (float*)d_ws;

    float* inv1  = ws;
    float* inv2  = ws + NBP;
    float* sim12 = ws + 2 * NBP;

    if (ws_size >= (size_t)WS_NEED) {
        char* t1q = (char*)d_ws + WS_T1Q;
        char* t2q = (char*)d_ws + WS_T2Q;
        unsigned long long* parts = (unsigned long long*)((char*)d_ws + WS_PARTS);

        filip_prep6<<<(NBP + NB * 256) / 4, 256, 0, stream>>>(t1, t2, inv1, inv2, sim12, t1q, t2q);
        filip_mega<<<6528, 256, 0, stream>>>(t1q, t2q, sim12, t1, t2, inv1, inv2, parts, out);
        filip_finloss<<<50, 256, 0, stream>>>(parts, sim12, out);
    } else {
        filip_norms<<<2 * NBP, 64, 0, stream>>>(t1, t2, inv1, inv2, sim12);
        filip_mfma<<<dim3(98, NB), 256, 0, stream>>>(t1, t2, inv1, inv2, sim12);
        filip_diag<<<NB, 256, 0, stream>>>(t1, t2, inv1, inv2, out);
        filip_loss<<<1, 64, 0, stream>>>(sim12, out);
    }
}

// Round 13
// 131.263 us; speedup vs baseline: 2.8439x; 1.0312x over previous
//
#include <hip/hip_runtime.h>
#include <math.h>

#define NB 64
#define NP 196
#define ND 256
#define NBP (NB * NP)   // 12544

typedef __bf16 v8bf __attribute__((ext_vector_type(8)));
typedef float f32x16 __attribute__((ext_vector_type(16)));

// ws layout (fast path), bytes:
//   inv1   @ 0        : 12544 f32
//   inv2   @ 50176    : 12544 f32
//   sim12  @ 100352   : 4096  f32
//   t1q    @ 116736   : 98 tiles  x fp8 fragment-linear [kkp8][hi2][row128][16B] = 3211264 B
//   t2q    @ 3328000  : 64 panels x fp8 fragment-linear [kkp8][hi2][col256][16B] = 4194304 B
//   parts  @ 7522304  : 64*4*196 u64 = 401408 B
#define WS_T1Q    116736
#define WS_T2Q    3328000
#define WS_PARTS  7522304
#define WS_NEED   7923712

// ---------------------------------------------------------------------------
// packed (value,index) for argmax with np first-occurrence tie-break
// ---------------------------------------------------------------------------
__device__ __forceinline__ unsigned int fmono(float v) {
    unsigned int u = __float_as_uint(v);
    return (u & 0x80000000u) ? ~u : (u | 0x80000000u);
}
__device__ __forceinline__ unsigned long long packVI(float v, int idx) {
    return ((unsigned long long)fmono(v) << 32) | (unsigned int)(~idx);
}

// ===========================================================================
// FAST PATH
// ===========================================================================

// Kernel 1: per-row norm -> inv arrays; write normalized FP8 (e4m3) in
// fragment-linear layout. Per 16B granule: two K-steps (even kk bytes 0..7,
// odd kk bytes 8..15). Lane L holds k = 4L..4L+3:
//   kkp=(L>>3), odd=(L>>2)&1, hi=(L>>1)&1, j0=(L&1)*4.
__global__ __launch_bounds__(256)
void filip_prep6(const float* __restrict__ t1, const float* __restrict__ t2,
                 float* __restrict__ inv1, float* __restrict__ inv2,
                 float* __restrict__ sim12,
                 char* __restrict__ t1q, char* __restrict__ t2q) {
    const int tid = threadIdx.x;
    if (blockIdx.x == 0) {
        float4 z = make_float4(0.f, 0.f, 0.f, 0.f);
        float4* s4 = reinterpret_cast<float4*>(sim12);
        #pragma unroll
        for (int j = 0; j < 4; ++j) s4[tid * 4 + j] = z;
    }
    int id = blockIdx.x * 4 + (tid >> 6);   // 0 .. NBP + NB*256 - 1
    int L = tid & 63;
    int kkp = L >> 3, odd = (L >> 2) & 1, hi = (L >> 1) & 1, j0 = (L & 1) * 4;
    if (id < NBP) {
        const float* src = t1 + (size_t)id * ND;
        float4 v = reinterpret_cast<const float4*>(src)[L];
        float ss = v.x * v.x + v.y * v.y + v.z * v.z + v.w * v.w;
        #pragma unroll
        for (int off = 32; off > 0; off >>= 1) ss += __shfl_xor(ss, off, 64);
        float inv = 1.0f / fmaxf(sqrtf(ss), 1e-12f);
        if (L == 0) inv1[id] = inv;
        int w0 = __builtin_amdgcn_cvt_pk_fp8_f32(v.x * inv, v.y * inv, 0, false);
        int w  = __builtin_amdgcn_cvt_pk_fp8_f32(v.z * inv, v.w * inv, w0, true);
        int t = id >> 7, r = id & 127;
        *reinterpret_cast<int*>(t1q + (size_t)t * 32768 + kkp * 4096 + hi * 2048
                                + r * 16 + odd * 8 + j0) = w;
    } else {
        int pid = id - NBP;          // 0..16383
        int b2 = pid >> 8, c = pid & 255;
        char* dst = t2q + (size_t)b2 * 65536 + kkp * 8192 + hi * 4096
                    + c * 16 + odd * 8 + j0;
        if (c < NP) {
            const float* src = t2 + (size_t)(b2 * NP + c) * ND;
            float4 v = reinterpret_cast<const float4*>(src)[L];
            float ss = v.x * v.x + v.y * v.y + v.z * v.z + v.w * v.w;
            #pragma unroll
            for (int off = 32; off > 0; off >>= 1) ss += __shfl_xor(ss, off, 64);
            float inv = 1.0f / fmaxf(sqrtf(ss), 1e-12f);
            if (L == 0) inv2[b2 * NP + c] = inv;
            int w0 = __builtin_amdgcn_cvt_pk_fp8_f32(v.x * inv, v.y * inv, 0, false);
            int w  = __builtin_amdgcn_cvt_pk_fp8_f32(v.z * inv, v.w * inv, w0, true);
            *reinterpret_cast<int*>(dst) = w;
        } else {
            *reinterpret_cast<int*>(dst) = 0;   // fp8 zeros
        }
    }
}

#define BM 128
#define BN 256

// 8 MFMAs (2 mt x 4 nt) for one K-step; args are i64 fp8 operands
#define QMFMA8(A0, A1, B0, B1, B2, B3)                                                 \
    acc[0][0] = __builtin_amdgcn_mfma_f32_32x32x16_fp8_fp8((long)(A0), (long)(B0), acc[0][0], 0, 0, 0); \
    acc[0][1] = __builtin_amdgcn_mfma_f32_32x32x16_fp8_fp8((long)(A0), (long)(B1), acc[0][1], 0, 0, 0); \
    acc[0][2] = __builtin_amdgcn_mfma_f32_32x32x16_fp8_fp8((long)(A0), (long)(B2), acc[0][2], 0, 0, 0); \
    acc[0][3] = __builtin_amdgcn_mfma_f32_32x32x16_fp8_fp8((long)(A0), (long)(B3), acc[0][3], 0, 0, 0); \
    acc[1][0] = __builtin_amdgcn_mfma_f32_32x32x16_fp8_fp8((long)(A1), (long)(B0), acc[1][0], 0, 0, 0); \
    acc[1][1] = __builtin_amdgcn_mfma_f32_32x32x16_fp8_fp8((long)(A1), (long)(B1), acc[1][1], 0, 0, 0); \
    acc[1][2] = __builtin_amdgcn_mfma_f32_32x32x16_fp8_fp8((long)(A1), (long)(B2), acc[1][2], 0, 0, 0); \
    acc[1][3] = __builtin_amdgcn_mfma_f32_32x32x16_fp8_fp8((long)(A1), (long)(B3), acc[1][3], 0, 0, 0);

// one superstep = 2 K-steps: even kk in .x, odd kk in .y
#define QMFMA_SET(SA0, SA1, SB0, SB1, SB2, SB3)                      \
    QMFMA8(SA0.x, SA1.x, SB0.x, SB1.x, SB2.x, SB3.x);                \
    QMFMA8(SA0.y, SA1.y, SB0.y, SB1.y, SB2.y, SB3.y);

// Kernel 2 (MEGA): blocks [0,256) = fp32-exact diagonal argmax (overlaps the
// GEMM); blocks [256, 6528) = FP8 MFMA GEMM: all A fragments preloaded to
// registers, full B panel (64KB, K complete) staged once to LDS, then a
// BARRIER-FREE K-loop of pure ds_read(imm)+MFMA. Zero global loads, zero
// barriers, zero vmcnt in the loop.
__global__ __launch_bounds__(256, 2)
void filip_mega(const char* __restrict__ t1q, const char* __restrict__ t2q,
                float* __restrict__ sim12,
                const float* __restrict__ t1, const float* __restrict__ t2,
                const float* __restrict__ inv1, const float* __restrict__ inv2,
                unsigned long long* __restrict__ parts,
                float* __restrict__ out)
{
    __shared__ __align__(16) char smem[65536];
    const int bid = blockIdx.x;
    const int tid = threadIdx.x;

    if (bid >= 256) {
        // =================== FP8 MFMA GEMM path ===================
        int n = bid - 256;                      // 0..6271
        int x = n & 7, local = n >> 3;
        const int bRow = local >> 3;            // 0..97
        const int b2   = x * 8 + (local & 7);   // 0..63

        const int lane = tid & 63, wave = tid >> 6;
        const int wr = wave >> 1, wc = wave & 1;
        const int ln = lane & 31, hi = lane >> 5;

        // per-lane A fragment base: [kkp][hi][row][16B]
        const char* Ag = t1q + (size_t)bRow * 32768 + hi * 2048 + (wr * 64 + ln) * 16;
        const char* Bg = t2q + (size_t)b2 * 65536;

        // issue ALL 16 A fragment-pair loads (64 VGPR); latency hides under
        // the B staging below.
        ulonglong2 aA[8][2];
        #pragma unroll
        for (int sp = 0; sp < 8; ++sp) {
            aA[sp][0] = *reinterpret_cast<const ulonglong2*>(Ag + sp * 4096);
            aA[sp][1] = *reinterpret_cast<const ulonglong2*>(Ag + sp * 4096 + 512);
        }

        // stage full B panel (64KB, byte-identical fragment-linear image)
        #pragma unroll
        for (int i = 0; i < 16; ++i) {
            *reinterpret_cast<ulonglong2*>(smem + i * 4096 + tid * 16) =
                *reinterpret_cast<const ulonglong2*>(Bg + i * 4096 + tid * 16);
        }

        f32x16 acc[2][4];
        #pragma unroll
        for (int mt = 0; mt < 2; ++mt)
            #pragma unroll
            for (int nt = 0; nt < 4; ++nt)
                #pragma unroll
                for (int r = 0; r < 16; ++r) acc[mt][nt][r] = 0.0f;

        __syncthreads();   // B panel complete (also drains A loads)

        // barrier-free K-loop: one LDS base VGPR, all offsets immediate.
        const char* Bl = smem + hi * 4096 + wc * 2048 + ln * 16;
        __builtin_amdgcn_s_setprio(1);
        #pragma unroll
        for (int sp = 0; sp < 8; ++sp) {
            ulonglong2 b0 = *reinterpret_cast<const ulonglong2*>(Bl + sp * 8192);
            ulonglong2 b1 = *reinterpret_cast<const ulonglong2*>(Bl + sp * 8192 + 512);
            ulonglong2 b2v = *reinterpret_cast<const ulonglong2*>(Bl + sp * 8192 + 1024);
            ulonglong2 b3v = *reinterpret_cast<const ulonglong2*>(Bl + sp * 8192 + 1536);
            QMFMA_SET(aA[sp][0], aA[sp][1], b0, b1, b2v, b3v);
        }
        __builtin_amdgcn_s_setprio(0);

        __syncthreads();   // all B reads done before pmx overwrites smem

        // rowmax epilogue via LDS transpose (max associative -> exact)
        // C/D layout (dtype-independent): col = lane&31, row = (r&3)+8*(r>>2)+4*hi
        float (*pmx)[68] = reinterpret_cast<float (*)[68]>(smem);
        #pragma unroll
        for (int mt = 0; mt < 2; ++mt) {
            #pragma unroll
            for (int r = 0; r < 16; ++r) {
                float m = fmaxf(fmaxf(acc[mt][0][r], acc[mt][1][r]),
                                fmaxf(acc[mt][2][r], acc[mt][3][r]));
                int row = wr * 64 + mt * 32 + (r & 3) + 8 * (r >> 2) + 4 * hi;
                pmx[row][wc * 32 + ln] = m;
            }
        }
        __syncthreads();
        if (tid < BM) {
            const float4* prow = reinterpret_cast<const float4*>(pmx[tid]);
            float m = -3.0e38f;
            #pragma unroll
            for (int j = 0; j < 16; ++j) {
                float4 v = prow[j];
                m = fmaxf(m, fmaxf(fmaxf(v.x, v.y), fmaxf(v.z, v.w)));
            }
            int grow = bRow * BM + tid;
            int b1 = grow / NP;
            int fb = (bRow * BM) / NP;
            float v0 = (b1 == fb) ? m : 0.0f;
            float v1 = (b1 != fb) ? m : 0.0f;
            #pragma unroll
            for (int off = 1; off < 64; off <<= 1) {
                v0 += __shfl_xor(v0, off, 64);
                v1 += __shfl_xor(v1, off, 64);
            }
            if (lane == 0) {
                atomicAdd(&sim12[fb * NB + b2], v0);
                int lb = (bRow * BM + BM - 1) / NP;
                if (lb != fb) atomicAdd(&sim12[lb * NB + b2], v1);
            }
        }
        return;
    }

    // =================== fp32-exact diagonal path ===================
    {
        const int q = bid & 3;             // 0..3 (row quarter)
        const int b = bid >> 2;            // 0..63
        const int r0 = q * 49;
        const int tx = tid & 15, ty = tid >> 4;

        float* As = reinterpret_cast<float*>(smem);
        float* Bs = As + 2176;
        unsigned long long* colP = reinterpret_cast<unsigned long long*>(smem);

        const float* Ap = t1 + (size_t)b * NP * ND;
        const float* Bp = t2 + (size_t)b * NP * ND;
        const float* ia = inv1 + b * NP;
        const float* ib = inv2 + b * NP;

        float acc[4][4][4];
        #pragma unroll
        for (int i = 0; i < 4; ++i)
            #pragma unroll
            for (int j = 0; j < 4; ++j)
                #pragma unroll
                for (int l = 0; l < 4; ++l) acc[i][j][l] = 0.0f;

        for (int kc = 0; kc < 8; ++kc) {
            __syncthreads();
            #pragma unroll
            for (int i = 0; i < 2; ++i) {
                int f4 = tid + 256 * i;            // 0..511
                int row = f4 >> 3, k4 = f4 & 7;
                float4 v = make_float4(0.f, 0.f, 0.f, 0.f);
                if (row < 49) {
                    v = *reinterpret_cast<const float4*>(Ap + (size_t)(r0 + row) * ND + kc * 32 + 4 * k4);
                    float s = ia[r0 + row];
                    v.x *= s; v.y *= s; v.z *= s; v.w *= s;
                }
                As[(4 * k4 + 0) * 68 + row] = v.x;
                As[(4 * k4 + 1) * 68 + row] = v.y;
                As[(4 * k4 + 2) * 68 + row] = v.z;
                As[(4 * k4 + 3) * 68 + row] = v.w;
            }
            #pragma unroll
            for (int i = 0; i < 8; ++i) {
                int f4 = tid + 256 * i;            // 0..2047
                int col = f4 >> 3, k4 = f4 & 7;
                float4 v = make_float4(0.f, 0.f, 0.f, 0.f);
                if (col < NP) {
                    v = *reinterpret_cast<const float4*>(Bp + (size_t)col * ND + kc * 32 + 4 * k4);
                    float s = ib[col];
                    v.x *= s; v.y *= s; v.z *= s; v.w *= s;
                }
                Bs[(4 * k4 + 0) * 260 + col] = v.x;
                Bs[(4 * k4 + 1) * 260 + col] = v.y;
                Bs[(4 * k4 + 2) * 260 + col] = v.z;
                Bs[(4 * k4 + 3) * 260 + col] = v.w;
            }
            __syncthreads();
            #pragma unroll 4
            for (int k = 0; k < 32; ++k) {
                float a0 = As[k * 68 + 4 * ty + 0];
                float a1 = As[k * 68 + 4 * ty + 1];
                float a2 = As[k * 68 + 4 * ty + 2];
                float a3 = As[k * 68 + 4 * ty + 3];
                float4 bq[4];
                #pragma unroll
                for (int j = 0; j < 4; ++j)
                    bq[j] = *reinterpret_cast<const float4*>(&Bs[k * 260 + 4 * tx + 64 * j]);
                #pragma unroll
                for (int j = 0; j < 4; ++j) {
                    acc[0][j][0] = fmaf(a0, bq[j].x, acc[0][j][0]);
                    acc[0][j][1] = fmaf(a0, bq[j].y, acc[0][j][1]);
                    acc[0][j][2] = fmaf(a0, bq[j].z, acc[0][j][2]);
                    acc[0][j][3] = fmaf(a0, bq[j].w, acc[0][j][3]);
                    acc[1][j][0] = fmaf(a1, bq[j].x, acc[1][j][0]);
                    acc[1][j][1] = fmaf(a1, bq[j].y, acc[1][j][1]);
                    acc[1][j][2] = fmaf(a1, bq[j].z, acc[1][j][2]);
                    acc[1][j][3] = fmaf(a1, bq[j].w, acc[1][j][3]);
                    acc[2][j][0] = fmaf(a2, bq[j].x, acc[2][j][0]);
                    acc[2][j][1] = fmaf(a2, bq[j].y, acc[2][j][1]);
                    acc[2][j][2] = fmaf(a2, bq[j].z, acc[2][j][2]);
                    acc[2][j][3] = fmaf(a2, bq[j].w, acc[2][j][3]);
                    acc[3][j][0] = fmaf(a3, bq[j].x, acc[3][j][0]);
                    acc[3][j][1] = fmaf(a3, bq[j].y, acc[3][j][1]);
                    acc[3][j][2] = fmaf(a3, bq[j].z, acc[3][j][2]);
                    acc[3][j][3] = fmaf(a3, bq[j].w, acc[3][j][3]);
                }
            }
        }

        // row argmax (idx_to_keep1_2)
        #pragma unroll
        for (int i = 0; i < 4; ++i) {
            unsigned long long best = 0ull;
            #pragma unroll
            for (int j = 0; j < 4; ++j)
                #pragma unroll
                for (int l = 0; l < 4; ++l) {
                    int c = 64 * j + 4 * tx + l;
                    if (c < NP) {
                        unsigned long long p = packVI(acc[i][j][l], c);
                        if (p > best) best = p;
                    }
                }
            #pragma unroll
            for (int off = 1; off < 16; off <<= 1) {
                unsigned long long o = __shfl_xor(best, off, 16);
                if (o > best) best = o;
            }
            int rl = 4 * ty + i;
            if (tx == 0 && rl < 49)
                out[1 + b * NP + r0 + rl] = (float)(unsigned int)(~best);
        }

        // col argmax partials (idx_to_keep2_1)
        __syncthreads();
        #pragma unroll
        for (int j = 0; j < 4; ++j)
            #pragma unroll
            for (int l = 0; l < 4; ++l) {
                unsigned long long best = 0ull;
                #pragma unroll
                for (int i = 0; i < 4; ++i) {
                    int rl = 4 * ty + i;
                    if (rl < 49) {
                        unsigned long long p = packVI(acc[i][j][l], r0 + rl);
                        if (p > best) best = p;
                    }
                }
                colP[ty * 256 + 64 * j + 4 * tx + l] = best;
            }
        __syncthreads();
        {
            unsigned long long best = 0ull;
            #pragma unroll
            for (int y = 0; y < 16; ++y) {
                unsigned long long o = colP[y * 256 + tid];
                if (o > best) best = o;
            }
            if (tid < NP) parts[(b * 4 + q) * NP + tid] = best;
        }
    }
}

// Kernel 3: merged fin (blocks 0..48) + loss (block 49).
__global__ void filip_finloss(const unsigned long long* __restrict__ parts,
                              const float* __restrict__ sim12,
                              float* __restrict__ out) {
    if (blockIdx.x < 49) {
        int id = blockIdx.x * 256 + threadIdx.x;   // 49*256 = 12544
        int b = id / NP, c = id - b * NP;
        unsigned long long best = 0ull;
        #pragma unroll
        for (int qq = 0; qq < 4; ++qq) {
            unsigned long long o = parts[(b * 4 + qq) * NP + c];
            if (o > best) best = o;
        }
        out[1 + NBP + id] = (float)(unsigned int)(~best);
    } else if (threadIdx.x < 64) {
        int i = threadIdx.x;  // 0..63
        const float SC = 10.0f / 196.0f;
        const float* row = sim12 + i * NB;
        float mx = -3.0e38f;
        for (int j = 0; j < NB; ++j) mx = fmaxf(mx, row[j] * SC);
        float s = 0.0f;
        for (int j = 0; j < NB; ++j) s += expf(row[j] * SC - mx);
        float lse = mx + logf(s);
        float li = lse - row[i] * SC;
        #pragma unroll
        for (int off = 32; off > 0; off >>= 1)
            li += __shfl_xor(li, off, 64);
        if (i == 0) out[0] = li / 64.0f;
    }
}

// ===========================================================================
// FALLBACK PATH (verbatim round-2, known-passing) — used if ws too small
// ===========================================================================
__global__ void filip_norms(const float* __restrict__ t1,
                            const float* __restrict__ t2,
                            float* __restrict__ inv1,
                            float* __restrict__ inv2,
                            float* __restrict__ sim12) {
    int row = blockIdx.x;
    int lane = threadIdx.x;
    if (row < NB) sim12[row * NB + lane] = 0.0f;
    const float* src; float* dst; int r;
    if (row < NBP) { src = t1; dst = inv1; r = row; }
    else           { src = t2; dst = inv2; r = row - NBP; }
    float4 v = reinterpret_cast<const float4*>(src + (size_t)r * ND)[lane];
    float ss = v.x * v.x + v.y * v.y + v.z * v.z + v.w * v.w;
    #pragma unroll
    for (int off = 32; off > 0; off >>= 1)
        ss += __shfl_xor(ss, off, 64);
    if (lane == 0)
        dst[r] = 1.0f / fmaxf(sqrtf(ss), 1e-12f);
}

__device__ __forceinline__ v8bf cvt8(float4 a, float4 b, float s) {
    v8bf v;
    v[0] = (__bf16)(a.x * s); v[1] = (__bf16)(a.y * s);
    v[2] = (__bf16)(a.z * s); v[3] = (__bf16)(a.w * s);
    v[4] = (__bf16)(b.x * s); v[5] = (__bf16)(b.y * s);
    v[6] = (__bf16)(b.z * s); v[7] = (__bf16)(b.w * s);
    return v;
}

#define BKF 64
__global__ __launch_bounds__(256, 2)
void filip_mfma(const float* __restrict__ t1, const float* __restrict__ t2,
                const float* __restrict__ inv1, const float* __restrict__ inv2,
                float* __restrict__ sim12)
{
    __shared__ unsigned short Asb[BM * BKF];
    __shared__ unsigned short Bsb[BN * BKF];
    __shared__ float rmx[2][BM];

    const int bRow = blockIdx.x;
    const int b2   = blockIdx.y;
    const int tid  = threadIdx.x;
    const int lane = tid & 63, wave = tid >> 6;
    const int wr = wave >> 1, wc = wave & 1;
    const int ln = lane & 31, hi = lane >> 5;

    const float* Abase = t1 + (size_t)bRow * BM * ND;
    const float* Bbase = t2 + (size_t)b2 * NP * ND;

    f32x16 acc[2][4];
    #pragma unroll
    for (int mt = 0; mt < 2; ++mt)
        #pragma unroll
        for (int nt = 0; nt < 4; ++nt)
            #pragma unroll
            for (int r = 0; r < 16; ++r) acc[mt][nt][r] = 0.0f;

    for (int kc = 0; kc < 4; ++kc) {
        __syncthreads();
        #pragma unroll
        for (int i = 0; i < 4; ++i) {
            int flat = (i * 256 + tid) * 8;
            int r = flat >> 6, k0 = flat & 63;
            const float* gp = Abase + (size_t)r * ND + kc * BKF + k0;
            float4 f0 = *reinterpret_cast<const float4*>(gp);
            float4 f1 = *reinterpret_cast<const float4*>(gp + 4);
            float s = inv1[bRow * BM + r];
            v8bf v = cvt8(f0, f1, s);
            int off = r * 128 + ((k0 * 2) ^ ((r & 7) << 4));
            *reinterpret_cast<v8bf*>(reinterpret_cast<char*>(Asb) + off) = v;
        }
        #pragma unroll
        for (int i = 0; i < 8; ++i) {
            int flat = (i * 256 + tid) * 8;
            int r = flat >> 6, k0 = flat & 63;
            v8bf v;
            if (r < NP) {
                const float* gp = Bbase + (size_t)r * ND + kc * BKF + k0;
                float4 f0 = *reinterpret_cast<const float4*>(gp);
                float4 f1 = *reinterpret_cast<const float4*>(gp + 4);
                float s = inv2[b2 * NP + r];
                v = cvt8(f0, f1, s);
            } else {
                #pragma unroll
                for (int j = 0; j < 8; ++j) v[j] = (__bf16)0.0f;
            }
            int off = r * 128 + ((k0 * 2) ^ ((r & 7) << 4));
            *reinterpret_cast<v8bf*>(reinterpret_cast<char*>(Bsb) + off) = v;
        }
        __syncthreads();
        #pragma unroll
        for (int ks = 0; ks < 4; ++ks) {
            const int kb = ks * 32 + hi * 16;
            v8bf af[2], bfr[4];
            #pragma unroll
            for (int mt = 0; mt < 2; ++mt) {
                int r = wr * 64 + mt * 32 + ln;
                af[mt] = *reinterpret_cast<const v8bf*>(
                    reinterpret_cast<const char*>(Asb) + r * 128 + (kb ^ ((r & 7) << 4)));
            }
            #pragma unroll
            for (int nt = 0; nt < 4; ++nt) {
                int c = wc * 128 + nt * 32 + ln;
                bfr[nt] = *reinterpret_cast<const v8bf*>(
                    reinterpret_cast<const char*>(Bsb) + c * 128 + (kb ^ ((c & 7) << 4)));
            }
            #pragma unroll
            for (int mt = 0; mt < 2; ++mt)
                #pragma unroll
                for (int nt = 0; nt < 4; ++nt)
                    acc[mt][nt] = __builtin_amdgcn_mfma_f32_32x32x16_bf16(
                        af[mt], bfr[nt], acc[mt][nt], 0, 0, 0);
        }
    }

    #pragma unroll
    for (int mt = 0; mt < 2; ++mt) {
        float t[16];
        #pragma unroll
        for (int r = 0; r < 16; ++r) {
            float m = fmaxf(fmaxf(acc[mt][0][r], acc[mt][1][r]),
                            fmaxf(acc[mt][2][r], acc[mt][3][r]));
            #pragma unroll
            for (int off = 1; off <= 16; off <<= 1)
                m = fmaxf(m, __shfl_xor(m, off, 64));
            t[r] = m;
        }
        if (ln == 0) {
            #pragma unroll
            for (int r = 0; r < 16; ++r) {
                int row = wr * 64 + mt * 32 + (r & 3) + 8 * (r >> 2) + 4 * hi;
                rmx[wc][row] = t[r];
            }
        }
    }
    __syncthreads();
    if (tid < BM) {
        float m = fmaxf(rmx[0][tid], rmx[1][tid]);
        int grow = bRow * BM + tid;
        int b1 = grow / NP;
        int fb = (bRow * BM) / NP;
        float v0 = (b1 == fb) ? m : 0.0f;
        float v1 = (b1 != fb) ? m : 0.0f;
        #pragma unroll
        for (int off = 1; off < 64; off <<= 1) {
            v0 += __shfl_xor(v0, off, 64);
            v1 += __shfl_xor(v1, off, 64);
        }
        if (lane == 0) {
            atomicAdd(&sim12[fb * NB + b2], v0);
            int lb = (bRow * BM + BM - 1) / NP;
            if (lb != fb) atomicAdd(&sim12[lb * NB + b2], v1);
        }
    }
}

__global__ __launch_bounds__(256)
void filip_diag(const float* __restrict__ t1, const float* __restrict__ t2,
                const float* __restrict__ inv1, const float* __restrict__ inv2,
                float* __restrict__ out)
{
    const int b = blockIdx.x;
    const int tid = threadIdx.x;
    const int tx = tid & 15, ty = tid >> 4;

    __shared__ float As2[16][209];
    __shared__ float Bs2[16][65];
    __shared__ float colV[16][65];
    __shared__ int   colI[16][65];

    const float* Ap = t1 + (size_t)b * NP * ND;
    const float* Bp = t2 + (size_t)b * NP * ND;
    const float* ia = inv1 + b * NP;
    const float* ib = inv2 + b * NP;

    float rmax[13];
    int   ridx[13];
    #pragma unroll
    for (int m = 0; m < 13; ++m) { rmax[m] = -3.0e38f; ridx[m] = 1 << 30; }

    for (int tile = 0; tile < 4; ++tile) {
        float acc[13][4];
        #pragma unroll
        for (int m = 0; m < 13; ++m)
            #pragma unroll
            for (int n = 0; n < 4; ++n) acc[m][n] = 0.0f;

        for (int kk = 0; kk < 16; ++kk) {
            __syncthreads();
            #pragma unroll
            for (int i = 0; i < 13; ++i) {
                int e = tid + 256 * i;
                int p1 = e >> 4, k = e & 15;
                float v = 0.0f;
                if (p1 < NP) v = Ap[p1 * ND + kk * 16 + k] * ia[p1];
                As2[k][p1] = v;
            }
            #pragma unroll
            for (int i = 0; i < 4; ++i) {
                int e = tid + 256 * i;
                int pl = e >> 4, k = e & 15;
                int p2 = tile * 64 + pl;
                float v = 0.0f;
                if (p2 < NP) v = Bp[p2 * ND + kk * 16 + k] * ib[p2];
                Bs2[k][pl] = v;
            }
            __syncthreads();
            #pragma unroll 4
            for (int k = 0; k < 16; ++k) {
                float a[13], bq[4];
                #pragma unroll
                for (int m = 0; m < 13; ++m) a[m] = As2[k][ty + 16 * m];
                #pragma unroll
                for (int n = 0; n < 4; ++n) bq[n] = Bs2[k][tx + 16 * n];
                #pragma unroll
                for (int m = 0; m < 13; ++m)
                    #pragma unroll
                    for (int n = 0; n < 4; ++n)
                        acc[m][n] = fmaf(a[m], bq[n], acc[m][n]);
            }
        }

        #pragma unroll
        for (int n = 0; n < 4; ++n) {
            int c = tile * 64 + tx + 16 * n;
            if (c < NP) {
                #pragma unroll
                for (int m = 0; m < 13; ++m) {
                    float v = acc[m][n];
                    if (v > rmax[m] || (v == rmax[m] && c < ridx[m])) {
                        rmax[m] = v; ridx[m] = c;
                    }
                }
            }
        }

        #pragma unroll
        for (int n = 0; n < 4; ++n) {
            float bv = -3.0e38f; int bi = 1 << 30;
            #pragma unroll
            for (int m = 0; m < 13; ++m) {
                int row = ty + 16 * m;
                if (row < NP) {
                    float v = acc[m][n];
                    if (v > bv || (v == bv && row < bi)) { bv = v; bi = row; }
                }
            }
            colV[ty][tx + 16 * n] = bv;
            colI[ty][tx + 16 * n] = bi;
        }
        __syncthreads();
        if (tid < 64) {
            int c = tile * 64 + tid;
            if (c < NP) {
                float bv = -3.0e38f; int bi = 1 << 30;
                #pragma unroll
                for (int y = 0; y < 16; ++y) {
                    float v = colV[y][tid]; int i2 = colI[y][tid];
                    if (v > bv || (v == bv && i2 < bi)) { bv = v; bi = i2; }
                }
                out[1 + NBP + b * NP + c] = (float)bi;
            }
        }
        __syncthreads();
    }

    #pragma unroll
    for (int m = 0; m < 13; ++m) {
        float v = rmax[m]; int ix = ridx[m];
        #pragma unroll
        for (int off = 1; off < 16; off <<= 1) {
            float ov = __shfl_xor(v, off, 16);
            int   oi = __shfl_xor(ix, off, 16);
            if (ov > v || (ov == v && oi < ix)) { v = ov; ix = oi; }
        }
        rmax[m] = v; ridx[m] = ix;
    }
    if (tx == 0) {
        #pragma unroll
        for (int m = 0; m < 13; ++m) {
            int row = ty + 16 * m;
            if (row < NP) out[1 + b * NP + row] = (float)ridx[m];
        }
    }
}

__global__ void filip_loss(const float* __restrict__ sim12,
                           float* __restrict__ out) {
    int i = threadIdx.x;  // 0..63
    const float SC = 10.0f / 196.0f;
    const float* row = sim12 + i * NB;
    float mx = -3.0e38f;
    for (int j = 0; j < NB; ++j) mx = fmaxf(mx, row[j] * SC);
    float s = 0.0f;
    for (int j = 0; j < NB; ++j) s += expf(row[j] * SC - mx);
    float lse = mx + logf(s);
    float li = lse - row[i] * SC;
    #pragma unroll
    for (int off = 32; off > 0; off >>= 1)
        li += __shfl_xor(li, off, 64);
    if (i == 0) out[0] = li / 64.0f;
}

// ---------------------------------------------------------------------------
extern "C" void kernel_launch(void* const* d_in, const int* in_sizes, int n_in,
                              void* d_out, int out_size, void* d_ws, size_t ws_size,
                              hipStream_t stream) {
    const float* t1 = (const float*)d_in[0];
    const float* t2 = (const float*)d_in[1];
    float* out = (float*)d_out;
    float* ws  = (float*)d_ws;

    float* inv1  = ws;
    float* inv2  = ws + NBP;
    float* sim12 = ws + 2 * NBP;

    if (ws_size >= (size_t)WS_NEED) {
        char* t1q = (char*)d_ws + WS_T1Q;
        char* t2q = (char*)d_ws + WS_T2Q;
        unsigned long long* parts = (unsigned long long*)((char*)d_ws + WS_PARTS);

        filip_prep6<<<(NBP + NB * 256) / 4, 256, 0, stream>>>(t1, t2, inv1, inv2, sim12, t1q, t2q);
        filip_mega<<<6528, 256, 0, stream>>>(t1q, t2q, sim12, t1, t2, inv1, inv2, parts, out);
        filip_finloss<<<50, 256, 0, stream>>>(parts, sim12, out);
    } else {
        filip_norms<<<2 * NBP, 64, 0, stream>>>(t1, t2, inv1, inv2, sim12);
        filip_mfma<<<dim3(98, NB), 256, 0, stream>>>(t1, t2, inv1, inv2, sim12);
        filip_diag<<<NB, 256, 0, stream>>>(t1, t2, inv1, inv2, out);
        filip_loss<<<1, 64, 0, stream>>>(sim12, out);
    }
}